// Round 11
// baseline (652.060 us; speedup 1.0000x reference)
//
#include <hip/hip_runtime.h>
#include <math.h>

#define EE 1024
#define ROWS_TOT 784   // 576 + 144 + 64
#define WWN 10752      // 768 + 3072 + 6912

typedef __attribute__((ext_vector_type(4))) float f4;
typedef __attribute__((ext_vector_type(4))) float f32x4;
typedef __attribute__((ext_vector_type(8))) __bf16 bf16x8;
typedef __attribute__((ext_vector_type(8))) unsigned short ushort8;

__device__ __forceinline__ unsigned short f2b(float x) {
    unsigned int u = __float_as_uint(x);
    unsigned int r = (u + 0x7fffu + ((u >> 16) & 1u)) >> 16;
    return (unsigned short)r;
}
__device__ __forceinline__ float b2f(unsigned short u) {
    unsigned int v = ((unsigned int)u) << 16;
    return __uint_as_float(v);
}

#define GLOAD16(g, l) __builtin_amdgcn_global_load_lds( \
    (const __attribute__((address_space(1))) unsigned int*)(g), \
    (__attribute__((address_space(3))) unsigned int*)(l), 16, 0, 0)

// ---------------------------------------------------------------------------
// MERGED value GEMM: all 3 levels + split-K in ONE 1408-block dispatch for
// near-ideal CU packing (levels: 576x12-step, 576x12-step, 256x27-step).
// Geometry/schedule identical to round-10 best (256x256, BK=64, 8 waves,
// 128KB LDS dbuf, T3/T4/T5 phases, 128B-row swizzle s^(r&7)).
// L1 writes VAL(+bias); L2/L3 write bf16 partials per z-slice.
// ---------------------------------------------------------------------------
__global__ __launch_bounds__(512, 2) void gemm_val(
    const unsigned short* __restrict__ FEAT, const unsigned short* __restrict__ WW,
    const float* __restrict__ b1, unsigned short* __restrict__ VAL,
    unsigned short* __restrict__ PART_L2, unsigned short* __restrict__ PART_L3)
{
    __shared__ unsigned short As[2][256 * 64];   // 32KB each
    __shared__ unsigned short Bs[2][256 * 64];

    const int t = threadIdx.x;
    const int lane = t & 63;
    const int w = t >> 6;                // 0..7
    const int wm = w >> 2;               // 0..1  (128-row half)
    const int wn = w & 3;                // 0..3  (64-col quarter)

    // bijective XCD swizzle over 1408 blocks (1408/8 = 176)
    int bid = blockIdx.x;
    int swz = (bid & 7) * 176 + (bid >> 3);

    int mode, by, bx, z, ktCount;
    if (swz < 576)       { mode = 1; ktCount = 12; z = 0;        by = swz >> 2; bx = swz & 3; }
    else if (swz < 1152) { int r = swz - 576;  mode = 2; ktCount = 12; z = r / 144; r -= z * 144; by = r >> 2; bx = r & 3; }
    else                 { int r = swz - 1152; mode = 3; ktCount = 27; z = r >> 6;  r &= 63;      by = r >> 2; bx = r & 3; }
    const int ktBase = z * ktCount;
    const int gw     = (mode == 1) ? 24 : (mode == 2 ? 12 : 8);
    const int Rl     = gw * gw;
    const int colOff = (mode == 1) ? 0 : (mode == 2 ? 768 : 3840);
    const int m0 = by * 256, n0 = bx * 256;

    f32x4 acc[8][4] = {};

    // ---- staging roles: 4 gloads per operand per wave (32 rows x 128B) ----
    const int srow = lane >> 3;                  // 0..7 row within 8-row gload
    const int sseg = lane & 7;                   // stored 16B slot 0..7
    const int sgx  = sseg ^ srow;                // pre-swizzled global chunk
    int rbA[4];
#pragma unroll
    for (int g = 0; g < 4; ++g) {
        int gr = m0 + w * 32 + g * 8 + srow;
        if (mode == 1) rbA[g] = gr;
        else {
            int b_ = gr / Rl, rl = gr - b_ * Rl;
            rbA[g] = b_ * 576 + (mode * (rl / gw)) * 24 + mode * (rl % gw);
        }
    }
    const unsigned short* gBbase = WW + (size_t)(n0 + w * 32 + srow) * WWN + colOff + sgx * 8;

    // ---- fragment-read roles ----
    const int fr = lane & 15;
    const int kg = lane >> 4;
    const int kgx0 = kg ^ (fr & 7);              // kk=0 slot
    const int kgx1 = kgx0 ^ 4;                   // kk=1 slot
    const int aOff0 = (wm * 128 + fr) * 64 + kgx0 * 8;
    const int aOff1 = (wm * 128 + fr) * 64 + kgx1 * 8;
    const int bOff0 = (wn * 64 + fr) * 64 + kgx0 * 8;
    const int bOff1 = (wn * 64 + fr) * 64 + kgx1 * 8;

    auto STAGE = [&](int buf, int ktl) {
        int kt = ktBase + ktl;                   // BK=64 tile index
        int s = kt / 12;                         // which 768-chunk of K
        int within = (kt - s * 12) * 64;         // + sgx*8 stays within the chunk
        int add = 0;
        if (mode == 2)      add = (s >> 1) * 24 + (s & 1);
        else if (mode == 3) { int di = s / 3; add = di * 24 + (s - 3 * di); }
#pragma unroll
        for (int g = 0; g < 4; ++g)
            GLOAD16(FEAT + (size_t)(rbA[g] + add) * 768 + within + sgx * 8,
                    &As[buf][(w * 32 + g * 8) * 64]);
#pragma unroll
        for (int g = 0; g < 4; ++g)
            GLOAD16(gBbase + (size_t)(g * 8) * WWN + (size_t)kt * 64,
                    &Bs[buf][(w * 32 + g * 8) * 64]);
    };

    const int nt = ktCount;
    int cur = 0;
    STAGE(0, 0);

    for (int tt = 0; tt < nt; ++tt) {
        // boundary: wait only for the stage issued one full iteration ago
        asm volatile("s_waitcnt vmcnt(0)" ::: "memory");
        __builtin_amdgcn_s_barrier();
        __builtin_amdgcn_sched_barrier(0);

        if (tt + 1 < nt) STAGE(cur ^ 1, tt + 1);        // in flight across phases
        __builtin_amdgcn_sched_barrier(0);

        // ---- phase kk=0: K elems [0,32), 32 MFMA ----
        {
            bf16x8 bf[4], af[8];
#pragma unroll
            for (int j = 0; j < 4; ++j) bf[j] = *(const bf16x8*)(&Bs[cur][bOff0] + j * 1024);
#pragma unroll
            for (int i = 0; i < 8; ++i) af[i] = *(const bf16x8*)(&As[cur][aOff0] + i * 1024);
            __builtin_amdgcn_s_setprio(1);
#pragma unroll
            for (int i = 0; i < 8; ++i)
#pragma unroll
                for (int j = 0; j < 4; ++j)
                    acc[i][j] = __builtin_amdgcn_mfma_f32_16x16x32_bf16(af[i], bf[j], acc[i][j], 0, 0, 0);
            __builtin_amdgcn_s_setprio(0);
        }
        __builtin_amdgcn_s_barrier();
        __builtin_amdgcn_sched_barrier(0);

        // ---- phase kk=1: K elems [32,64), 32 MFMA ----
        {
            bf16x8 bf[4], af[8];
#pragma unroll
            for (int j = 0; j < 4; ++j) bf[j] = *(const bf16x8*)(&Bs[cur][bOff1] + j * 1024);
#pragma unroll
            for (int i = 0; i < 8; ++i) af[i] = *(const bf16x8*)(&As[cur][aOff1] + i * 1024);
            __builtin_amdgcn_s_setprio(1);
#pragma unroll
            for (int i = 0; i < 8; ++i)
#pragma unroll
                for (int j = 0; j < 4; ++j)
                    acc[i][j] = __builtin_amdgcn_mfma_f32_16x16x32_bf16(af[i], bf[j], acc[i][j], 0, 0, 0);
            __builtin_amdgcn_s_setprio(0);
        }
        cur ^= 1;
    }

    unsigned short* dst;
    if (mode == 1)      dst = nullptr;
    else if (mode == 2) dst = PART_L2 + (size_t)z * 9437184;
    else                dst = PART_L3 + (size_t)z * 4194304;

#pragma unroll
    for (int i = 0; i < 8; ++i) {
#pragma unroll
        for (int r = 0; r < 4; ++r) {
            int m = m0 + wm * 128 + i * 16 + kg * 4 + r;   // local level row
#pragma unroll
            for (int j = 0; j < 4; ++j) {
                int n = n0 + wn * 64 + j * 16 + fr;
                if (mode == 1) {
                    int b_o = m / 576, rl_o = m - b_o * 576;
                    int crow = b_o * ROWS_TOT + rl_o;
                    VAL[(size_t)crow * EE + n] = f2b(acc[i][j][r] + b1[n]);
                } else {
                    dst[(size_t)m * EE + n] = f2b(acc[i][j][r]);
                }
            }
        }
    }
}

// merged reduce: blocks [0,4608) = L2 (4 slices, rows 576..719/batch);
// [4608,6656) = L3 (4 slices, rows 720..783/batch)
__global__ void reduce_both_kernel(const unsigned short* __restrict__ P2, const unsigned short* __restrict__ P3,
                                   const float* __restrict__ b2, const float* __restrict__ b3,
                                   unsigned short* __restrict__ VAL)
{
    int blk = blockIdx.x;
    const unsigned short* P;
    const float* bb;
    size_t stride;
    int isL2 = (blk < 4608);
    if (isL2) { P = P2; bb = b2; stride = 9437184; }
    else      { P = P3; bb = b3; stride = 4194304; blk -= 4608; }
    size_t e0 = ((size_t)blk * 256 + threadIdx.x) * 8;
    int m = (int)(e0 >> 10);
    int n = (int)(e0 & 1023);
    float s[8] = {0.f};
#pragma unroll
    for (int k = 0; k < 4; ++k) {
        ushort8 a = *(const ushort8*)(P + (size_t)k * stride + e0);
#pragma unroll
        for (int i = 0; i < 8; ++i) s[i] += b2f(a[i]);
    }
    int crow;
    if (isL2) crow = (m / 144) * ROWS_TOT + 576 + (m % 144);
    else      crow = (m >> 6) * ROWS_TOT + 720 + (m & 63);
    ushort8 o;
#pragma unroll
    for (int i = 0; i < 8; ++i) o[i] = f2b(s[i] + bb[n + i]);
    *(ushort8*)(VAL + (size_t)crow * EE + n) = o;
}

// ---------------------------------------------------------------------------
// 2-phase double-buffered bf16 MFMA GEMM (128x128, 4 waves) — round-5 proven.
// ---------------------------------------------------------------------------
template<bool OB>
__global__ __launch_bounds__(256) void gemm2(
    const unsigned short* __restrict__ A, const unsigned short* __restrict__ Bw,
    const float* __restrict__ bias, void* __restrict__ Cv,
    int M, int N, int K)
{
    __shared__ unsigned short As[2][128 * 32];
    __shared__ unsigned short Bs[2][128 * 32];
    const int t = threadIdx.x;
    const int lane = t & 63;
    const int w = t >> 6;
    const int wm = w >> 1, wn = w & 1;

    int nwg = gridDim.x * gridDim.y;
    int bid = blockIdx.y * gridDim.x + blockIdx.x;
    int chunk = nwg >> 3;
    int swz = (bid & 7) * chunk + (bid >> 3);
    int by = swz / gridDim.x, bx = swz % gridDim.x;
    const int m0 = by * 128, n0 = bx * 128;

    f32x4 acc[4][4] = {};

    const int sr = lane >> 2;
    const int sc = lane & 3;
    const int scx = sc ^ ((sr >> 1) & 3);
    const unsigned short* gA0 = A + (size_t)(m0 + w * 32 + sr) * K + scx * 8;
    const unsigned short* gA1 = gA0 + (size_t)16 * K;
    const unsigned short* gB0 = Bw + (size_t)(n0 + w * 32 + sr) * K + scx * 8;
    const unsigned short* gB1 = gB0 + (size_t)16 * K;

    const int fr = lane & 15;
    const int kg = lane >> 4;
    const int kgx = kg ^ ((fr >> 1) & 3);

    const int nt = K >> 5;
    int cur = 0;

    auto STAGE = [&](int buf, int k0) {
        GLOAD16(gA0 + k0, &As[buf][w * 1024]);
        GLOAD16(gA1 + k0, &As[buf][w * 1024 + 512]);
        GLOAD16(gB0 + k0, &Bs[buf][w * 1024]);
        GLOAD16(gB1 + k0, &Bs[buf][w * 1024 + 512]);
    };

    STAGE(0, 0);
    __syncthreads();

    for (int tt = 0; tt < nt; ++tt) {
        if (tt + 1 < nt) STAGE(cur ^ 1, (tt + 1) * 32);
        const unsigned short* rdA = &As[cur][(wm * 64 + fr) * 32 + kgx * 8];
        const unsigned short* rdB = &Bs[cur][(wn * 64 + fr) * 32 + kgx * 8];
        bf16x8 af[4], bfr[4];
#pragma unroll
        for (int i = 0; i < 4; ++i) af[i]  = *(const bf16x8*)(rdA + i * 512);
#pragma unroll
        for (int j = 0; j < 4; ++j) bfr[j] = *(const bf16x8*)(rdB + j * 512);
#pragma unroll
        for (int i = 0; i < 4; ++i)
#pragma unroll
            for (int j = 0; j < 4; ++j)
                acc[i][j] = __builtin_amdgcn_mfma_f32_16x16x32_bf16(af[i], bfr[j], acc[i][j], 0, 0, 0);
        if (tt + 1 < nt) { __syncthreads(); cur ^= 1; }
    }

#pragma unroll
    for (int i = 0; i < 4; ++i) {
#pragma unroll
        for (int r = 0; r < 4; ++r) {
            int m = m0 + wm * 64 + i * 16 + kg * 4 + r;
#pragma unroll
            for (int j = 0; j < 4; ++j) {
                int n = n0 + wn * 64 + j * 16 + fr;
                float v = acc[i][j][r];
                if (bias) v += bias[n];
                if (OB) ((unsigned short*)Cv)[(size_t)m * N + n] = f2b(v);
                else    ((float*)Cv)[(size_t)m * N + n] = v;
            }
        }
    }
}

// all fp32->bf16 conversions in one dispatch:
// blocks [0,13824): features; then 512 each for vp_w / op_w / fin_w
__global__ void convall_kernel(const float* __restrict__ feat, unsigned short* __restrict__ FEAT,
                               const float* __restrict__ a, unsigned short* __restrict__ oa,
                               const float* __restrict__ b, unsigned short* __restrict__ ob,
                               const float* __restrict__ c, unsigned short* __restrict__ oc)
{
    int blk = blockIdx.x;
    const float* in; unsigned short* out;
    if (blk < 13824)       { in = feat; out = FEAT; }
    else if (blk < 14336)  { in = a; out = oa; blk -= 13824; }
    else if (blk < 14848)  { in = b; out = ob; blk -= 14336; }
    else                   { in = c; out = oc; blk -= 14848; }
    size_t i = ((size_t)blk * 256 + threadIdx.x) * 8;
    f4 x = *(const f4*)(in + i);
    f4 y = *(const f4*)(in + i + 4);
    ushort8 o;
    o[0] = f2b(x[0]); o[1] = f2b(x[1]); o[2] = f2b(x[2]); o[3] = f2b(x[3]);
    o[4] = f2b(y[0]); o[5] = f2b(y[1]); o[6] = f2b(y[2]); o[7] = f2b(y[3]);
    *(ushort8*)(out + i) = o;
}

// three transpose-converts (R=1024 for all) in one dispatch
__global__ void tconv3_kernel(const float* __restrict__ p1, const float* __restrict__ p2,
                              const float* __restrict__ p3, unsigned short* __restrict__ PT)
{
    __shared__ float tile[32][33];
    int bx = blockIdx.x;
    const float* in; unsigned short* out; int C;
    if (bx < 24)       { in = p1; out = PT;                C = 768; }
    else if (bx < 120) { in = p2; out = PT + 768  * 1024;  C = 3072; bx -= 24; }
    else               { in = p3; out = PT + 3840 * 1024;  C = 6912; bx -= 120; }
    const int R = 1024;
    int c0 = bx * 32, r0 = blockIdx.y * 32;
    int tx = threadIdx.x & 31, ty = threadIdx.x >> 5;
#pragma unroll
    for (int i = 0; i < 32; i += 8)
        tile[ty + i][tx] = in[(size_t)(r0 + ty + i) * C + c0 + tx];
    __syncthreads();
#pragma unroll
    for (int i = 0; i < 32; i += 8)
        out[(size_t)(c0 + ty + i) * R + r0 + tx] = f2b(tile[tx][ty + i]);
}

// three fused biases in one dispatch: b'[e] = vp_w[e,:]·pb + vp_b[e]
__global__ void fused_bias3_kernel(const float* __restrict__ vp_w, const float* __restrict__ vp_b,
                                   const float* __restrict__ pb1, const float* __restrict__ pb2,
                                   const float* __restrict__ pb3,
                                   float* __restrict__ o1, float* __restrict__ o2, float* __restrict__ o3)
{
    int blk = blockIdx.x;
    const float* pb; float* bout;
    if (blk < 256)      { pb = pb1; bout = o1; }
    else if (blk < 512) { pb = pb2; bout = o2; blk -= 256; }
    else                { pb = pb3; bout = o3; blk -= 512; }
    int e = blk * 4 + (threadIdx.x >> 6);
    int lane = threadIdx.x & 63;
    float s = 0.f;
    for (int k = lane; k < EE; k += 64) s += vp_w[(size_t)e * EE + k] * pb[k];
#pragma unroll
    for (int o = 32; o > 0; o >>= 1) s += __shfl_down(s, o, 64);
    if (lane == 0) bout[e] = s + vp_b[e];
}

// ---------------------------------------------------------------------------
// Query branch (batch-independent), fp64 — DO NOT ALTER (index-snap safety)
// ---------------------------------------------------------------------------
__global__ void rg1_kernel(const float* __restrict__ qe, const float* __restrict__ w,
                           const float* __restrict__ b, double* __restrict__ h0)
{
    int o = blockIdx.x * 4 + (threadIdx.x >> 6);
    int lane = threadIdx.x & 63;
    int q = o >> 10, n = o & 1023;
    double s = 0.0;
    for (int k = lane; k < EE; k += 64)
        s += (double)qe[q * EE + k] * (double)w[(size_t)n * EE + k];
#pragma unroll
    for (int off = 32; off > 0; off >>= 1) s += __shfl_down(s, off, 64);
    if (lane == 0) h0[o] = s + (double)b[n];
}

__global__ void ln_gelu_kernel(const double* __restrict__ h0, const float* __restrict__ g,
                               const float* __restrict__ bb, double* __restrict__ h)
{
    __shared__ double red[256];
    __shared__ double stats[2];
    int q = blockIdx.x, t = threadIdx.x;
    double x[4];
#pragma unroll
    for (int i = 0; i < 4; ++i) x[i] = h0[q * 1024 + t + i * 256];
    double s = x[0] + x[1] + x[2] + x[3];
    red[t] = s; __syncthreads();
    for (int o = 128; o; o >>= 1) { if (t < o) red[t] += red[t + o]; __syncthreads(); }
    if (t == 0) stats[0] = red[0] / 1024.0;
    __syncthreads();
    double mean = stats[0];
    double d = 0.0;
#pragma unroll
    for (int i = 0; i < 4; ++i) { double dd = x[i] - mean; d += dd * dd; }
    red[t] = d; __syncthreads();
    for (int o = 128; o; o >>= 1) { if (t < o) red[t] += red[t + o]; __syncthreads(); }
    if (t == 0) stats[1] = red[0] / 1024.0;
    __syncthreads();
    double inv = 1.0 / sqrt(stats[1] + 1e-5);
#pragma unroll
    for (int i = 0; i < 4; ++i) {
        int c = t + i * 256;
        double y = (x[i] - mean) * inv * (double)g[c] + (double)bb[c];
        h[q * 1024 + c] = y * 0.5 * (1.0 + erf(y * 0.70710678118654752440));
    }
}

__global__ void rp_kernel(const double* __restrict__ h, const float* __restrict__ w2,
                          const float* __restrict__ b2, double* __restrict__ rp)
{
    int o = blockIdx.x * 4 + (threadIdx.x >> 6);
    int lane = threadIdx.x & 63;
    int q = o >> 1, r = o & 1;
    double s = 0.0;
    for (int k = lane; k < EE; k += 64)
        s += h[q * 1024 + k] * (double)w2[r * 1024 + k];
#pragma unroll
    for (int off = 32; off > 0; off >>= 1) s += __shfl_down(s, off, 64);
    if (lane == 0) rp[o] = 1.0 / (1.0 + exp(-(s + (double)b2[r])));
}

__global__ void offidx_kernel(const float* __restrict__ qe, const float* __restrict__ so_w,
                              const float* __restrict__ so_b, const float* __restrict__ aw_w,
                              const float* __restrict__ aw_b, const double* __restrict__ rp,
                              float* __restrict__ awf, int* __restrict__ idxv)
{
    __shared__ double offv[128];
    __shared__ double logit[64];
    int q = blockIdx.x, t = threadIdx.x;
    if (t < 128) {
        double s = 0.0;
        for (int k = 0; k < EE; ++k) s += (double)qe[q * EE + k] * (double)so_w[(size_t)t * EE + k];
        offv[t] = s + (double)so_b[t];
    } else if (t < 192) {
        int n = t - 128;
        double s = 0.0;
        for (int k = 0; k < EE; ++k) s += (double)qe[q * EE + k] * (double)aw_w[(size_t)n * EE + k];
        logit[n] = s + (double)aw_b[n];
    }
    __syncthreads();
    if (t < 64) {
        int hh = t >> 2, p = t & 3;
        double l0 = logit[hh * 4 + 0], l1 = logit[hh * 4 + 1];
        double l2 = logit[hh * 4 + 2], l3 = logit[hh * 4 + 3];
        double m = fmax(fmax(l0, l1), fmax(l2, l3));
        double den = exp(l0 - m) + exp(l1 - m) + exp(l2 - m) + exp(l3 - m);
        awf[(q * 16 + hh) * 4 + p] = (float)(exp(logit[hh * 4 + p] - m) / den);
        const int Wss[3] = {24, 12, 8};
        const int starts[3] = {0, 576, 720};
        double ox = offv[(hh * 4 + p) * 2 + 0], oy = offv[(hh * 4 + p) * 2 + 1];
        double rx = rp[q * 2 + 0], ry = rp[q * 2 + 1];
#pragma unroll
        for (int l = 0; l < 3; ++l) {
            int Ws = Wss[l];
            double sx = rx + ox; sx = sx < 0.0 ? 0.0 : (sx > 1.0 ? 1.0 : sx);
            double sy = ry + oy; sy = sy < 0.0 ? 0.0 : (sy > 1.0 ? 1.0 : sy);
            int x0 = (int)floor(sx * (double)(Ws - 1));
            int y0 = (int)floor(sy * (double)(Ws - 1));
            idxv[((l * 64 + q) * 16 + hh) * 4 + p] = starts[l] + y0 * Ws + x0;
        }
    }
}

// out0[b,q,h,:] = sum_{l,p} aw[q,h,p] * value[b, idx[l,q,h,p], h, :]   (bf16)
__global__ void gather_kernel(const unsigned short* __restrict__ value, const float* __restrict__ awf,
                              const int* __restrict__ idxv, unsigned short* __restrict__ out0)
{
    int unit = blockIdx.x * 4 + (threadIdx.x >> 6);
    int lane = threadIdx.x & 63;
    int b = unit >> 10;
    int rem = unit & 1023;
    int q = rem >> 4, h = rem & 15;
    float acc = 0.f;
#pragma unroll
    for (int l = 0; l < 3; ++l)
#pragma unroll
        for (int p = 0; p < 4; ++p) {
            int row = idxv[((l * 64 + q) * 16 + h) * 4 + p];
            float wgt = awf[(q * 16 + h) * 4 + p];
            acc += wgt * b2f(value[((size_t)(b * ROWS_TOT + row)) * 1024 + h * 64 + lane]);
        }
    out0[((size_t)(b * 64 + q)) * 1024 + h * 64 + lane] = f2b(acc);
}

// fp32 LayerNorm over 1024, output bf16
__global__ void ln_bf16_kernel(const float* __restrict__ x, const float* __restrict__ g,
                               const float* __restrict__ bb, unsigned short* __restrict__ y)
{
    __shared__ float red[256];
    __shared__ float stats[2];
    int r = blockIdx.x, t = threadIdx.x;
    float v[4];
#pragma unroll
    for (int i = 0; i < 4; ++i) v[i] = x[(size_t)r * 1024 + t + i * 256];
    float s = v[0] + v[1] + v[2] + v[3];
    red[t] = s; __syncthreads();
    for (int o = 128; o; o >>= 1) { if (t < o) red[t] += red[t + o]; __syncthreads(); }
    if (t == 0) stats[0] = red[0] / 1024.f;
    __syncthreads();
    float mean = stats[0];
    float d = 0.f;
#pragma unroll
    for (int i = 0; i < 4; ++i) { float dd = v[i] - mean; d += dd * dd; }
    red[t] = d; __syncthreads();
    for (int o = 128; o; o >>= 1) { if (t < o) red[t] += red[t + o]; __syncthreads(); }
    if (t == 0) stats[1] = red[0] / 1024.f;
    __syncthreads();
    float inv = 1.f / sqrtf(stats[1] + 1e-5f);
#pragma unroll
    for (int i = 0; i < 4; ++i) {
        int c = t + i * 256;
        y[(size_t)r * 1024 + c] = f2b((v[i] - mean) * inv * g[c] + bb[c]);
    }
}

extern "C" void kernel_launch(void* const* d_in, const int* in_sizes, int n_in,
                              void* d_out, int out_size, void* d_ws, size_t ws_size,
                              hipStream_t stream)
{
    const float* features  = (const float*)d_in[0];
    const float* p1_w      = (const float*)d_in[1];
    const float* p1_b      = (const float*)d_in[2];
    const float* p2_w      = (const float*)d_in[3];
    const float* p2_b      = (const float*)d_in[4];
    const float* p3_w      = (const float*)d_in[5];
    const float* p3_b      = (const float*)d_in[6];
    const float* query_emb = (const float*)d_in[7];
    const float* rg_w1     = (const float*)d_in[8];
    const float* rg_b1     = (const float*)d_in[9];
    const float* rg_g      = (const float*)d_in[10];
    const float* rg_b      = (const float*)d_in[11];
    const float* rg_w2     = (const float*)d_in[12];
    const float* rg_b2     = (const float*)d_in[13];
    const float* so_w      = (const float*)d_in[14];
    const float* so_b      = (const float*)d_in[15];
    const float* aw_w      = (const float*)d_in[16];
    const float* aw_b      = (const float*)d_in[17];
    const float* vp_w      = (const float*)d_in[18];
    const float* vp_b      = (const float*)d_in[19];
    const float* op_w      = (const float*)d_in[20];
    const float* op_b      = (const float*)d_in[21];
    const float* fln_g     = (const float*)d_in[22];
    const float* fln_b     = (const float*)d_in[23];
    const float* fin_w     = (const float*)d_in[24];
    const float* fin_b     = (const float*)d_in[25];
    float* out = (float*)d_out;

    // ---- workspace layout (bytes) ----
    char* p = (char*)d_ws;
    unsigned short* FEAT = (unsigned short*)p; p += 56623104;   // bf16 [B*576,768]
    unsigned short* PT   = (unsigned short*)p; p += 22020096;   // [10752,1024] stacked p_w^T
    unsigned short* WW   = (unsigned short*)p; p += 22020096;   // [1024,10752] fused weights
    unsigned short* VPW  = (unsigned short*)p; p += 2097152;
    unsigned short* VAL  = (unsigned short*)p; p += 102760448;  // value bf16 [64*784,1024]
    char*           UNI  = p;                  p += 109051904;  // PART (value phase) / OUT1+OUT0+LNO (epilogue)
    unsigned short* OPW  = (unsigned short*)p; p += 2097152;
    unsigned short* FINW = (unsigned short*)p; p += 2097152;
    float* b1p  = (float*)p; p += 4096;
    float* b2p  = (float*)p; p += 4096;
    float* b3p  = (float*)p; p += 4096;
    float* awf  = (float*)p; p += 16384;
    int*   idxv = (int*)p;   p += 49152;
    double* h0  = (double*)p; p += 524288;
    double* hb  = (double*)p; p += 524288;
    double* rp  = (double*)p; p += 1024;

    // UNION region views (disjoint in time):
    unsigned short* PART_L2 = (unsigned short*)UNI;               // 4 x 9437184 elems
    unsigned short* PART_L3 = PART_L2 + 4 * 9437184;              // 4 x 4194304 elems
    float*          OUT1    = (float*)UNI;                        // 4096x1024 f32
    unsigned short* OUT0    = (unsigned short*)(UNI + 16777216);  // 4096x1024 bf16
    unsigned short* LNO     = (unsigned short*)(UNI + 25165824);  // 4096x1024 bf16

    dim3 blk(256);

    // ---- query branch (fp64, batch-independent) ----
    rg1_kernel<<<16384, blk, 0, stream>>>(query_emb, rg_w1, rg_b1, h0);
    ln_gelu_kernel<<<64, blk, 0, stream>>>(h0, rg_g, rg_b, hb);
    rp_kernel<<<32, blk, 0, stream>>>(hb, rg_w2, rg_b2, rp);
    offidx_kernel<<<64, blk, 0, stream>>>(query_emb, so_w, so_b, aw_w, aw_b, rp, awf, idxv);

    // ---- conversions (merged) ----
    convall_kernel<<<15360, blk, 0, stream>>>(features, FEAT, vp_w, VPW, op_w, OPW, fin_w, FINW);
    fused_bias3_kernel<<<768, blk, 0, stream>>>(vp_w, vp_b, p1_b, p2_b, p3_b, b1p, b2p, b3p);
    tconv3_kernel<<<dim3(336, 32), blk, 0, stream>>>(p1_w, p2_w, p3_w, PT);

    // ---- fused weights: WW[1024,10752] = VPW @ PT^T ----
    gemm2<true><<<dim3(84, 8), blk, 0, stream>>>(VPW, PT, nullptr, WW, 1024, WWN, 1024);

    // ---- value GEMMs: all 3 levels + split-K in ONE 1408-block dispatch ----
    gemm_val<<<1408, 512, 0, stream>>>(FEAT, WW, b1p, VAL, PART_L2, PART_L3);
    reduce_both_kernel<<<6656, blk, 0, stream>>>(PART_L2, PART_L3, b2p, b3p, VAL);

    // ---- deformable gather ----
    gather_kernel<<<16384, blk, 0, stream>>>(VAL, awf, idxv, OUT0);

    // ---- output projection + LN + final projection ----
    gemm2<false><<<dim3(8, 32), blk, 0, stream>>>(OUT0, OPW, op_b, OUT1, 4096, 1024, 1024);
    ln_bf16_kernel<<<4096, blk, 0, stream>>>(OUT1, fln_g, fln_b, LNO);
    gemm2<false><<<dim3(8, 32), blk, 0, stream>>>(LNO, FINW, fin_b, out, 4096, 1024, 1024);
}

// Round 12
// 545.387 us; speedup vs baseline: 1.1956x; 1.1956x over previous
//
#include <hip/hip_runtime.h>
#include <math.h>

#define EE 1024
#define ROWS_TOT 784   // 576 + 144 + 64
#define WWN 10752      // 768 + 3072 + 6912

typedef __attribute__((ext_vector_type(4))) float f4;
typedef __attribute__((ext_vector_type(4))) float f32x4;
typedef __attribute__((ext_vector_type(8))) __bf16 bf16x8;
typedef __attribute__((ext_vector_type(8))) unsigned short ushort8;

__device__ __forceinline__ unsigned short f2b(float x) {
    unsigned int u = __float_as_uint(x);
    unsigned int r = (u + 0x7fffu + ((u >> 16) & 1u)) >> 16;
    return (unsigned short)r;
}
__device__ __forceinline__ float b2f(unsigned short u) {
    unsigned int v = ((unsigned int)u) << 16;
    return __uint_as_float(v);
}

#define GLOAD16(g, l) __builtin_amdgcn_global_load_lds( \
    (const __attribute__((address_space(1))) unsigned int*)(g), \
    (__attribute__((address_space(3))) unsigned int*)(l), 16, 0, 0)

// ---------------------------------------------------------------------------
// 256x256 value GEMM, BK=64, 8 waves (2m x 4n), per-wave 128x64.
// LDS 128KB dbuf -> 1 block/CU. Round-10 proven (best measured: 118us/dispatch).
// Swizzle: 128B rows = 8 x 16B slots; slot s of row r holds global chunk
// s ^ (r&7); reads use (kk*4+kg) ^ (fr&7). T3/T4/T5 schedule.
// SPLIT: write bf16 partial (no bias) for K-chunk blockIdx.z.
// ---------------------------------------------------------------------------
template<int MODE, bool SPLIT>
__global__ __launch_bounds__(512, 2) void gemm256(
    const unsigned short* __restrict__ FEAT, const unsigned short* __restrict__ WW,
    const float* __restrict__ bias, void* __restrict__ outp,
    int ktCount, int partStride)
{
    constexpr int gw = (MODE == 1) ? 24 : (MODE == 2 ? 12 : 8);
    constexpr int Rl = gw * gw;                                   // 576/144/64
    constexpr int colOff = (MODE == 1) ? 0 : (MODE == 2 ? 768 : 3840);
    constexpr int rowOff = (MODE == 1) ? 0 : (MODE == 2 ? 576 : 720);

    __shared__ unsigned short As[2][256 * 64];   // 32KB each
    __shared__ unsigned short Bs[2][256 * 64];

    const int t = threadIdx.x;
    const int lane = t & 63;
    const int w = t >> 6;                // 0..7
    const int wm = w >> 2;               // 0..1  (128-row half)
    const int wn = w & 3;                // 0..3  (64-col quarter)

    // bijective XCD swizzle over x*y (always %8==0); z untouched
    int nwg = gridDim.x * gridDim.y;
    int bid = blockIdx.y * gridDim.x + blockIdx.x;
    int chunk = nwg >> 3;
    int swz = (bid & 7) * chunk + (bid >> 3);
    int by = swz / gridDim.x, bx = swz % gridDim.x;
    const int m0 = by * 256, n0 = bx * 256;
    const int ktBase = blockIdx.z * ktCount;

    f32x4 acc[8][4] = {};

    // ---- staging roles: 4 gloads per operand per wave (32 rows x 128B) ----
    const int srow = lane >> 3;                  // 0..7 row within 8-row gload
    const int sseg = lane & 7;                   // stored 16B slot 0..7
    const int sgx  = sseg ^ srow;                // pre-swizzled global chunk
    int rbA[4];
#pragma unroll
    for (int g = 0; g < 4; ++g) {
        int gr = m0 + w * 32 + g * 8 + srow;
        if (MODE == 1) rbA[g] = gr;
        else {
            int b_ = gr / Rl, rl = gr - b_ * Rl;
            rbA[g] = b_ * 576 + (MODE * (rl / gw)) * 24 + MODE * (rl % gw);
        }
    }
    const unsigned short* gBbase = WW + (size_t)(n0 + w * 32 + srow) * WWN + colOff + sgx * 8;

    // ---- fragment-read roles ----
    const int fr = lane & 15;
    const int kg = lane >> 4;
    const int kgx0 = kg ^ (fr & 7);              // kk=0 slot
    const int kgx1 = kgx0 ^ 4;                   // kk=1 slot
    const int aOff0 = (wm * 128 + fr) * 64 + kgx0 * 8;
    const int aOff1 = (wm * 128 + fr) * 64 + kgx1 * 8;
    const int bOff0 = (wn * 64 + fr) * 64 + kgx0 * 8;
    const int bOff1 = (wn * 64 + fr) * 64 + kgx1 * 8;

    auto STAGE = [&](int buf, int ktl) {
        int kt = ktBase + ktl;                   // BK=64 tile index
        int s = kt / 12;                         // which 768-chunk of K
        int within = (kt - s * 12) * 64;         // + sgx*8 stays within the chunk
        int add = 0;
        if (MODE == 2)      add = (s >> 1) * 24 + (s & 1);
        else if (MODE == 3) { int di = s / 3; add = di * 24 + (s - 3 * di); }
#pragma unroll
        for (int g = 0; g < 4; ++g)
            GLOAD16(FEAT + (size_t)(rbA[g] + add) * 768 + within + sgx * 8,
                    &As[buf][(w * 32 + g * 8) * 64]);
#pragma unroll
        for (int g = 0; g < 4; ++g)
            GLOAD16(gBbase + (size_t)(g * 8) * WWN + (size_t)kt * 64,
                    &Bs[buf][(w * 32 + g * 8) * 64]);
    };

    const int nt = ktCount;
    int cur = 0;
    STAGE(0, 0);

    for (int tt = 0; tt < nt; ++tt) {
        // boundary: wait only for the stage issued one full iteration ago
        asm volatile("s_waitcnt vmcnt(0)" ::: "memory");
        __builtin_amdgcn_s_barrier();
        __builtin_amdgcn_sched_barrier(0);

        if (tt + 1 < nt) STAGE(cur ^ 1, tt + 1);        // in flight across phases
        __builtin_amdgcn_sched_barrier(0);

        // ---- phase kk=0: K elems [0,32), 32 MFMA ----
        {
            bf16x8 bf[4], af[8];
#pragma unroll
            for (int j = 0; j < 4; ++j) bf[j] = *(const bf16x8*)(&Bs[cur][bOff0] + j * 1024);
#pragma unroll
            for (int i = 0; i < 8; ++i) af[i] = *(const bf16x8*)(&As[cur][aOff0] + i * 1024);
            __builtin_amdgcn_s_setprio(1);
#pragma unroll
            for (int i = 0; i < 8; ++i)
#pragma unroll
                for (int j = 0; j < 4; ++j)
                    acc[i][j] = __builtin_amdgcn_mfma_f32_16x16x32_bf16(af[i], bf[j], acc[i][j], 0, 0, 0);
            __builtin_amdgcn_s_setprio(0);
        }
        __builtin_amdgcn_s_barrier();
        __builtin_amdgcn_sched_barrier(0);

        // ---- phase kk=1: K elems [32,64), 32 MFMA ----
        {
            bf16x8 bf[4], af[8];
#pragma unroll
            for (int j = 0; j < 4; ++j) bf[j] = *(const bf16x8*)(&Bs[cur][bOff1] + j * 1024);
#pragma unroll
            for (int i = 0; i < 8; ++i) af[i] = *(const bf16x8*)(&As[cur][aOff1] + i * 1024);
            __builtin_amdgcn_s_setprio(1);
#pragma unroll
            for (int i = 0; i < 8; ++i)
#pragma unroll
                for (int j = 0; j < 4; ++j)
                    acc[i][j] = __builtin_amdgcn_mfma_f32_16x16x32_bf16(af[i], bf[j], acc[i][j], 0, 0, 0);
            __builtin_amdgcn_s_setprio(0);
        }
        cur ^= 1;
    }

#pragma unroll
    for (int i = 0; i < 8; ++i) {
#pragma unroll
        for (int r = 0; r < 4; ++r) {
            int m = m0 + wm * 128 + i * 16 + kg * 4 + r;   // local level row
#pragma unroll
            for (int j = 0; j < 4; ++j) {
                int n = n0 + wn * 64 + j * 16 + fr;
                if (SPLIT) {
                    unsigned short* P = (unsigned short*)outp + (size_t)blockIdx.z * partStride;
                    P[(size_t)m * EE + n] = f2b(acc[i][j][r]);
                } else {
                    int b_o = m / Rl, rl_o = m - b_o * Rl;
                    int crow = b_o * ROWS_TOT + rowOff + rl_o;
                    ((unsigned short*)outp)[(size_t)crow * EE + n] = f2b(acc[i][j][r] + bias[n]);
                }
            }
        }
    }
}

// merged reduce (round-11 proven): blocks [0,4608) = L2 (4 slices, rows
// 576..719/batch); [4608,6656) = L3 (4 slices, rows 720..783/batch)
__global__ void reduce_both_kernel(const unsigned short* __restrict__ P2, const unsigned short* __restrict__ P3,
                                   const float* __restrict__ b2, const float* __restrict__ b3,
                                   unsigned short* __restrict__ VAL)
{
    int blk = blockIdx.x;
    const unsigned short* P;
    const float* bb;
    size_t stride;
    int isL2 = (blk < 4608);
    if (isL2) { P = P2; bb = b2; stride = 9437184; }
    else      { P = P3; bb = b3; stride = 4194304; blk -= 4608; }
    size_t e0 = ((size_t)blk * 256 + threadIdx.x) * 8;
    int m = (int)(e0 >> 10);
    int n = (int)(e0 & 1023);
    float s[8] = {0.f};
#pragma unroll
    for (int k = 0; k < 4; ++k) {
        ushort8 a = *(const ushort8*)(P + (size_t)k * stride + e0);
#pragma unroll
        for (int i = 0; i < 8; ++i) s[i] += b2f(a[i]);
    }
    int crow;
    if (isL2) crow = (m / 144) * ROWS_TOT + 576 + (m % 144);
    else      crow = (m >> 6) * ROWS_TOT + 720 + (m & 63);
    ushort8 o;
#pragma unroll
    for (int i = 0; i < 8; ++i) o[i] = f2b(s[i] + bb[n + i]);
    *(ushort8*)(VAL + (size_t)crow * EE + n) = o;
}

// ---------------------------------------------------------------------------
// 2-phase double-buffered bf16 MFMA GEMM (128x128, 4 waves) — round-5 proven.
// ---------------------------------------------------------------------------
template<bool OB>
__global__ __launch_bounds__(256) void gemm2(
    const unsigned short* __restrict__ A, const unsigned short* __restrict__ Bw,
    const float* __restrict__ bias, void* __restrict__ Cv,
    int M, int N, int K)
{
    __shared__ unsigned short As[2][128 * 32];
    __shared__ unsigned short Bs[2][128 * 32];
    const int t = threadIdx.x;
    const int lane = t & 63;
    const int w = t >> 6;
    const int wm = w >> 1, wn = w & 1;

    int nwg = gridDim.x * gridDim.y;
    int bid = blockIdx.y * gridDim.x + blockIdx.x;
    int chunk = nwg >> 3;
    int swz = (bid & 7) * chunk + (bid >> 3);
    int by = swz / gridDim.x, bx = swz % gridDim.x;
    const int m0 = by * 128, n0 = bx * 128;

    f32x4 acc[4][4] = {};

    const int sr = lane >> 2;
    const int sc = lane & 3;
    const int scx = sc ^ ((sr >> 1) & 3);
    const unsigned short* gA0 = A + (size_t)(m0 + w * 32 + sr) * K + scx * 8;
    const unsigned short* gA1 = gA0 + (size_t)16 * K;
    const unsigned short* gB0 = Bw + (size_t)(n0 + w * 32 + sr) * K + scx * 8;
    const unsigned short* gB1 = gB0 + (size_t)16 * K;

    const int fr = lane & 15;
    const int kg = lane >> 4;
    const int kgx = kg ^ ((fr >> 1) & 3);

    const int nt = K >> 5;
    int cur = 0;

    auto STAGE = [&](int buf, int k0) {
        GLOAD16(gA0 + k0, &As[buf][w * 1024]);
        GLOAD16(gA1 + k0, &As[buf][w * 1024 + 512]);
        GLOAD16(gB0 + k0, &Bs[buf][w * 1024]);
        GLOAD16(gB1 + k0, &Bs[buf][w * 1024 + 512]);
    };

    STAGE(0, 0);
    __syncthreads();

    for (int tt = 0; tt < nt; ++tt) {
        if (tt + 1 < nt) STAGE(cur ^ 1, (tt + 1) * 32);
        const unsigned short* rdA = &As[cur][(wm * 64 + fr) * 32 + kgx * 8];
        const unsigned short* rdB = &Bs[cur][(wn * 64 + fr) * 32 + kgx * 8];
        bf16x8 af[4], bfr[4];
#pragma unroll
        for (int i = 0; i < 4; ++i) af[i]  = *(const bf16x8*)(rdA + i * 512);
#pragma unroll
        for (int j = 0; j < 4; ++j) bfr[j] = *(const bf16x8*)(rdB + j * 512);
#pragma unroll
        for (int i = 0; i < 4; ++i)
#pragma unroll
            for (int j = 0; j < 4; ++j)
                acc[i][j] = __builtin_amdgcn_mfma_f32_16x16x32_bf16(af[i], bfr[j], acc[i][j], 0, 0, 0);
        if (tt + 1 < nt) { __syncthreads(); cur ^= 1; }
    }

#pragma unroll
    for (int i = 0; i < 4; ++i) {
#pragma unroll
        for (int r = 0; r < 4; ++r) {
            int m = m0 + wm * 64 + i * 16 + kg * 4 + r;
#pragma unroll
            for (int j = 0; j < 4; ++j) {
                int n = n0 + wn * 64 + j * 16 + fr;
                float v = acc[i][j][r];
                if (bias) v += bias[n];
                if (OB) ((unsigned short*)Cv)[(size_t)m * N + n] = f2b(v);
                else    ((float*)Cv)[(size_t)m * N + n] = v;
            }
        }
    }
}

// ---------------------------------------------------------------------------
// MERGED prep dispatch (independent producers, disjoint outputs):
//   blocks [0,13824): features fp32->bf16
//   [13824,15360): vp_w/op_w/fin_w fp32->bf16 (512 each)
//   [15360,26112): transpose-convert p1/p2/p3 -> PT (flattened 336x32)
//   [26112,26880): fused biases b1p/b2p/b3p
// ---------------------------------------------------------------------------
__global__ void prep_kernel(const float* __restrict__ feat, unsigned short* __restrict__ FEAT,
                            const float* __restrict__ vpw, unsigned short* __restrict__ VPW,
                            const float* __restrict__ opw, unsigned short* __restrict__ OPW,
                            const float* __restrict__ finw, unsigned short* __restrict__ FINW,
                            const float* __restrict__ p1, const float* __restrict__ p2,
                            const float* __restrict__ p3, unsigned short* __restrict__ PT,
                            const float* __restrict__ vp_b,
                            const float* __restrict__ pb1, const float* __restrict__ pb2,
                            const float* __restrict__ pb3,
                            float* __restrict__ o1, float* __restrict__ o2, float* __restrict__ o3)
{
    __shared__ float tile[32][33];
    int blk = blockIdx.x;
    if (blk < 15360) {
        // ---- straight fp32 -> bf16 conversions ----
        const float* in; unsigned short* out;
        if (blk < 13824)       { in = feat; out = FEAT; }
        else if (blk < 14336)  { in = vpw;  out = VPW;  blk -= 13824; }
        else if (blk < 14848)  { in = opw;  out = OPW;  blk -= 14336; }
        else                   { in = finw; out = FINW; blk -= 14848; }
        size_t i = ((size_t)blk * 256 + threadIdx.x) * 8;
        f4 x = *(const f4*)(in + i);
        f4 y = *(const f4*)(in + i + 4);
        ushort8 o;
        o[0] = f2b(x[0]); o[1] = f2b(x[1]); o[2] = f2b(x[2]); o[3] = f2b(x[3]);
        o[4] = f2b(y[0]); o[5] = f2b(y[1]); o[6] = f2b(y[2]); o[7] = f2b(y[3]);
        *(ushort8*)(out + i) = o;
    } else if (blk < 26112) {
        // ---- transpose-convert: flattened (336 x, 32 y) ----
        int fl = blk - 15360;
        int bx = fl % 336, byy = fl / 336;
        const float* in; unsigned short* out; int C;
        if (bx < 24)       { in = p1; out = PT;                C = 768; }
        else if (bx < 120) { in = p2; out = PT + 768  * 1024;  C = 3072; bx -= 24; }
        else               { in = p3; out = PT + 3840 * 1024;  C = 6912; bx -= 120; }
        const int R = 1024;
        int c0 = bx * 32, r0 = byy * 32;
        int tx = threadIdx.x & 31, ty = threadIdx.x >> 5;
#pragma unroll
        for (int i = 0; i < 32; i += 8)
            tile[ty + i][tx] = in[(size_t)(r0 + ty + i) * C + c0 + tx];
        __syncthreads();
#pragma unroll
        for (int i = 0; i < 32; i += 8)
            out[(size_t)(c0 + ty + i) * R + r0 + tx] = f2b(tile[tx][ty + i]);
    } else {
        // ---- fused biases: b'[e] = vp_w[e,:]·pb + vp_b[e] ----
        int b = blk - 26112;
        const float* pb; float* bout;
        if (b < 256)      { pb = pb1; bout = o1; }
        else if (b < 512) { pb = pb2; bout = o2; b -= 256; }
        else              { pb = pb3; bout = o3; b -= 512; }
        int e = b * 4 + (threadIdx.x >> 6);
        int lane = threadIdx.x & 63;
        float s = 0.f;
        for (int k = lane; k < EE; k += 64) s += vpw[(size_t)e * EE + k] * pb[k];
#pragma unroll
        for (int o = 32; o > 0; o >>= 1) s += __shfl_down(s, o, 64);
        if (lane == 0) bout[e] = s + vp_b[e];
    }
}

// ---------------------------------------------------------------------------
// Query branch (batch-independent), fp64 — DO NOT ALTER (index-snap safety)
// ---------------------------------------------------------------------------
__global__ void rg1_kernel(const float* __restrict__ qe, const float* __restrict__ w,
                           const float* __restrict__ b, double* __restrict__ h0)
{
    int o = blockIdx.x * 4 + (threadIdx.x >> 6);
    int lane = threadIdx.x & 63;
    int q = o >> 10, n = o & 1023;
    double s = 0.0;
    for (int k = lane; k < EE; k += 64)
        s += (double)qe[q * EE + k] * (double)w[(size_t)n * EE + k];
#pragma unroll
    for (int off = 32; off > 0; off >>= 1) s += __shfl_down(s, off, 64);
    if (lane == 0) h0[o] = s + (double)b[n];
}

__global__ void ln_gelu_kernel(const double* __restrict__ h0, const float* __restrict__ g,
                               const float* __restrict__ bb, double* __restrict__ h)
{
    __shared__ double red[256];
    __shared__ double stats[2];
    int q = blockIdx.x, t = threadIdx.x;
    double x[4];
#pragma unroll
    for (int i = 0; i < 4; ++i) x[i] = h0[q * 1024 + t + i * 256];
    double s = x[0] + x[1] + x[2] + x[3];
    red[t] = s; __syncthreads();
    for (int o = 128; o; o >>= 1) { if (t < o) red[t] += red[t + o]; __syncthreads(); }
    if (t == 0) stats[0] = red[0] / 1024.0;
    __syncthreads();
    double mean = stats[0];
    double d = 0.0;
#pragma unroll
    for (int i = 0; i < 4; ++i) { double dd = x[i] - mean; d += dd * dd; }
    red[t] = d; __syncthreads();
    for (int o = 128; o; o >>= 1) { if (t < o) red[t] += red[t + o]; __syncthreads(); }
    if (t == 0) stats[1] = red[0] / 1024.0;
    __syncthreads();
    double inv = 1.0 / sqrt(stats[1] + 1e-5);
#pragma unroll
    for (int i = 0; i < 4; ++i) {
        int c = t + i * 256;
        double y = (x[i] - mean) * inv * (double)g[c] + (double)bb[c];
        h[q * 1024 + c] = y * 0.5 * (1.0 + erf(y * 0.70710678118654752440));
    }
}

__global__ void rp_kernel(const double* __restrict__ h, const float* __restrict__ w2,
                          const float* __restrict__ b2, double* __restrict__ rp)
{
    int o = blockIdx.x * 4 + (threadIdx.x >> 6);
    int lane = threadIdx.x & 63;
    int q = o >> 1, r = o & 1;
    double s = 0.0;
    for (int k = lane; k < EE; k += 64)
        s += h[q * 1024 + k] * (double)w2[r * 1024 + k];
#pragma unroll
    for (int off = 32; off > 0; off >>= 1) s += __shfl_down(s, off, 64);
    if (lane == 0) rp[o] = 1.0 / (1.0 + exp(-(s + (double)b2[r])));
}

__global__ void offidx_kernel(const float* __restrict__ qe, const float* __restrict__ so_w,
                              const float* __restrict__ so_b, const float* __restrict__ aw_w,
                              const float* __restrict__ aw_b, const double* __restrict__ rp,
                              float* __restrict__ awf, int* __restrict__ idxv)
{
    __shared__ double offv[128];
    __shared__ double logit[64];
    int q = blockIdx.x, t = threadIdx.x;
    if (t < 128) {
        double s = 0.0;
        for (int k = 0; k < EE; ++k) s += (double)qe[q * EE + k] * (double)so_w[(size_t)t * EE + k];
        offv[t] = s + (double)so_b[t];
    } else if (t < 192) {
        int n = t - 128;
        double s = 0.0;
        for (int k = 0; k < EE; ++k) s += (double)qe[q * EE + k] * (double)aw_w[(size_t)n * EE + k];
        logit[n] = s + (double)aw_b[n];
    }
    __syncthreads();
    if (t < 64) {
        int hh = t >> 2, p = t & 3;
        double l0 = logit[hh * 4 + 0], l1 = logit[hh * 4 + 1];
        double l2 = logit[hh * 4 + 2], l3 = logit[hh * 4 + 3];
        double m = fmax(fmax(l0, l1), fmax(l2, l3));
        double den = exp(l0 - m) + exp(l1 - m) + exp(l2 - m) + exp(l3 - m);
        awf[(q * 16 + hh) * 4 + p] = (float)(exp(logit[hh * 4 + p] - m) / den);
        const int Wss[3] = {24, 12, 8};
        const int starts[3] = {0, 576, 720};
        double ox = offv[(hh * 4 + p) * 2 + 0], oy = offv[(hh * 4 + p) * 2 + 1];
        double rx = rp[q * 2 + 0], ry = rp[q * 2 + 1];
#pragma unroll
        for (int l = 0; l < 3; ++l) {
            int Ws = Wss[l];
            double sx = rx + ox; sx = sx < 0.0 ? 0.0 : (sx > 1.0 ? 1.0 : sx);
            double sy = ry + oy; sy = sy < 0.0 ? 0.0 : (sy > 1.0 ? 1.0 : sy);
            int x0 = (int)floor(sx * (double)(Ws - 1));
            int y0 = (int)floor(sy * (double)(Ws - 1));
            idxv[((l * 64 + q) * 16 + hh) * 4 + p] = starts[l] + y0 * Ws + x0;
        }
    }
}

// out0[b,q,h,:] = sum_{l,p} aw[q,h,p] * value[b, idx[l,q,h,p], h, :]   (bf16)
__global__ void gather_kernel(const unsigned short* __restrict__ value, const float* __restrict__ awf,
                              const int* __restrict__ idxv, unsigned short* __restrict__ out0)
{
    int unit = blockIdx.x * 4 + (threadIdx.x >> 6);
    int lane = threadIdx.x & 63;
    int b = unit >> 10;
    int rem = unit & 1023;
    int q = rem >> 4, h = rem & 15;
    float acc = 0.f;
#pragma unroll
    for (int l = 0; l < 3; ++l)
#pragma unroll
        for (int p = 0; p < 4; ++p) {
            int row = idxv[((l * 64 + q) * 16 + h) * 4 + p];
            float wgt = awf[(q * 16 + h) * 4 + p];
            acc += wgt * b2f(value[((size_t)(b * ROWS_TOT + row)) * 1024 + h * 64 + lane]);
        }
    out0[((size_t)(b * 64 + q)) * 1024 + h * 64 + lane] = f2b(acc);
}

// fp32 LayerNorm over 1024, output bf16
__global__ void ln_bf16_kernel(const float* __restrict__ x, const float* __restrict__ g,
                               const float* __restrict__ bb, unsigned short* __restrict__ y)
{
    __shared__ float red[256];
    __shared__ float stats[2];
    int r = blockIdx.x, t = threadIdx.x;
    float v[4];
#pragma unroll
    for (int i = 0; i < 4; ++i) v[i] = x[(size_t)r * 1024 + t + i * 256];
    float s = v[0] + v[1] + v[2] + v[3];
    red[t] = s; __syncthreads();
    for (int o = 128; o; o >>= 1) { if (t < o) red[t] += red[t + o]; __syncthreads(); }
    if (t == 0) stats[0] = red[0] / 1024.f;
    __syncthreads();
    float mean = stats[0];
    float d = 0.f;
#pragma unroll
    for (int i = 0; i < 4; ++i) { float dd = v[i] - mean; d += dd * dd; }
    red[t] = d; __syncthreads();
    for (int o = 128; o; o >>= 1) { if (t < o) red[t] += red[t + o]; __syncthreads(); }
    if (t == 0) stats[1] = red[0] / 1024.f;
    __syncthreads();
    float inv = 1.f / sqrtf(stats[1] + 1e-5f);
#pragma unroll
    for (int i = 0; i < 4; ++i) {
        int c = t + i * 256;
        y[(size_t)r * 1024 + c] = f2b((v[i] - mean) * inv * g[c] + bb[c]);
    }
}

extern "C" void kernel_launch(void* const* d_in, const int* in_sizes, int n_in,
                              void* d_out, int out_size, void* d_ws, size_t ws_size,
                              hipStream_t stream)
{
    const float* features  = (const float*)d_in[0];
    const float* p1_w      = (const float*)d_in[1];
    const float* p1_b      = (const float*)d_in[2];
    const float* p2_w      = (const float*)d_in[3];
    const float* p2_b      = (const float*)d_in[4];
    const float* p3_w      = (const float*)d_in[5];
    const float* p3_b      = (const float*)d_in[6];
    const float* query_emb = (const float*)d_in[7];
    const float* rg_w1     = (const float*)d_in[8];
    const float* rg_b1     = (const float*)d_in[9];
    const float* rg_g      = (const float*)d_in[10];
    const float* rg_b      = (const float*)d_in[11];
    const float* rg_w2     = (const float*)d_in[12];
    const float* rg_b2     = (const float*)d_in[13];
    const float* so_w      = (const float*)d_in[14];
    const float* so_b      = (const float*)d_in[15];
    const float* aw_w      = (const float*)d_in[16];
    const float* aw_b      = (const float*)d_in[17];
    const float* vp_w      = (const float*)d_in[18];
    const float* vp_b      = (const float*)d_in[19];
    const float* op_w      = (const float*)d_in[20];
    const float* op_b      = (const float*)d_in[21];
    const float* fln_g     = (const float*)d_in[22];
    const float* fln_b     = (const float*)d_in[23];
    const float* fin_w     = (const float*)d_in[24];
    const float* fin_b     = (const float*)d_in[25];
    float* out = (float*)d_out;

    // ---- workspace layout (bytes) ----
    char* p = (char*)d_ws;
    unsigned short* FEAT = (unsigned short*)p; p += 56623104;   // bf16 [B*576,768]
    unsigned short* PT   = (unsigned short*)p; p += 22020096;   // [10752,1024] stacked p_w^T
    unsigned short* WW   = (unsigned short*)p; p += 22020096;   // [1024,10752] fused weights
    unsigned short* VPW  = (unsigned short*)p; p += 2097152;
    unsigned short* VAL  = (unsigned short*)p; p += 102760448;  // value bf16 [64*784,1024]
    unsigned short* PART = (unsigned short*)p; p += 75497472;   // bf16 partials (L2: 4x9437184)
    float*          OUT1 = (float*)p;          p += 16777216;   // fp32 [4096,1024]
    unsigned short* OUT0 = (unsigned short*)p; p += 8388608;
    unsigned short* LNO  = (unsigned short*)p; p += 8388608;
    unsigned short* OPW  = (unsigned short*)p; p += 2097152;
    unsigned short* FINW = (unsigned short*)p; p += 2097152;
    float* b1p  = (float*)p; p += 4096;
    float* b2p  = (float*)p; p += 4096;
    float* b3p  = (float*)p; p += 4096;
    float* awf  = (float*)p; p += 16384;
    int*   idxv = (int*)p;   p += 49152;
    double* h0  = (double*)p; p += 524288;
    double* hb  = (double*)p; p += 524288;
    double* rp  = (double*)p; p += 1024;

    dim3 blk(256);

    // ---- query branch (fp64, batch-independent) ----
    rg1_kernel<<<16384, blk, 0, stream>>>(query_emb, rg_w1, rg_b1, h0);
    ln_gelu_kernel<<<64, blk, 0, stream>>>(h0, rg_g, rg_b, hb);
    rp_kernel<<<32, blk, 0, stream>>>(hb, rg_w2, rg_b2, rp);
    offidx_kernel<<<64, blk, 0, stream>>>(query_emb, so_w, so_b, aw_w, aw_b, rp, awf, idxv);

    // ---- merged prep: all conversions + transposes + fused biases ----
    prep_kernel<<<26880, blk, 0, stream>>>(features, FEAT, vp_w, VPW, op_w, OPW, fin_w, FINW,
                                           p1_w, p2_w, p3_w, PT,
                                           vp_b, p1_b, p2_b, p3_b, b1p, b2p, b3p);

    // ---- fused weights: WW[1024,10752] = VPW @ PT^T ----
    gemm2<true><<<dim3(84, 8), blk, 0, stream>>>(VPW, PT, nullptr, WW, 1024, WWN, 1024);

    // ---- value GEMMs, 256x256 BK=64 tiles, per level (round-10 proven) ----
    gemm256<1, false><<<dim3(4, 144),    512, 0, stream>>>(FEAT, WW, b1p, VAL, 12, 0);
    gemm256<2, true><<<dim3(4, 36, 4),   512, 0, stream>>>(FEAT, WW, nullptr, PART, 12, 9437184);
    gemm256<3, true><<<dim3(4, 16, 4),   512, 0, stream>>>(FEAT, WW, nullptr, PART + 4 * 9437184, 27, 4194304);
    reduce_both_kernel<<<6656, blk, 0, stream>>>(PART, PART + 4 * 9437184, b2p, b3p, VAL);

    // ---- deformable gather ----
    gather_kernel<<<16384, blk, 0, stream>>>(VAL, awf, idxv, OUT0);

    // ---- output projection + LN + final projection ----
    gemm2<false><<<dim3(8, 32), blk, 0, stream>>>(OUT0, OPW, op_b, OUT1, 4096, 1024, 1024);
    ln_bf16_kernel<<<4096, blk, 0, stream>>>(OUT1, fln_g, fln_b, LNO);
    gemm2<false><<<dim3(8, 32), blk, 0, stream>>>(LNO, FINW, fin_b, out, 4096, 1024, 1024);
}

// Round 13
// 517.203 us; speedup vs baseline: 1.2607x; 1.0545x over previous
//
#include <hip/hip_runtime.h>
#include <math.h>

#define EE 1024
#define ROWS_TOT 784   // 576 + 144 + 64
#define WWN 10752      // 768 + 3072 + 6912

typedef __attribute__((ext_vector_type(4))) float f4;
typedef __attribute__((ext_vector_type(4))) float f32x4;
typedef __attribute__((ext_vector_type(8))) __bf16 bf16x8;
typedef __attribute__((ext_vector_type(8))) unsigned short ushort8;

__device__ __forceinline__ unsigned short f2b(float x) {
    unsigned int u = __float_as_uint(x);
    unsigned int r = (u + 0x7fffu + ((u >> 16) & 1u)) >> 16;
    return (unsigned short)r;
}
__device__ __forceinline__ float b2f(unsigned short u) {
    unsigned int v = ((unsigned int)u) << 16;
    return __uint_as_float(v);
}

#define GLOAD16(g, l) __builtin_amdgcn_global_load_lds( \
    (const __attribute__((address_space(1))) unsigned int*)(g), \
    (__attribute__((address_space(3))) unsigned int*)(l), 16, 0, 0)

// ---------------------------------------------------------------------------
// 256x256 value GEMM, BK=64, 8 waves (2m x 4n), per-wave 128x64.
// LDS 128KB dbuf -> 1 block/CU. Round-10/12 proven (best measured).
// Swizzle: 128B rows = 8 x 16B slots; slot s of row r holds global chunk
// s ^ (r&7); reads use (kk*4+kg) ^ (fr&7). T3/T4/T5 schedule.
// SPLIT: write bf16 partial (no bias) for K-chunk blockIdx.z.
// ---------------------------------------------------------------------------
template<int MODE, bool SPLIT>
__global__ __launch_bounds__(512, 2) void gemm256(
    const unsigned short* __restrict__ FEAT, const unsigned short* __restrict__ WW,
    const float* __restrict__ bias, void* __restrict__ outp,
    int ktCount, int partStride)
{
    constexpr int gw = (MODE == 1) ? 24 : (MODE == 2 ? 12 : 8);
    constexpr int Rl = gw * gw;                                   // 576/144/64
    constexpr int colOff = (MODE == 1) ? 0 : (MODE == 2 ? 768 : 3840);
    constexpr int rowOff = (MODE == 1) ? 0 : (MODE == 2 ? 576 : 720);

    __shared__ unsigned short As[2][256 * 64];   // 32KB each
    __shared__ unsigned short Bs[2][256 * 64];

    const int t = threadIdx.x;
    const int lane = t & 63;
    const int w = t >> 6;                // 0..7
    const int wm = w >> 2;               // 0..1  (128-row half)
    const int wn = w & 3;                // 0..3  (64-col quarter)

    // bijective XCD swizzle over x*y (always %8==0); z untouched
    int nwg = gridDim.x * gridDim.y;
    int bid = blockIdx.y * gridDim.x + blockIdx.x;
    int chunk = nwg >> 3;
    int swz = (bid & 7) * chunk + (bid >> 3);
    int by = swz / gridDim.x, bx = swz % gridDim.x;
    const int m0 = by * 256, n0 = bx * 256;
    const int ktBase = blockIdx.z * ktCount;

    f32x4 acc[8][4] = {};

    // ---- staging roles: 4 gloads per operand per wave (32 rows x 128B) ----
    const int srow = lane >> 3;                  // 0..7 row within 8-row gload
    const int sseg = lane & 7;                   // stored 16B slot 0..7
    const int sgx  = sseg ^ srow;                // pre-swizzled global chunk
    int rbA[4];
#pragma unroll
    for (int g = 0; g < 4; ++g) {
        int gr = m0 + w * 32 + g * 8 + srow;
        if (MODE == 1) rbA[g] = gr;
        else {
            int b_ = gr / Rl, rl = gr - b_ * Rl;
            rbA[g] = b_ * 576 + (MODE * (rl / gw)) * 24 + MODE * (rl % gw);
        }
    }
    const unsigned short* gBbase = WW + (size_t)(n0 + w * 32 + srow) * WWN + colOff + sgx * 8;

    // ---- fragment-read roles ----
    const int fr = lane & 15;
    const int kg = lane >> 4;
    const int kgx0 = kg ^ (fr & 7);              // kk=0 slot
    const int kgx1 = kgx0 ^ 4;                   // kk=1 slot
    const int aOff0 = (wm * 128 + fr) * 64 + kgx0 * 8;
    const int aOff1 = (wm * 128 + fr) * 64 + kgx1 * 8;
    const int bOff0 = (wn * 64 + fr) * 64 + kgx0 * 8;
    const int bOff1 = (wn * 64 + fr) * 64 + kgx1 * 8;

    auto STAGE = [&](int buf, int ktl) {
        int kt = ktBase + ktl;                   // BK=64 tile index
        int s = kt / 12;                         // which 768-chunk of K
        int within = (kt - s * 12) * 64;         // + sgx*8 stays within the chunk
        int add = 0;
        if (MODE == 2)      add = (s >> 1) * 24 + (s & 1);
        else if (MODE == 3) { int di = s / 3; add = di * 24 + (s - 3 * di); }
#pragma unroll
        for (int g = 0; g < 4; ++g)
            GLOAD16(FEAT + (size_t)(rbA[g] + add) * 768 + within + sgx * 8,
                    &As[buf][(w * 32 + g * 8) * 64]);
#pragma unroll
        for (int g = 0; g < 4; ++g)
            GLOAD16(gBbase + (size_t)(g * 8) * WWN + (size_t)kt * 64,
                    &Bs[buf][(w * 32 + g * 8) * 64]);
    };

    const int nt = ktCount;
    int cur = 0;
    STAGE(0, 0);

    for (int tt = 0; tt < nt; ++tt) {
        // boundary: wait only for the stage issued one full iteration ago
        asm volatile("s_waitcnt vmcnt(0)" ::: "memory");
        __builtin_amdgcn_s_barrier();
        __builtin_amdgcn_sched_barrier(0);

        if (tt + 1 < nt) STAGE(cur ^ 1, tt + 1);        // in flight across phases
        __builtin_amdgcn_sched_barrier(0);

        // ---- phase kk=0: K elems [0,32), 32 MFMA ----
        {
            bf16x8 bf[4], af[8];
#pragma unroll
            for (int j = 0; j < 4; ++j) bf[j] = *(const bf16x8*)(&Bs[cur][bOff0] + j * 1024);
#pragma unroll
            for (int i = 0; i < 8; ++i) af[i] = *(const bf16x8*)(&As[cur][aOff0] + i * 1024);
            __builtin_amdgcn_s_setprio(1);
#pragma unroll
            for (int i = 0; i < 8; ++i)
#pragma unroll
                for (int j = 0; j < 4; ++j)
                    acc[i][j] = __builtin_amdgcn_mfma_f32_16x16x32_bf16(af[i], bf[j], acc[i][j], 0, 0, 0);
            __builtin_amdgcn_s_setprio(0);
        }
        __builtin_amdgcn_s_barrier();
        __builtin_amdgcn_sched_barrier(0);

        // ---- phase kk=1: K elems [32,64), 32 MFMA ----
        {
            bf16x8 bf[4], af[8];
#pragma unroll
            for (int j = 0; j < 4; ++j) bf[j] = *(const bf16x8*)(&Bs[cur][bOff1] + j * 1024);
#pragma unroll
            for (int i = 0; i < 8; ++i) af[i] = *(const bf16x8*)(&As[cur][aOff1] + i * 1024);
            __builtin_amdgcn_s_setprio(1);
#pragma unroll
            for (int i = 0; i < 8; ++i)
#pragma unroll
                for (int j = 0; j < 4; ++j)
                    acc[i][j] = __builtin_amdgcn_mfma_f32_16x16x32_bf16(af[i], bf[j], acc[i][j], 0, 0, 0);
            __builtin_amdgcn_s_setprio(0);
        }
        cur ^= 1;
    }

#pragma unroll
    for (int i = 0; i < 8; ++i) {
#pragma unroll
        for (int r = 0; r < 4; ++r) {
            int m = m0 + wm * 128 + i * 16 + kg * 4 + r;   // local level row
#pragma unroll
            for (int j = 0; j < 4; ++j) {
                int n = n0 + wn * 64 + j * 16 + fr;
                if (SPLIT) {
                    unsigned short* P = (unsigned short*)outp + (size_t)blockIdx.z * partStride;
                    P[(size_t)m * EE + n] = f2b(acc[i][j][r]);
                } else {
                    int b_o = m / Rl, rl_o = m - b_o * Rl;
                    int crow = b_o * ROWS_TOT + rowOff + rl_o;
                    ((unsigned short*)outp)[(size_t)crow * EE + n] = f2b(acc[i][j][r] + bias[n]);
                }
            }
        }
    }
}

// merged reduce: blocks [0,4608) = L2 (3 slices, rows 576..719/batch);
// [4608,6656) = L3 (4 slices, rows 720..783/batch)
__global__ void reduce_both_kernel(const unsigned short* __restrict__ P2, const unsigned short* __restrict__ P3,
                                   const float* __restrict__ b2, const float* __restrict__ b3,
                                   unsigned short* __restrict__ VAL)
{
    int blk = blockIdx.x;
    const unsigned short* P;
    const float* bb;
    size_t stride;
    int nsl;
    int isL2 = (blk < 4608);
    if (isL2) { P = P2; bb = b2; stride = 9437184; nsl = 3; }
    else      { P = P3; bb = b3; stride = 4194304; nsl = 4; blk -= 4608; }
    size_t e0 = ((size_t)blk * 256 + threadIdx.x) * 8;
    int m = (int)(e0 >> 10);
    int n = (int)(e0 & 1023);
    float s[8] = {0.f};
    for (int k = 0; k < nsl; ++k) {
        ushort8 a = *(const ushort8*)(P + (size_t)k * stride + e0);
#pragma unroll
        for (int i = 0; i < 8; ++i) s[i] += b2f(a[i]);
    }
    int crow;
    if (isL2) crow = (m / 144) * ROWS_TOT + 576 + (m % 144);
    else      crow = (m >> 6) * ROWS_TOT + 720 + (m & 63);
    ushort8 o;
#pragma unroll
    for (int i = 0; i < 8; ++i) o[i] = f2b(s[i] + bb[n + i]);
    *(ushort8*)(VAL + (size_t)crow * EE + n) = o;
}

// ---------------------------------------------------------------------------
// 2-phase double-buffered bf16 MFMA GEMM (128x128, 4 waves) — round-5 proven.
// ---------------------------------------------------------------------------
template<bool OB>
__global__ __launch_bounds__(256) void gemm2(
    const unsigned short* __restrict__ A, const unsigned short* __restrict__ Bw,
    const float* __restrict__ bias, void* __restrict__ Cv,
    int M, int N, int K)
{
    __shared__ unsigned short As[2][128 * 32];
    __shared__ unsigned short Bs[2][128 * 32];
    const int t = threadIdx.x;
    const int lane = t & 63;
    const int w = t >> 6;
    const int wm = w >> 1, wn = w & 1;

    int nwg = gridDim.x * gridDim.y;
    int bid = blockIdx.y * gridDim.x + blockIdx.x;
    int chunk = nwg >> 3;
    int swz = (bid & 7) * chunk + (bid >> 3);
    int by = swz / gridDim.x, bx = swz % gridDim.x;
    const int m0 = by * 128, n0 = bx * 128;

    f32x4 acc[4][4] = {};

    const int sr = lane >> 2;
    const int sc = lane & 3;
    const int scx = sc ^ ((sr >> 1) & 3);
    const unsigned short* gA0 = A + (size_t)(m0 + w * 32 + sr) * K + scx * 8;
    const unsigned short* gA1 = gA0 + (size_t)16 * K;
    const unsigned short* gB0 = Bw + (size_t)(n0 + w * 32 + sr) * K + scx * 8;
    const unsigned short* gB1 = gB0 + (size_t)16 * K;

    const int fr = lane & 15;
    const int kg = lane >> 4;
    const int kgx = kg ^ ((fr >> 1) & 3);

    const int nt = K >> 5;
    int cur = 0;

    auto STAGE = [&](int buf, int k0) {
        GLOAD16(gA0 + k0, &As[buf][w * 1024]);
        GLOAD16(gA1 + k0, &As[buf][w * 1024 + 512]);
        GLOAD16(gB0 + k0, &Bs[buf][w * 1024]);
        GLOAD16(gB1 + k0, &Bs[buf][w * 1024 + 512]);
    };

    STAGE(0, 0);
    __syncthreads();

    for (int tt = 0; tt < nt; ++tt) {
        if (tt + 1 < nt) STAGE(cur ^ 1, (tt + 1) * 32);
        const unsigned short* rdA = &As[cur][(wm * 64 + fr) * 32 + kgx * 8];
        const unsigned short* rdB = &Bs[cur][(wn * 64 + fr) * 32 + kgx * 8];
        bf16x8 af[4], bfr[4];
#pragma unroll
        for (int i = 0; i < 4; ++i) af[i]  = *(const bf16x8*)(rdA + i * 512);
#pragma unroll
        for (int j = 0; j < 4; ++j) bfr[j] = *(const bf16x8*)(rdB + j * 512);
#pragma unroll
        for (int i = 0; i < 4; ++i)
#pragma unroll
            for (int j = 0; j < 4; ++j)
                acc[i][j] = __builtin_amdgcn_mfma_f32_16x16x32_bf16(af[i], bfr[j], acc[i][j], 0, 0, 0);
        if (tt + 1 < nt) { __syncthreads(); cur ^= 1; }
    }

#pragma unroll
    for (int i = 0; i < 4; ++i) {
#pragma unroll
        for (int r = 0; r < 4; ++r) {
            int m = m0 + wm * 64 + i * 16 + kg * 4 + r;
#pragma unroll
            for (int j = 0; j < 4; ++j) {
                int n = n0 + wn * 64 + j * 16 + fr;
                float v = acc[i][j][r];
                if (bias) v += bias[n];
                if (OB) ((unsigned short*)Cv)[(size_t)m * N + n] = f2b(v);
                else    ((float*)Cv)[(size_t)m * N + n] = v;
            }
        }
    }
}

// ---------------------------------------------------------------------------
// MERGED prep dispatch (round-12 proven):
//   blocks [0,13824): features fp32->bf16
//   [13824,15360): vp_w/op_w/fin_w fp32->bf16 (512 each)
//   [15360,26112): transpose-convert p1/p2/p3 -> PT (flattened 336x32)
//   [26112,26880): fused biases b1p/b2p/b3p
// ---------------------------------------------------------------------------
__global__ void prep_kernel(const float* __restrict__ feat, unsigned short* __restrict__ FEAT,
                            const float* __restrict__ vpw, unsigned short* __restrict__ VPW,
                            const float* __restrict__ opw, unsigned short* __restrict__ OPW,
                            const float* __restrict__ finw, unsigned short* __restrict__ FINW,
                            const float* __restrict__ p1, const float* __restrict__ p2,
                            const float* __restrict__ p3, unsigned short* __restrict__ PT,
                            const float* __restrict__ vp_b,
                            const float* __restrict__ pb1, const float* __restrict__ pb2,
                            const float* __restrict__ pb3,
                            float* __restrict__ o1, float* __restrict__ o2, float* __restrict__ o3)
{
    __shared__ float tile[32][33];
    int blk = blockIdx.x;
    if (blk < 15360) {
        const float* in; unsigned short* out;
        if (blk < 13824)       { in = feat; out = FEAT; }
        else if (blk < 14336)  { in = vpw;  out = VPW;  blk -= 13824; }
        else if (blk < 14848)  { in = opw;  out = OPW;  blk -= 14336; }
        else                   { in = finw; out = FINW; blk -= 14848; }
        size_t i = ((size_t)blk * 256 + threadIdx.x) * 8;
        f4 x = *(const f4*)(in + i);
        f4 y = *(const f4*)(in + i + 4);
        ushort8 o;
        o[0] = f2b(x[0]); o[1] = f2b(x[1]); o[2] = f2b(x[2]); o[3] = f2b(x[3]);
        o[4] = f2b(y[0]); o[5] = f2b(y[1]); o[6] = f2b(y[2]); o[7] = f2b(y[3]);
        *(ushort8*)(out + i) = o;
    } else if (blk < 26112) {
        int fl = blk - 15360;
        int bx = fl % 336, byy = fl / 336;
        const float* in; unsigned short* out; int C;
        if (bx < 24)       { in = p1; out = PT;                C = 768; }
        else if (bx < 120) { in = p2; out = PT + 768  * 1024;  C = 3072; bx -= 24; }
        else               { in = p3; out = PT + 3840 * 1024;  C = 6912; bx -= 120; }
        const int R = 1024;
        int c0 = bx * 32, r0 = byy * 32;
        int tx = threadIdx.x & 31, ty = threadIdx.x >> 5;
#pragma unroll
        for (int i = 0; i < 32; i += 8)
            tile[ty + i][tx] = in[(size_t)(r0 + ty + i) * C + c0 + tx];
        __syncthreads();
#pragma unroll
        for (int i = 0; i < 32; i += 8)
            out[(size_t)(c0 + ty + i) * R + r0 + tx] = f2b(tile[tx][ty + i]);
    } else {
        int b = blk - 26112;
        const float* pb; float* bout;
        if (b < 256)      { pb = pb1; bout = o1; }
        else if (b < 512) { pb = pb2; bout = o2; b -= 256; }
        else              { pb = pb3; bout = o3; b -= 512; }
        int e = b * 4 + (threadIdx.x >> 6);
        int lane = threadIdx.x & 63;
        float s = 0.f;
        for (int k = lane; k < EE; k += 64) s += vpw[(size_t)e * EE + k] * pb[k];
#pragma unroll
        for (int o = 32; o > 0; o >>= 1) s += __shfl_down(s, o, 64);
        if (lane == 0) bout[e] = s + vp_b[e];
    }
}

// ---------------------------------------------------------------------------
// Query branch (batch-independent), fp64 — semantics preserved exactly
// ---------------------------------------------------------------------------
__global__ void rg1_kernel(const float* __restrict__ qe, const float* __restrict__ w,
                           const float* __restrict__ b, double* __restrict__ h0)
{
    int o = blockIdx.x * 4 + (threadIdx.x >> 6);
    int lane = threadIdx.x & 63;
    int q = o >> 10, n = o & 1023;
    double s = 0.0;
    for (int k = lane; k < EE; k += 64)
        s += (double)qe[q * EE + k] * (double)w[(size_t)n * EE + k];
#pragma unroll
    for (int off = 32; off > 0; off >>= 1) s += __shfl_down(s, off, 64);
    if (lane == 0) h0[o] = s + (double)b[n];
}

__global__ void ln_gelu_kernel(const double* __restrict__ h0, const float* __restrict__ g,
                               const float* __restrict__ bb, double* __restrict__ h)
{
    __shared__ double red[256];
    __shared__ double stats[2];
    int q = blockIdx.x, t = threadIdx.x;
    double x[4];
#pragma unroll
    for (int i = 0; i < 4; ++i) x[i] = h0[q * 1024 + t + i * 256];
    double s = x[0] + x[1] + x[2] + x[3];
    red[t] = s; __syncthreads();
    for (int o = 128; o; o >>= 1) { if (t < o) red[t] += red[t + o]; __syncthreads(); }
    if (t == 0) stats[0] = red[0] / 1024.0;
    __syncthreads();
    double mean = stats[0];
    double d = 0.0;
#pragma unroll
    for (int i = 0; i < 4; ++i) { double dd = x[i] - mean; d += dd * dd; }
    red[t] = d; __syncthreads();
    for (int o = 128; o; o >>= 1) { if (t < o) red[t] += red[t + o]; __syncthreads(); }
    if (t == 0) stats[1] = red[0] / 1024.0;
    __syncthreads();
    double inv = 1.0 / sqrt(stats[1] + 1e-5);
#pragma unroll
    for (int i = 0; i < 4; ++i) {
        int c = t + i * 256;
        double y = (x[i] - mean) * inv * (double)g[c] + (double)bb[c];
        h[q * 1024 + c] = y * 0.5 * (1.0 + erf(y * 0.70710678118654752440));
    }
}

__global__ void rp_kernel(const double* __restrict__ h, const float* __restrict__ w2,
                          const float* __restrict__ b2, double* __restrict__ rp)
{
    int o = blockIdx.x * 4 + (threadIdx.x >> 6);
    int lane = threadIdx.x & 63;
    int q = o >> 1, r = o & 1;
    double s = 0.0;
    for (int k = lane; k < EE; k += 64)
        s += h[q * 1024 + k] * (double)w2[r * 1024 + k];
#pragma unroll
    for (int off = 32; off > 0; off >>= 1) s += __shfl_down(s, off, 64);
    if (lane == 0) rp[o] = 1.0 / (1.0 + exp(-(s + (double)b2[r])));
}

// wave-parallel so/aw logits (fp64, order-preserving lane-strided sum like rg1):
// outputs o in [0,12288): o<8192 -> offv_g[q*128+j]; else logit_g[q*64+n]
__global__ void offlog_kernel(const float* __restrict__ qe, const float* __restrict__ so_w,
                              const float* __restrict__ so_b, const float* __restrict__ aw_w,
                              const float* __restrict__ aw_b,
                              double* __restrict__ offv_g, double* __restrict__ logit_g)
{
    int o = blockIdx.x * 4 + (threadIdx.x >> 6);
    int lane = threadIdx.x & 63;
    const float* wrow;
    double bias;
    int q;
    if (o < 8192) { q = o >> 7; int j = o & 127; wrow = so_w + (size_t)j * EE; bias = (double)so_b[j]; }
    else          { int r = o - 8192; q = r >> 6; int n = r & 63; wrow = aw_w + (size_t)n * EE; bias = (double)aw_b[n]; }
    double s = 0.0;
    for (int k = lane; k < EE; k += 64)
        s += (double)qe[q * EE + k] * (double)wrow[k];
#pragma unroll
    for (int off = 32; off > 0; off >>= 1) s += __shfl_down(s, off, 64);
    if (lane == 0) {
        if (o < 8192) offv_g[o] = s + bias;
        else          logit_g[o - 8192] = s + bias;
    }
}

// finalize: softmax over p + sampling-point index snap (fp64, exact)
__global__ void offfin_kernel(const double* __restrict__ offv_g, const double* __restrict__ logit_g,
                              const double* __restrict__ rp,
                              float* __restrict__ awf, int* __restrict__ idxv)
{
    int q = blockIdx.x, t = threadIdx.x;   // 64 threads
    int hh = t >> 2, p = t & 3;
    const double* logit = logit_g + q * 64;
    const double* offv  = offv_g + q * 128;
    double l0 = logit[hh * 4 + 0], l1 = logit[hh * 4 + 1];
    double l2 = logit[hh * 4 + 2], l3 = logit[hh * 4 + 3];
    double m = fmax(fmax(l0, l1), fmax(l2, l3));
    double den = exp(l0 - m) + exp(l1 - m) + exp(l2 - m) + exp(l3 - m);
    awf[(q * 16 + hh) * 4 + p] = (float)(exp(logit[hh * 4 + p] - m) / den);
    const int Wss[3] = {24, 12, 8};
    const int starts[3] = {0, 576, 720};
    double ox = offv[(hh * 4 + p) * 2 + 0], oy = offv[(hh * 4 + p) * 2 + 1];
    double rx = rp[q * 2 + 0], ry = rp[q * 2 + 1];
#pragma unroll
    for (int l = 0; l < 3; ++l) {
        int Ws = Wss[l];
        double sx = rx + ox; sx = sx < 0.0 ? 0.0 : (sx > 1.0 ? 1.0 : sx);
        double sy = ry + oy; sy = sy < 0.0 ? 0.0 : (sy > 1.0 ? 1.0 : sy);
        int x0 = (int)floor(sx * (double)(Ws - 1));
        int y0 = (int)floor(sy * (double)(Ws - 1));
        idxv[((l * 64 + q) * 16 + hh) * 4 + p] = starts[l] + y0 * Ws + x0;
    }
}

// out0[b,q,h,:] = sum_{l,p} aw[q,h,p] * value[b, idx[l,q,h,p], h, :]   (bf16)
__global__ void gather_kernel(const unsigned short* __restrict__ value, const float* __restrict__ awf,
                              const int* __restrict__ idxv, unsigned short* __restrict__ out0)
{
    int unit = blockIdx.x * 4 + (threadIdx.x >> 6);
    int lane = threadIdx.x & 63;
    int b = unit >> 10;
    int rem = unit & 1023;
    int q = rem >> 4, h = rem & 15;
    float acc = 0.f;
#pragma unroll
    for (int l = 0; l < 3; ++l)
#pragma unroll
        for (int p = 0; p < 4; ++p) {
            int row = idxv[((l * 64 + q) * 16 + h) * 4 + p];
            float wgt = awf[(q * 16 + h) * 4 + p];
            acc += wgt * b2f(value[((size_t)(b * ROWS_TOT + row)) * 1024 + h * 64 + lane]);
        }
    out0[((size_t)(b * 64 + q)) * 1024 + h * 64 + lane] = f2b(acc);
}

// fp32 LayerNorm over 1024, output bf16
__global__ void ln_bf16_kernel(const float* __restrict__ x, const float* __restrict__ g,
                               const float* __restrict__ bb, unsigned short* __restrict__ y)
{
    __shared__ float red[256];
    __shared__ float stats[2];
    int r = blockIdx.x, t = threadIdx.x;
    float v[4];
#pragma unroll
    for (int i = 0; i < 4; ++i) v[i] = x[(size_t)r * 1024 + t + i * 256];
    float s = v[0] + v[1] + v[2] + v[3];
    red[t] = s; __syncthreads();
    for (int o = 128; o; o >>= 1) { if (t < o) red[t] += red[t + o]; __syncthreads(); }
    if (t == 0) stats[0] = red[0] / 1024.f;
    __syncthreads();
    float mean = stats[0];
    float d = 0.f;
#pragma unroll
    for (int i = 0; i < 4; ++i) { float dd = v[i] - mean; d += dd * dd; }
    red[t] = d; __syncthreads();
    for (int o = 128; o; o >>= 1) { if (t < o) red[t] += red[t + o]; __syncthreads(); }
    if (t == 0) stats[1] = red[0] / 1024.f;
    __syncthreads();
    float inv = 1.f / sqrtf(stats[1] + 1e-5f);
#pragma unroll
    for (int i = 0; i < 4; ++i) {
        int c = t + i * 256;
        y[(size_t)r * 1024 + c] = f2b((v[i] - mean) * inv * g[c] + bb[c]);
    }
}

extern "C" void kernel_launch(void* const* d_in, const int* in_sizes, int n_in,
                              void* d_out, int out_size, void* d_ws, size_t ws_size,
                              hipStream_t stream)
{
    const float* features  = (const float*)d_in[0];
    const float* p1_w      = (const float*)d_in[1];
    const float* p1_b      = (const float*)d_in[2];
    const float* p2_w      = (const float*)d_in[3];
    const float* p2_b      = (const float*)d_in[4];
    const float* p3_w      = (const float*)d_in[5];
    const float* p3_b      = (const float*)d_in[6];
    const float* query_emb = (const float*)d_in[7];
    const float* rg_w1     = (const float*)d_in[8];
    const float* rg_b1     = (const float*)d_in[9];
    const float* rg_g      = (const float*)d_in[10];
    const float* rg_b      = (const float*)d_in[11];
    const float* rg_w2     = (const float*)d_in[12];
    const float* rg_b2     = (const float*)d_in[13];
    const float* so_w      = (const float*)d_in[14];
    const float* so_b      = (const float*)d_in[15];
    const float* aw_w      = (const float*)d_in[16];
    const float* aw_b      = (const float*)d_in[17];
    const float* vp_w      = (const float*)d_in[18];
    const float* vp_b      = (const float*)d_in[19];
    const float* op_w      = (const float*)d_in[20];
    const float* op_b      = (const float*)d_in[21];
    const float* fln_g     = (const float*)d_in[22];
    const float* fln_b     = (const float*)d_in[23];
    const float* fin_w     = (const float*)d_in[24];
    const float* fin_b     = (const float*)d_in[25];
    float* out = (float*)d_out;

    // ---- workspace layout (bytes) ----
    char* p = (char*)d_ws;
    unsigned short* FEAT = (unsigned short*)p; p += 56623104;   // bf16 [B*576,768]
    unsigned short* PT   = (unsigned short*)p; p += 22020096;   // [10752,1024] stacked p_w^T
    unsigned short* WW   = (unsigned short*)p; p += 22020096;   // [1024,10752] fused weights
    unsigned short* VPW  = (unsigned short*)p; p += 2097152;
    unsigned short* VAL  = (unsigned short*)p; p += 102760448;  // value bf16 [64*784,1024]
    unsigned short* PART = (unsigned short*)p; p += 75497472;   // bf16 partials (L2: 3x, L3: 4x)
    float*          OUT1 = (float*)p;          p += 16777216;   // fp32 [4096,1024]
    unsigned short* OUT0 = (unsigned short*)p; p += 8388608;
    unsigned short* LNO  = (unsigned short*)p; p += 8388608;
    unsigned short* OPW  = (unsigned short*)p; p += 2097152;
    unsigned short* FINW = (unsigned short*)p; p += 2097152;
    float* b1p  = (float*)p; p += 4096;
    float* b2p  = (float*)p; p += 4096;
    float* b3p  = (float*)p; p += 4096;
    float* awf  = (float*)p; p += 16384;
    int*   idxv = (int*)p;   p += 49152;
    double* h0  = (double*)p; p += 524288;
    double* hb  = (double*)p; p += 524288;
    double* rp  = (double*)p; p += 1024;
    double* offv_g  = (double*)p; p += 65536;   // [64,128]
    double* logit_g = (double*)p; p += 32768;   // [64,64]

    dim3 blk(256);

    // ---- query branch (fp64, batch-independent) ----
    rg1_kernel<<<16384, blk, 0, stream>>>(query_emb, rg_w1, rg_b1, h0);
    ln_gelu_kernel<<<64, blk, 0, stream>>>(h0, rg_g, rg_b, hb);
    rp_kernel<<<32, blk, 0, stream>>>(hb, rg_w2, rg_b2, rp);
    offlog_kernel<<<3072, blk, 0, stream>>>(query_emb, so_w, so_b, aw_w, aw_b, offv_g, logit_g);
    offfin_kernel<<<64, 64, 0, stream>>>(offv_g, logit_g, rp, awf, idxv);

    // ---- merged prep: all conversions + transposes + fused biases ----
    prep_kernel<<<26880, blk, 0, stream>>>(features, FEAT, vp_w, VPW, op_w, OPW, fin_w, FINW,
                                           p1_w, p2_w, p3_w, PT,
                                           vp_b, p1_b, p2_b, p3_b, b1p, b2p, b3p);

    // ---- fused weights: WW[1024,10752] = VPW @ PT^T ----
    gemm2<true><<<dim3(84, 8), blk, 0, stream>>>(VPW, PT, nullptr, WW, 1024, WWN, 1024);

    // ---- value GEMMs, 256x256 BK=64 tiles, per level; L2 z=3 (better packing) ----
    gemm256<1, false><<<dim3(4, 144),    512, 0, stream>>>(FEAT, WW, b1p, VAL, 12, 0);
    gemm256<2, true><<<dim3(4, 36, 3),   512, 0, stream>>>(FEAT, WW, nullptr, PART, 16, 9437184);
    gemm256<3, true><<<dim3(4, 16, 4),   512, 0, stream>>>(FEAT, WW, nullptr, PART + 3 * 9437184, 27, 4194304);
    reduce_both_kernel<<<6656, blk, 0, stream>>>(PART, PART + 3 * 9437184, b2p, b3p, VAL);

    // ---- deformable gather ----
    gather_kernel<<<16384, blk, 0, stream>>>(VAL, awf, idxv, OUT0);

    // ---- output projection + LN + final projection ----
    gemm2<false><<<dim3(8, 32), blk, 0, stream>>>(OUT0, OPW, op_b, OUT1, 4096, 1024, 1024);
    ln_bf16_kernel<<<4096, blk, 0, stream>>>(OUT1, fln_g, fln_b, LNO);
    gemm2<false><<<dim3(8, 32), blk, 0, stream>>>(LNO, FINW, fin_b, out, 4096, 1024, 1024);
}

// Round 15
// 510.067 us; speedup vs baseline: 1.2784x; 1.0140x over previous
//
#include <hip/hip_runtime.h>
#include <math.h>

#define EE 1024
#define ROWS_TOT 784   // 576 + 144 + 64
#define WWN 10752      // 768 + 3072 + 6912

typedef __attribute__((ext_vector_type(4))) float f4;
typedef __attribute__((ext_vector_type(4))) float f32x4;
typedef __attribute__((ext_vector_type(8))) __bf16 bf16x8;
typedef __attribute__((ext_vector_type(8))) unsigned short ushort8;
typedef __attribute__((ext_vector_type(4))) unsigned short us4;

__device__ __forceinline__ unsigned short f2b(float x) {
    unsigned int u = __float_as_uint(x);
    unsigned int r = (u + 0x7fffu + ((u >> 16) & 1u)) >> 16;
    return (unsigned short)r;
}
__device__ __forceinline__ float b2f(unsigned short u) {
    unsigned int v = ((unsigned int)u) << 16;
    return __uint_as_float(v);
}

#define GLOAD16(g, l) __builtin_amdgcn_global_load_lds( \
    (const __attribute__((address_space(1))) unsigned int*)(g), \
    (__attribute__((address_space(3))) unsigned int*)(l), 16, 0, 0)

// ---------------------------------------------------------------------------
// 256x256 value GEMM, BK=64, 8 waves (2m x 4n), per-wave 128x64.
// LDS 128KB dbuf -> 1 block/CU. Round-10/12 proven (best measured).
// Swizzle: 128B rows = 8 x 16B slots; slot s of row r holds global chunk
// s ^ (r&7); reads use (kk*4+kg) ^ (fr&7). T3/T4/T5 schedule.
// SPLIT: write bf16 partial (no bias) for K-chunk blockIdx.z.
// ---------------------------------------------------------------------------
template<int MODE, bool SPLIT>
__global__ __launch_bounds__(512, 2) void gemm256(
    const unsigned short* __restrict__ FEAT, const unsigned short* __restrict__ WW,
    const float* __restrict__ bias, void* __restrict__ outp,
    int ktCount, int partStride)
{
    constexpr int gw = (MODE == 1) ? 24 : (MODE == 2 ? 12 : 8);
    constexpr int Rl = gw * gw;                                   // 576/144/64
    constexpr int colOff = (MODE == 1) ? 0 : (MODE == 2 ? 768 : 3840);
    constexpr int rowOff = (MODE == 1) ? 0 : (MODE == 2 ? 576 : 720);

    __shared__ unsigned short As[2][256 * 64];   // 32KB each
    __shared__ unsigned short Bs[2][256 * 64];

    const int t = threadIdx.x;
    const int lane = t & 63;
    const int w = t >> 6;                // 0..7
    const int wm = w >> 2;               // 0..1  (128-row half)
    const int wn = w & 3;                // 0..3  (64-col quarter)

    // bijective XCD swizzle over x*y (always %8==0); z untouched
    int nwg = gridDim.x * gridDim.y;
    int bid = blockIdx.y * gridDim.x + blockIdx.x;
    int chunk = nwg >> 3;
    int swz = (bid & 7) * chunk + (bid >> 3);
    int by = swz / gridDim.x, bx = swz % gridDim.x;
    const int m0 = by * 256, n0 = bx * 256;
    const int ktBase = blockIdx.z * ktCount;

    f32x4 acc[8][4] = {};

    // ---- staging roles: 4 gloads per operand per wave (32 rows x 128B) ----
    const int srow = lane >> 3;                  // 0..7 row within 8-row gload
    const int sseg = lane & 7;                   // stored 16B slot 0..7
    const int sgx  = sseg ^ srow;                // pre-swizzled global chunk
    int rbA[4];
#pragma unroll
    for (int g = 0; g < 4; ++g) {
        int gr = m0 + w * 32 + g * 8 + srow;
        if (MODE == 1) rbA[g] = gr;
        else {
            int b_ = gr / Rl, rl = gr - b_ * Rl;
            rbA[g] = b_ * 576 + (MODE * (rl / gw)) * 24 + MODE * (rl % gw);
        }
    }
    const unsigned short* gBbase = WW + (size_t)(n0 + w * 32 + srow) * WWN + colOff + sgx * 8;

    // ---- fragment-read roles ----
    const int fr = lane & 15;
    const int kg = lane >> 4;
    const int kgx0 = kg ^ (fr & 7);              // kk=0 slot
    const int kgx1 = kgx0 ^ 4;                   // kk=1 slot
    const int aOff0 = (wm * 128 + fr) * 64 + kgx0 * 8;
    const int aOff1 = (wm * 128 + fr) * 64 + kgx1 * 8;
    const int bOff0 = (wn * 64 + fr) * 64 + kgx0 * 8;
    const int bOff1 = (wn * 64 + fr) * 64 + kgx1 * 8;

    auto STAGE = [&](int buf, int ktl) {
        int kt = ktBase + ktl;                   // BK=64 tile index
        int s = kt / 12;                         // which 768-chunk of K
        int within = (kt - s * 12) * 64;         // + sgx*8 stays within the chunk
        int add = 0;
        if (MODE == 2)      add = (s >> 1) * 24 + (s & 1);
        else if (MODE == 3) { int di = s / 3; add = di * 24 + (s - 3 * di); }
#pragma unroll
        for (int g = 0; g < 4; ++g)
            GLOAD16(FEAT + (size_t)(rbA[g] + add) * 768 + within + sgx * 8,
                    &As[buf][(w * 32 + g * 8) * 64]);
#pragma unroll
        for (int g = 0; g < 4; ++g)
            GLOAD16(gBbase + (size_t)(g * 8) * WWN + (size_t)kt * 64,
                    &Bs[buf][(w * 32 + g * 8) * 64]);
    };

    const int nt = ktCount;
    int cur = 0;
    STAGE(0, 0);

    for (int tt = 0; tt < nt; ++tt) {
        // boundary: wait only for the stage issued one full iteration ago
        asm volatile("s_waitcnt vmcnt(0)" ::: "memory");
        __builtin_amdgcn_s_barrier();
        __builtin_amdgcn_sched_barrier(0);

        if (tt + 1 < nt) STAGE(cur ^ 1, tt + 1);        // in flight across phases
        __builtin_amdgcn_sched_barrier(0);

        // ---- phase kk=0: K elems [0,32), 32 MFMA ----
        {
            bf16x8 bf[4], af[8];
#pragma unroll
            for (int j = 0; j < 4; ++j) bf[j] = *(const bf16x8*)(&Bs[cur][bOff0] + j * 1024);
#pragma unroll
            for (int i = 0; i < 8; ++i) af[i] = *(const bf16x8*)(&As[cur][aOff0] + i * 1024);
            __builtin_amdgcn_s_setprio(1);
#pragma unroll
            for (int i = 0; i < 8; ++i)
#pragma unroll
                for (int j = 0; j < 4; ++j)
                    acc[i][j] = __builtin_amdgcn_mfma_f32_16x16x32_bf16(af[i], bf[j], acc[i][j], 0, 0, 0);
            __builtin_amdgcn_s_setprio(0);
        }
        __builtin_amdgcn_s_barrier();
        __builtin_amdgcn_sched_barrier(0);

        // ---- phase kk=1: K elems [32,64), 32 MFMA ----
        {
            bf16x8 bf[4], af[8];
#pragma unroll
            for (int j = 0; j < 4; ++j) bf[j] = *(const bf16x8*)(&Bs[cur][bOff1] + j * 1024);
#pragma unroll
            for (int i = 0; i < 8; ++i) af[i] = *(const bf16x8*)(&As[cur][aOff1] + i * 1024);
            __builtin_amdgcn_s_setprio(1);
#pragma unroll
            for (int i = 0; i < 8; ++i)
#pragma unroll
                for (int j = 0; j < 4; ++j)
                    acc[i][j] = __builtin_amdgcn_mfma_f32_16x16x32_bf16(af[i], bf[j], acc[i][j], 0, 0, 0);
            __builtin_amdgcn_s_setprio(0);
        }
        cur ^= 1;
    }

#pragma unroll
    for (int i = 0; i < 8; ++i) {
#pragma unroll
        for (int r = 0; r < 4; ++r) {
            int m = m0 + wm * 128 + i * 16 + kg * 4 + r;   // local level row
#pragma unroll
            for (int j = 0; j < 4; ++j) {
                int n = n0 + wn * 64 + j * 16 + fr;
                if (SPLIT) {
                    unsigned short* P = (unsigned short*)outp + (size_t)blockIdx.z * partStride;
                    P[(size_t)m * EE + n] = f2b(acc[i][j][r]);
                } else {
                    int b_o = m / Rl, rl_o = m - b_o * Rl;
                    int crow = b_o * ROWS_TOT + rowOff + rl_o;
                    ((unsigned short*)outp)[(size_t)crow * EE + n] = f2b(acc[i][j][r] + bias[n]);
                }
            }
        }
    }
}

// merged reduce: blocks [0,4608) = L2 (3 slices); [4608,6656) = L3 (4 slices)
__global__ void reduce_both_kernel(const unsigned short* __restrict__ P2, const unsigned short* __restrict__ P3,
                                   const float* __restrict__ b2, const float* __restrict__ b3,
                                   unsigned short* __restrict__ VAL)
{
    int blk = blockIdx.x;
    const unsigned short* P;
    const float* bb;
    size_t stride;
    int nsl;
    int isL2 = (blk < 4608);
    if (isL2) { P = P2; bb = b2; stride = 9437184; nsl = 3; }
    else      { P = P3; bb = b3; stride = 4194304; nsl = 4; blk -= 4608; }
    size_t e0 = ((size_t)blk * 256 + threadIdx.x) * 8;
    int m = (int)(e0 >> 10);
    int n = (int)(e0 & 1023);
    float s[8] = {0.f};
    for (int k = 0; k < nsl; ++k) {
        ushort8 a = *(const ushort8*)(P + (size_t)k * stride + e0);
#pragma unroll
        for (int i = 0; i < 8; ++i) s[i] += b2f(a[i]);
    }
    int crow;
    if (isL2) crow = (m / 144) * ROWS_TOT + 576 + (m % 144);
    else      crow = (m >> 6) * ROWS_TOT + 720 + (m & 63);
    ushort8 o;
#pragma unroll
    for (int i = 0; i < 8; ++i) o[i] = f2b(s[i] + bb[n + i]);
    *(ushort8*)(VAL + (size_t)crow * EE + n) = o;
}

// ---------------------------------------------------------------------------
// 128x128 GEMM, BK=64, 4 waves (2x2), per-wave 64x64 (4x4 frags).
// C[M,N] = A[M,K] @ B[N,K]^T + bias. gemm256 schedule (T3/T4/T5) + 128B-row
// swizzle; LDS 64KB dbuf -> 2 blocks/CU. K multiple of 64.
// ---------------------------------------------------------------------------
template<bool OB>
__global__ __launch_bounds__(256, 2) void gemm2w(
    const unsigned short* __restrict__ A, const unsigned short* __restrict__ Bw,
    const float* __restrict__ bias, void* __restrict__ Cv,
    int M, int N, int K)
{
    __shared__ unsigned short As[2][128 * 64];   // 16KB each
    __shared__ unsigned short Bs[2][128 * 64];

    const int t = threadIdx.x;
    const int lane = t & 63;
    const int w = t >> 6;                // 0..3
    const int wm = w >> 1, wn = w & 1;

    int nwg = gridDim.x * gridDim.y;
    int bid = blockIdx.y * gridDim.x + blockIdx.x;
    int chunk = nwg >> 3;
    int swz = (bid & 7) * chunk + (bid >> 3);
    int by = swz / gridDim.x, bx = swz % gridDim.x;
    const int m0 = by * 128, n0 = bx * 128;

    f32x4 acc[4][4] = {};

    const int srow = lane >> 3;                  // 0..7
    const int sseg = lane & 7;
    const int sgx  = sseg ^ srow;
    const unsigned short* gA = A + (size_t)(m0 + w * 32 + srow) * K + sgx * 8;
    const unsigned short* gB = Bw + (size_t)(n0 + w * 32 + srow) * K + sgx * 8;

    const int fr = lane & 15;
    const int kg = lane >> 4;
    const int kgx0 = kg ^ (fr & 7);
    const int kgx1 = kgx0 ^ 4;
    const int aOff0 = (wm * 64 + fr) * 64 + kgx0 * 8;
    const int aOff1 = (wm * 64 + fr) * 64 + kgx1 * 8;
    const int bOff0 = (wn * 64 + fr) * 64 + kgx0 * 8;
    const int bOff1 = (wn * 64 + fr) * 64 + kgx1 * 8;

    auto STAGE = [&](int buf, int kt) {
        size_t k0 = (size_t)kt * 64;
#pragma unroll
        for (int g = 0; g < 4; ++g)
            GLOAD16(gA + (size_t)(g * 8) * K + k0, &As[buf][(w * 32 + g * 8) * 64]);
#pragma unroll
        for (int g = 0; g < 4; ++g)
            GLOAD16(gB + (size_t)(g * 8) * K + k0, &Bs[buf][(w * 32 + g * 8) * 64]);
    };

    const int nt = K >> 6;
    int cur = 0;
    STAGE(0, 0);

    for (int tt = 0; tt < nt; ++tt) {
        asm volatile("s_waitcnt vmcnt(0)" ::: "memory");
        __builtin_amdgcn_s_barrier();
        __builtin_amdgcn_sched_barrier(0);

        if (tt + 1 < nt) STAGE(cur ^ 1, tt + 1);
        __builtin_amdgcn_sched_barrier(0);

        // phase kk=0
        {
            bf16x8 bf[4], af[4];
#pragma unroll
            for (int j = 0; j < 4; ++j) bf[j] = *(const bf16x8*)(&Bs[cur][bOff0] + j * 1024);
#pragma unroll
            for (int i = 0; i < 4; ++i) af[i] = *(const bf16x8*)(&As[cur][aOff0] + i * 1024);
            __builtin_amdgcn_s_setprio(1);
#pragma unroll
            for (int i = 0; i < 4; ++i)
#pragma unroll
                for (int j = 0; j < 4; ++j)
                    acc[i][j] = __builtin_amdgcn_mfma_f32_16x16x32_bf16(af[i], bf[j], acc[i][j], 0, 0, 0);
            __builtin_amdgcn_s_setprio(0);
        }
        __builtin_amdgcn_s_barrier();
        __builtin_amdgcn_sched_barrier(0);

        // phase kk=1
        {
            bf16x8 bf[4], af[4];
#pragma unroll
            for (int j = 0; j < 4; ++j) bf[j] = *(const bf16x8*)(&Bs[cur][bOff1] + j * 1024);
#pragma unroll
            for (int i = 0; i < 4; ++i) af[i] = *(const bf16x8*)(&As[cur][aOff1] + i * 1024);
            __builtin_amdgcn_s_setprio(1);
#pragma unroll
            for (int i = 0; i < 4; ++i)
#pragma unroll
                for (int j = 0; j < 4; ++j)
                    acc[i][j] = __builtin_amdgcn_mfma_f32_16x16x32_bf16(af[i], bf[j], acc[i][j], 0, 0, 0);
            __builtin_amdgcn_s_setprio(0);
        }
        cur ^= 1;
    }

#pragma unroll
    for (int i = 0; i < 4; ++i) {
#pragma unroll
        for (int r = 0; r < 4; ++r) {
            int m = m0 + wm * 64 + i * 16 + kg * 4 + r;
#pragma unroll
            for (int j = 0; j < 4; ++j) {
                int n = n0 + wn * 64 + j * 16 + fr;
                float v = acc[i][j][r];
                if (bias) v += bias[n];
                if (OB) ((unsigned short*)Cv)[(size_t)m * N + n] = f2b(v);
                else    ((float*)Cv)[(size_t)m * N + n] = v;
            }
        }
    }
}

// ---------------------------------------------------------------------------
// MERGED prep dispatch (round-12 proven)
// ---------------------------------------------------------------------------
__global__ void prep_kernel(const float* __restrict__ feat, unsigned short* __restrict__ FEAT,
                            const float* __restrict__ vpw, unsigned short* __restrict__ VPW,
                            const float* __restrict__ opw, unsigned short* __restrict__ OPW,
                            const float* __restrict__ finw, unsigned short* __restrict__ FINW,
                            const float* __restrict__ p1, const float* __restrict__ p2,
                            const float* __restrict__ p3, unsigned short* __restrict__ PT,
                            const float* __restrict__ vp_b,
                            const float* __restrict__ pb1, const float* __restrict__ pb2,
                            const float* __restrict__ pb3,
                            float* __restrict__ o1, float* __restrict__ o2, float* __restrict__ o3)
{
    __shared__ float tile[32][33];
    int blk = blockIdx.x;
    if (blk < 15360) {
        const float* in; unsigned short* out;
        if (blk < 13824)       { in = feat; out = FEAT; }
        else if (blk < 14336)  { in = vpw;  out = VPW;  blk -= 13824; }
        else if (blk < 14848)  { in = opw;  out = OPW;  blk -= 14336; }
        else                   { in = finw; out = FINW; blk -= 14848; }
        size_t i = ((size_t)blk * 256 + threadIdx.x) * 8;
        f4 x = *(const f4*)(in + i);
        f4 y = *(const f4*)(in + i + 4);
        ushort8 o;
        o[0] = f2b(x[0]); o[1] = f2b(x[1]); o[2] = f2b(x[2]); o[3] = f2b(x[3]);
        o[4] = f2b(y[0]); o[5] = f2b(y[1]); o[6] = f2b(y[2]); o[7] = f2b(y[3]);
        *(ushort8*)(out + i) = o;
    } else if (blk < 26112) {
        int fl = blk - 15360;
        int bx = fl % 336, byy = fl / 336;
        const float* in; unsigned short* out; int C;
        if (bx < 24)       { in = p1; out = PT;                C = 768; }
        else if (bx < 120) { in = p2; out = PT + 768  * 1024;  C = 3072; bx -= 24; }
        else               { in = p3; out = PT + 3840 * 1024;  C = 6912; bx -= 120; }
        const int R = 1024;
        int c0 = bx * 32, r0 = byy * 32;
        int tx = threadIdx.x & 31, ty = threadIdx.x >> 5;
#pragma unroll
        for (int i = 0; i < 32; i += 8)
            tile[ty + i][tx] = in[(size_t)(r0 + ty + i) * C + c0 + tx];
        __syncthreads();
#pragma unroll
        for (int i = 0; i < 32; i += 8)
            out[(size_t)(c0 + ty + i) * R + r0 + tx] = f2b(tile[tx][ty + i]);
    } else {
        int b = blk - 26112;
        const float* pb; float* bout;
        if (b < 256)      { pb = pb1; bout = o1; }
        else if (b < 512) { pb = pb2; bout = o2; b -= 256; }
        else              { pb = pb3; bout = o3; b -= 512; }
        int e = b * 4 + (threadIdx.x >> 6);
        int lane = threadIdx.x & 63;
        float s = 0.f;
        for (int k = lane; k < EE; k += 64) s += vpw[(size_t)e * EE + k] * pb[k];
#pragma unroll
        for (int o = 32; o > 0; o >>= 1) s += __shfl_down(s, o, 64);
        if (lane == 0) bout[e] = s + vp_b[e];
    }
}

// ---------------------------------------------------------------------------
// Query branch (batch-independent), fp64 — semantics preserved exactly
// ---------------------------------------------------------------------------
__global__ void rg1_kernel(const float* __restrict__ qe, const float* __restrict__ w,
                           const float* __restrict__ b, double* __restrict__ h0)
{
    int o = blockIdx.x * 4 + (threadIdx.x >> 6);
    int lane = threadIdx.x & 63;
    int q = o >> 10, n = o & 1023;
    double s = 0.0;
    for (int k = lane; k < EE; k += 64)
        s += (double)qe[q * EE + k] * (double)w[(size_t)n * EE + k];
#pragma unroll
    for (int off = 32; off > 0; off >>= 1) s += __shfl_down(s, off, 64);
    if (lane == 0) h0[o] = s + (double)b[n];
}

__global__ void ln_gelu_kernel(const double* __restrict__ h0, const float* __restrict__ g,
                               const float* __restrict__ bb, double* __restrict__ h)
{
    __shared__ double red[256];
    __shared__ double stats[2];
    int q = blockIdx.x, t = threadIdx.x;
    double x[4];
#pragma unroll
    for (int i = 0; i < 4; ++i) x[i] = h0[q * 1024 + t + i * 256];
    double s = x[0] + x[1] + x[2] + x[3];
    red[t] = s; __syncthreads();
    for (int o = 128; o; o >>= 1) { if (t < o) red[t] += red[t + o]; __syncthreads(); }
    if (t == 0) stats[0] = red[0] / 1024.0;
    __syncthreads();
    double mean = stats[0];
    double d = 0.0;
#pragma unroll
    for (int i = 0; i < 4; ++i) { double dd = x[i] - mean; d += dd * dd; }
    red[t] = d; __syncthreads();
    for (int o = 128; o; o >>= 1) { if (t < o) red[t] += red[t + o]; __syncthreads(); }
    if (t == 0) stats[1] = red[0] / 1024.0;
    __syncthreads();
    double inv = 1.0 / sqrt(stats[1] + 1e-5);
#pragma unroll
    for (int i = 0; i < 4; ++i) {
        int c = t + i * 256;
        double y = (x[i] - mean) * inv * (double)g[c] + (double)bb[c];
        h[q * 1024 + c] = y * 0.5 * (1.0 + erf(y * 0.70710678118654752440));
    }
}

__global__ void rp_kernel(const double* __restrict__ h, const float* __restrict__ w2,
                          const float* __restrict__ b2, double* __restrict__ rp)
{
    int o = blockIdx.x * 4 + (threadIdx.x >> 6);
    int lane = threadIdx.x & 63;
    int q = o >> 1, r = o & 1;
    double s = 0.0;
    for (int k = lane; k < EE; k += 64)
        s += h[q * 1024 + k] * (double)w2[r * 1024 + k];
#pragma unroll
    for (int off = 32; off > 0; off >>= 1) s += __shfl_down(s, off, 64);
    if (lane == 0) rp[o] = 1.0 / (1.0 + exp(-(s + (double)b2[r])));
}

// wave-parallel so/aw logits (fp64, order-preserving lane-strided sum)
__global__ void offlog_kernel(const float* __restrict__ qe, const float* __restrict__ so_w,
                              const float* __restrict__ so_b, const float* __restrict__ aw_w,
                              const float* __restrict__ aw_b,
                              double* __restrict__ offv_g, double* __restrict__ logit_g)
{
    int o = blockIdx.x * 4 + (threadIdx.x >> 6);
    int lane = threadIdx.x & 63;
    const float* wrow;
    double bias;
    int q;
    if (o < 8192) { q = o >> 7; int j = o & 127; wrow = so_w + (size_t)j * EE; bias = (double)so_b[j]; }
    else          { int r = o - 8192; q = r >> 6; int n = r & 63; wrow = aw_w + (size_t)n * EE; bias = (double)aw_b[n]; }
    double s = 0.0;
    for (int k = lane; k < EE; k += 64)
        s += (double)qe[q * EE + k] * (double)wrow[k];
#pragma unroll
    for (int off = 32; off > 0; off >>= 1) s += __shfl_down(s, off, 64);
    if (lane == 0) {
        if (o < 8192) offv_g[o] = s + bias;
        else          logit_g[o - 8192] = s + bias;
    }
}

// finalize: softmax over p + sampling-point index snap (fp64, exact)
__global__ void offfin_kernel(const double* __restrict__ offv_g, const double* __restrict__ logit_g,
                              const double* __restrict__ rp,
                              float* __restrict__ awf, int* __restrict__ idxv)
{
    int q = blockIdx.x, t = threadIdx.x;   // 64 threads
    int hh = t >> 2, p = t & 3;
    const double* logit = logit_g + q * 64;
    const double* offv  = offv_g + q * 128;
    double l0 = logit[hh * 4 + 0], l1 = logit[hh * 4 + 1];
    double l2 = logit[hh * 4 + 2], l3 = logit[hh * 4 + 3];
    double m = fmax(fmax(l0, l1), fmax(l2, l3));
    double den = exp(l0 - m) + exp(l1 - m) + exp(l2 - m) + exp(l3 - m);
    awf[(q * 16 + hh) * 4 + p] = (float)(exp(logit[hh * 4 + p] - m) / den);
    const int Wss[3] = {24, 12, 8};
    const int starts[3] = {0, 576, 720};
    double ox = offv[(hh * 4 + p) * 2 + 0], oy = offv[(hh * 4 + p) * 2 + 1];
    double rx = rp[q * 2 + 0], ry = rp[q * 2 + 1];
#pragma unroll
    for (int l = 0; l < 3; ++l) {
        int Ws = Wss[l];
        double sx = rx + ox; sx = sx < 0.0 ? 0.0 : (sx > 1.0 ? 1.0 : sx);
        double sy = ry + oy; sy = sy < 0.0 ? 0.0 : (sy > 1.0 ? 1.0 : sy);
        int x0 = (int)floor(sx * (double)(Ws - 1));
        int y0 = (int)floor(sy * (double)(Ws - 1));
        idxv[((l * 64 + q) * 16 + hh) * 4 + p] = starts[l] + y0 * Ws + x0;
    }
}

// vectorized gather: thread = (b,q,h,d8); 16B loads per (l,p) sample
__global__ void gather_kernel(const unsigned short* __restrict__ value, const float* __restrict__ awf,
                              const int* __restrict__ idxv, unsigned short* __restrict__ out0)
{
    int idx = blockIdx.x * 256 + threadIdx.x;     // 524288 threads
    int d8 = idx & 7;
    int h  = (idx >> 3) & 15;
    int bq = idx >> 7;                            // b*64+q
    int b  = bq >> 6, q = bq & 63;
    float s[8] = {0.f};
#pragma unroll
    for (int l = 0; l < 3; ++l)
#pragma unroll
        for (int p = 0; p < 4; ++p) {
            int row = idxv[((l * 64 + q) * 16 + h) * 4 + p];
            float wgt = awf[(q * 16 + h) * 4 + p];
            ushort8 v = *(const ushort8*)(value + ((size_t)(b * ROWS_TOT + row)) * 1024 + h * 64 + d8 * 8);
#pragma unroll
            for (int i = 0; i < 8; ++i) s[i] += wgt * b2f(v[i]);
        }
    ushort8 o;
#pragma unroll
    for (int i = 0; i < 8; ++i) o[i] = f2b(s[i]);
    *(ushort8*)(out0 + (size_t)bq * 1024 + h * 64 + d8 * 8) = o;
}

// LayerNorm over 1024: bf16 in, bf16 out; fp32 stats; us4 vector access
__global__ void ln_b2b_kernel(const unsigned short* __restrict__ x, const float* __restrict__ g,
                              const float* __restrict__ bb, unsigned short* __restrict__ y)
{
    __shared__ float red[256];
    __shared__ float stats[2];
    int r = blockIdx.x, t = threadIdx.x;
    us4 v4 = *(const us4*)(x + (size_t)r * 1024 + t * 4);
    float v[4];
#pragma unroll
    for (int i = 0; i < 4; ++i) v[i] = b2f(v4[i]);
    float s = v[0] + v[1] + v[2] + v[3];
    red[t] = s; __syncthreads();
    for (int o = 128; o; o >>= 1) { if (t < o) red[t] += red[t + o]; __syncthreads(); }
    if (t == 0) stats[0] = red[0] / 1024.f;
    __syncthreads();
    float mean = stats[0];
    float d = 0.f;
#pragma unroll
    for (int i = 0; i < 4; ++i) { float dd = v[i] - mean; d += dd * dd; }
    red[t] = d; __syncthreads();
    for (int o = 128; o; o >>= 1) { if (t < o) red[t] += red[t + o]; __syncthreads(); }
    if (t == 0) stats[1] = red[0] / 1024.f;
    __syncthreads();
    float inv = 1.f / sqrtf(stats[1] + 1e-5f);
    us4 o4;
#pragma unroll
    for (int i = 0; i < 4; ++i) {
        int c = t * 4 + i;
        o4[i] = f2b((v[i] - mean) * inv * g[c] + bb[c]);
    }
    *(us4*)(y + (size_t)r * 1024 + t * 4) = o4;
}

extern "C" void kernel_launch(void* const* d_in, const int* in_sizes, int n_in,
                              void* d_out, int out_size, void* d_ws, size_t ws_size,
                              hipStream_t stream)
{
    const float* features  = (const float*)d_in[0];
    const float* p1_w      = (const float*)d_in[1];
    const float* p1_b      = (const float*)d_in[2];
    const float* p2_w      = (const float*)d_in[3];
    const float* p2_b      = (const float*)d_in[4];
    const float* p3_w      = (const float*)d_in[5];
    const float* p3_b      = (const float*)d_in[6];
    const float* query_emb = (const float*)d_in[7];
    const float* rg_w1     = (const float*)d_in[8];
    const float* rg_b1     = (const float*)d_in[9];
    const float* rg_g      = (const float*)d_in[10];
    const float* rg_b      = (const float*)d_in[11];
    const float* rg_w2     = (const float*)d_in[12];
    const float* rg_b2     = (const float*)d_in[13];
    const float* so_w      = (const float*)d_in[14];
    const float* so_b      = (const float*)d_in[15];
    const float* aw_w      = (const float*)d_in[16];
    const float* aw_b      = (const float*)d_in[17];
    const float* vp_w      = (const float*)d_in[18];
    const float* vp_b      = (const float*)d_in[19];
    const float* op_w      = (const float*)d_in[20];
    const float* op_b      = (const float*)d_in[21];
    const float* fln_g     = (const float*)d_in[22];
    const float* fln_b     = (const float*)d_in[23];
    const float* fin_w     = (const float*)d_in[24];
    const float* fin_b     = (const float*)d_in[25];
    float* out = (float*)d_out;

    // ---- workspace layout (bytes) ----
    char* p = (char*)d_ws;
    unsigned short* FEAT = (unsigned short*)p; p += 56623104;   // bf16 [B*576,768]
    unsigned short* PT   = (unsigned short*)p; p += 22020096;   // [10752,1024] stacked p_w^T
    unsigned short* WW   = (unsigned short*)p; p += 22020096;   // [1024,10752] fused weights
    unsigned short* VPW  = (unsigned short*)p; p += 2097152;
    unsigned short* VAL  = (unsigned short*)p; p += 102760448;  // value bf16 [64*784,1024]
    unsigned short* PART = (unsigned short*)p; p += 75497472;   // bf16 partials (L2: 3x, L3: 4x)
    unsigned short* OPO  = (unsigned short*)p; p += 8388608;    // bf16 [4096,1024] op-proj out
    unsigned short* OUT0 = (unsigned short*)p; p += 8388608;
    unsigned short* LNO  = (unsigned short*)p; p += 8388608;
    unsigned short* OPW  = (unsigned short*)p; p += 2097152;
    unsigned short* FINW = (unsigned short*)p; p += 2097152;
    float* b1p  = (float*)p; p += 4096;
    float* b2p  = (float*)p; p += 4096;
    float* b3p  = (float*)p; p += 4096;
    float* awf  = (float*)p; p += 16384;
    int*   idxv = (int*)p;   p += 49152;
    double* h0  = (double*)p; p += 524288;
    double* hb  = (double*)p; p += 524288;
    double* rp  = (double*)p; p += 1024;
    double* offv_g  = (double*)p; p += 65536;   // [64,128]
    double* logit_g = (double*)p; p += 32768;   // [64,64]

    dim3 blk(256);

    // ---- query branch (fp64, batch-independent) ----
    rg1_kernel<<<16384, blk, 0, stream>>>(query_emb, rg_w1, rg_b1, h0);
    ln_gelu_kernel<<<64, blk, 0, stream>>>(h0, rg_g, rg_b, hb);
    rp_kernel<<<32, blk, 0, stream>>>(hb, rg_w2, rg_b2, rp);
    offlog_kernel<<<3072, blk, 0, stream>>>(query_emb, so_w, so_b, aw_w, aw_b, offv_g, logit_g);
    offfin_kernel<<<64, 64, 0, stream>>>(offv_g, logit_g, rp, awf, idxv);

    // ---- merged prep: all conversions + transposes + fused biases ----
    prep_kernel<<<26880, blk, 0, stream>>>(features, FEAT, vp_w, VPW, op_w, OPW, fin_w, FINW,
                                           p1_w, p2_w, p3_w, PT,
                                           vp_b, p1_b, p2_b, p3_b, b1p, b2p, b3p);

    // ---- fused weights: WW[1024,10752] = VPW @ PT^T  (BK=64 kernel) ----
    gemm2w<true><<<dim3(84, 8), blk, 0, stream>>>(VPW, PT, nullptr, WW, 1024, WWN, 1024);

    // ---- value GEMMs, 256x256 BK=64 tiles, per level; L2 z=3 ----
    gemm256<1, false><<<dim3(4, 144),    512, 0, stream>>>(FEAT, WW, b1p, VAL, 12, 0);
    gemm256<2, true><<<dim3(4, 36, 3),   512, 0, stream>>>(FEAT, WW, nullptr, PART, 16, 9437184);
    gemm256<3, true><<<dim3(4, 16, 4),   512, 0, stream>>>(FEAT, WW, nullptr, PART + 3 * 9437184, 27, 4194304);
    reduce_both_kernel<<<6656, blk, 0, stream>>>(PART, PART + 3 * 9437184, b2p, b3p, VAL);

    // ---- deformable gather (vectorized 16B/lane) ----
    gather_kernel<<<2048, blk, 0, stream>>>(VAL, awf, idxv, OUT0);

    // ---- output projection (bf16 out) + LN (bf16->bf16) + final projection ----
    gemm2w<true><<<dim3(8, 32), blk, 0, stream>>>(OUT0, OPW, op_b, OPO, 4096, 1024, 1024);
    ln_b2b_kernel<<<4096, blk, 0, stream>>>(OPO, fln_g, fln_b, LNO);
    gemm2w<false><<<dim3(8, 32), blk, 0, stream>>>(LNO, FINW, fin_b, out, 4096, 1024, 1024);
}

// Round 16
// 461.981 us; speedup vs baseline: 1.4114x; 1.1041x over previous
//
#include <hip/hip_runtime.h>
#include <math.h>

#define EE 1024
#define ROWS_TOT 784   // 576 + 144 + 64
#define WWN 10752      // 768 + 3072 + 6912

typedef __attribute__((ext_vector_type(4))) float f4;
typedef __attribute__((ext_vector_type(4))) float f32x4;
typedef __attribute__((ext_vector_type(8))) __bf16 bf16x8;
typedef __attribute__((ext_vector_type(8))) unsigned short ushort8;
typedef __attribute__((ext_vector_type(4))) unsigned short us4;

__device__ __forceinline__ unsigned short f2b(float x) {
    unsigned int u = __float_as_uint(x);
    unsigned int r = (u + 0x7fffu + ((u >> 16) & 1u)) >> 16;
    return (unsigned short)r;
}
__device__ __forceinline__ float b2f(unsigned short u) {
    unsigned int v = ((unsigned int)u) << 16;
    return __uint_as_float(v);
}

#define GLOAD16(g, l) __builtin_amdgcn_global_load_lds( \
    (const __attribute__((address_space(1))) unsigned int*)(g), \
    (__attribute__((address_space(3))) unsigned int*)(l), 16, 0, 0)

// ---------------------------------------------------------------------------
// Value-GEMM body: 256x256, BK=64, 8 waves (2m x 4n), per-wave 128x64.
// Round-10/12 proven K-loop (T3/T4/T5 schedule, 128B-row swizzle s^(r&7)).
// Fully compile-time specialized per (MODE, SPLIT, KT). LDS passed in.
// SPLIT: outp = bf16 partial slice (pre-offset by caller), no bias.
// ---------------------------------------------------------------------------
template<int MODE, bool SPLIT, int KT>
__device__ __forceinline__ void gemm_body(
    unsigned short* __restrict__ AsB, unsigned short* __restrict__ BsB,
    const unsigned short* __restrict__ FEAT, const unsigned short* __restrict__ WW,
    const float* __restrict__ bias, void* __restrict__ outp,
    int by, int bx, int ktBase)
{
    constexpr int gw = (MODE == 1) ? 24 : (MODE == 2 ? 12 : 8);
    constexpr int Rl = gw * gw;                                   // 576/144/64
    constexpr int colOff = (MODE == 1) ? 0 : (MODE == 2 ? 768 : 3840);
    constexpr int rowOff = (MODE == 1) ? 0 : (MODE == 2 ? 576 : 720);

    const int t = threadIdx.x;
    const int lane = t & 63;
    const int w = t >> 6;                // 0..7
    const int wm = w >> 2;               // 0..1  (128-row half)
    const int wn = w & 3;                // 0..3  (64-col quarter)
    const int m0 = by * 256, n0 = bx * 256;

    f32x4 acc[8][4] = {};

    // ---- staging roles: 4 gloads per operand per wave (32 rows x 128B) ----
    const int srow = lane >> 3;                  // 0..7 row within 8-row gload
    const int sseg = lane & 7;                   // stored 16B slot 0..7
    const int sgx  = sseg ^ srow;                // pre-swizzled global chunk
    int rbA[4];
#pragma unroll
    for (int g = 0; g < 4; ++g) {
        int gr = m0 + w * 32 + g * 8 + srow;
        if (MODE == 1) rbA[g] = gr;
        else {
            int b_ = gr / Rl, rl = gr - b_ * Rl;
            rbA[g] = b_ * 576 + (MODE * (rl / gw)) * 24 + MODE * (rl % gw);
        }
    }
    const unsigned short* gBbase = WW + (size_t)(n0 + w * 32 + srow) * WWN + colOff + sgx * 8;

    // ---- fragment-read roles ----
    const int fr = lane & 15;
    const int kg = lane >> 4;
    const int kgx0 = kg ^ (fr & 7);              // kk=0 slot
    const int kgx1 = kgx0 ^ 4;                   // kk=1 slot
    const int aOff0 = (wm * 128 + fr) * 64 + kgx0 * 8;
    const int aOff1 = (wm * 128 + fr) * 64 + kgx1 * 8;
    const int bOff0 = (wn * 64 + fr) * 64 + kgx0 * 8;
    const int bOff1 = (wn * 64 + fr) * 64 + kgx1 * 8;

    auto STAGE = [&](int buf, int ktl) {
        int kt = ktBase + ktl;                   // BK=64 tile index
        int s = kt / 12;                         // which 768-chunk of K
        int within = (kt - s * 12) * 64;         // + sgx*8 stays within the chunk
        int add = 0;
        if (MODE == 2)      add = (s >> 1) * 24 + (s & 1);
        else if (MODE == 3) { int di = s / 3; add = di * 24 + (s - 3 * di); }
        unsigned short* Asb = AsB + buf * 16384;
        unsigned short* Bsb = BsB + buf * 16384;
#pragma unroll
        for (int g = 0; g < 4; ++g)
            GLOAD16(FEAT + (size_t)(rbA[g] + add) * 768 + within + sgx * 8,
                    Asb + (w * 32 + g * 8) * 64);
#pragma unroll
        for (int g = 0; g < 4; ++g)
            GLOAD16(gBbase + (size_t)(g * 8) * WWN + (size_t)kt * 64,
                    Bsb + (w * 32 + g * 8) * 64);
    };

    int cur = 0;
    STAGE(0, 0);

    for (int tt = 0; tt < KT; ++tt) {
        // boundary: wait only for the stage issued one full iteration ago
        asm volatile("s_waitcnt vmcnt(0)" ::: "memory");
        __builtin_amdgcn_s_barrier();
        __builtin_amdgcn_sched_barrier(0);

        if (tt + 1 < KT) STAGE(cur ^ 1, tt + 1);        // in flight across phases
        __builtin_amdgcn_sched_barrier(0);

        const unsigned short* Asc = AsB + cur * 16384;
        const unsigned short* Bsc = BsB + cur * 16384;

        // ---- phase kk=0: K elems [0,32), 32 MFMA ----
        {
            bf16x8 bf[4], af[8];
#pragma unroll
            for (int j = 0; j < 4; ++j) bf[j] = *(const bf16x8*)(Bsc + bOff0 + j * 1024);
#pragma unroll
            for (int i = 0; i < 8; ++i) af[i] = *(const bf16x8*)(Asc + aOff0 + i * 1024);
            __builtin_amdgcn_s_setprio(1);
#pragma unroll
            for (int i = 0; i < 8; ++i)
#pragma unroll
                for (int j = 0; j < 4; ++j)
                    acc[i][j] = __builtin_amdgcn_mfma_f32_16x16x32_bf16(af[i], bf[j], acc[i][j], 0, 0, 0);
            __builtin_amdgcn_s_setprio(0);
        }
        __builtin_amdgcn_s_barrier();
        __builtin_amdgcn_sched_barrier(0);

        // ---- phase kk=1: K elems [32,64), 32 MFMA ----
        {
            bf16x8 bf[4], af[8];
#pragma unroll
            for (int j = 0; j < 4; ++j) bf[j] = *(const bf16x8*)(Bsc + bOff1 + j * 1024);
#pragma unroll
            for (int i = 0; i < 8; ++i) af[i] = *(const bf16x8*)(Asc + aOff1 + i * 1024);
            __builtin_amdgcn_s_setprio(1);
#pragma unroll
            for (int i = 0; i < 8; ++i)
#pragma unroll
                for (int j = 0; j < 4; ++j)
                    acc[i][j] = __builtin_amdgcn_mfma_f32_16x16x32_bf16(af[i], bf[j], acc[i][j], 0, 0, 0);
            __builtin_amdgcn_s_setprio(0);
        }
        cur ^= 1;
    }

#pragma unroll
    for (int i = 0; i < 8; ++i) {
#pragma unroll
        for (int r = 0; r < 4; ++r) {
            int m = m0 + wm * 128 + i * 16 + kg * 4 + r;   // local level row
#pragma unroll
            for (int j = 0; j < 4; ++j) {
                int n = n0 + wn * 64 + j * 16 + fr;
                if (SPLIT) {
                    ((unsigned short*)outp)[(size_t)m * EE + n] = f2b(acc[i][j][r]);
                } else {
                    int b_o = m / Rl, rl_o = m - b_o * Rl;
                    int crow = b_o * ROWS_TOT + rowOff + rl_o;
                    ((unsigned short*)outp)[(size_t)crow * EE + n] = f2b(acc[i][j][r] + bias[n]);
                }
            }
        }
    }
}

// ---------------------------------------------------------------------------
// MERGED value GEMM dispatch, LPT order (long blocks first) with per-segment
// bijective XCD swizzle. hw blocks [0,256)=L3 (27 steps), [256,688)=L2 (16),
// [688,1264)=L1 (12). Each path is a compile-time template instantiation.
// ---------------------------------------------------------------------------
__global__ __launch_bounds__(512, 2) void gemm_val_merged(
    const unsigned short* __restrict__ FEAT, const unsigned short* __restrict__ WW,
    const float* __restrict__ b1, unsigned short* __restrict__ VAL,
    unsigned short* __restrict__ PART2, unsigned short* __restrict__ PART3)
{
    __shared__ unsigned short As[2 * 256 * 64];   // 64KB
    __shared__ unsigned short Bs[2 * 256 * 64];   // 64KB

    int bid = blockIdx.x;
    if (bid < 256) {
        // L3: 4 z-slices x 64 tiles; chunk = 256/8 = 32
        int s = ((bid & 7) << 5) | (bid >> 3);
        int z = s >> 6, r = s & 63;
        gemm_body<3, true, 27>(As, Bs, FEAT, WW, nullptr,
                               PART3 + (size_t)z * 4194304, r >> 2, r & 3, z * 27);
    } else if (bid < 688) {
        // L2: 3 z-slices x 144 tiles; chunk = 432/8 = 54
        int j = bid - 256;
        int s = (j & 7) * 54 + (j >> 3);
        int z = s / 144, r = s - z * 144;
        gemm_body<2, true, 16>(As, Bs, FEAT, WW, nullptr,
                               PART2 + (size_t)z * 9437184, r >> 2, r & 3, z * 16);
    } else {
        // L1: 576 tiles; chunk = 576/8 = 72
        int j = bid - 688;
        int s = (j & 7) * 72 + (j >> 3);
        gemm_body<1, false, 12>(As, Bs, FEAT, WW, b1, VAL, s >> 2, s & 3, 0);
    }
}

// merged reduce: blocks [0,4608) = L2 (3 slices); [4608,6656) = L3 (4 slices)
__global__ void reduce_both_kernel(const unsigned short* __restrict__ P2, const unsigned short* __restrict__ P3,
                                   const float* __restrict__ b2, const float* __restrict__ b3,
                                   unsigned short* __restrict__ VAL)
{
    int blk = blockIdx.x;
    const unsigned short* P;
    const float* bb;
    size_t stride;
    int nsl;
    int isL2 = (blk < 4608);
    if (isL2) { P = P2; bb = b2; stride = 9437184; nsl = 3; }
    else      { P = P3; bb = b3; stride = 4194304; nsl = 4; blk -= 4608; }
    size_t e0 = ((size_t)blk * 256 + threadIdx.x) * 8;
    int m = (int)(e0 >> 10);
    int n = (int)(e0 & 1023);
    float s[8] = {0.f};
    for (int k = 0; k < nsl; ++k) {
        ushort8 a = *(const ushort8*)(P + (size_t)k * stride + e0);
#pragma unroll
        for (int i = 0; i < 8; ++i) s[i] += b2f(a[i]);
    }
    int crow;
    if (isL2) crow = (m / 144) * ROWS_TOT + 576 + (m % 144);
    else      crow = (m >> 6) * ROWS_TOT + 720 + (m & 63);
    ushort8 o;
#pragma unroll
    for (int i = 0; i < 8; ++i) o[i] = f2b(s[i] + bb[n + i]);
    *(ushort8*)(VAL + (size_t)crow * EE + n) = o;
}

// ---------------------------------------------------------------------------
// 128x128 GEMM, BK=64, 4 waves (2x2) — round-15 proven.
// ---------------------------------------------------------------------------
template<bool OB>
__global__ __launch_bounds__(256, 2) void gemm2w(
    const unsigned short* __restrict__ A, const unsigned short* __restrict__ Bw,
    const float* __restrict__ bias, void* __restrict__ Cv,
    int M, int N, int K)
{
    __shared__ unsigned short As[2][128 * 64];   // 16KB each
    __shared__ unsigned short Bs[2][128 * 64];

    const int t = threadIdx.x;
    const int lane = t & 63;
    const int w = t >> 6;                // 0..3
    const int wm = w >> 1, wn = w & 1;

    int nwg = gridDim.x * gridDim.y;
    int bid = blockIdx.y * gridDim.x + blockIdx.x;
    int chunk = nwg >> 3;
    int swz = (bid & 7) * chunk + (bid >> 3);
    int by = swz / gridDim.x, bx = swz % gridDim.x;
    const int m0 = by * 128, n0 = bx * 128;

    f32x4 acc[4][4] = {};

    const int srow = lane >> 3;                  // 0..7
    const int sseg = lane & 7;
    const int sgx  = sseg ^ srow;
    const unsigned short* gA = A + (size_t)(m0 + w * 32 + srow) * K + sgx * 8;
    const unsigned short* gB = Bw + (size_t)(n0 + w * 32 + srow) * K + sgx * 8;

    const int fr = lane & 15;
    const int kg = lane >> 4;
    const int kgx0 = kg ^ (fr & 7);
    const int kgx1 = kgx0 ^ 4;
    const int aOff0 = (wm * 64 + fr) * 64 + kgx0 * 8;
    const int aOff1 = (wm * 64 + fr) * 64 + kgx1 * 8;
    const int bOff0 = (wn * 64 + fr) * 64 + kgx0 * 8;
    const int bOff1 = (wn * 64 + fr) * 64 + kgx1 * 8;

    auto STAGE = [&](int buf, int kt) {
        size_t k0 = (size_t)kt * 64;
#pragma unroll
        for (int g = 0; g < 4; ++g)
            GLOAD16(gA + (size_t)(g * 8) * K + k0, &As[buf][(w * 32 + g * 8) * 64]);
#pragma unroll
        for (int g = 0; g < 4; ++g)
            GLOAD16(gB + (size_t)(g * 8) * K + k0, &Bs[buf][(w * 32 + g * 8) * 64]);
    };

    const int nt = K >> 6;
    int cur = 0;
    STAGE(0, 0);

    for (int tt = 0; tt < nt; ++tt) {
        asm volatile("s_waitcnt vmcnt(0)" ::: "memory");
        __builtin_amdgcn_s_barrier();
        __builtin_amdgcn_sched_barrier(0);

        if (tt + 1 < nt) STAGE(cur ^ 1, tt + 1);
        __builtin_amdgcn_sched_barrier(0);

        // phase kk=0
        {
            bf16x8 bf[4], af[4];
#pragma unroll
            for (int j = 0; j < 4; ++j) bf[j] = *(const bf16x8*)(&Bs[cur][bOff0] + j * 1024);
#pragma unroll
            for (int i = 0; i < 4; ++i) af[i] = *(const bf16x8*)(&As[cur][aOff0] + i * 1024);
            __builtin_amdgcn_s_setprio(1);
#pragma unroll
            for (int i = 0; i < 4; ++i)
#pragma unroll
                for (int j = 0; j < 4; ++j)
                    acc[i][j] = __builtin_amdgcn_mfma_f32_16x16x32_bf16(af[i], bf[j], acc[i][j], 0, 0, 0);
            __builtin_amdgcn_s_setprio(0);
        }
        __builtin_amdgcn_s_barrier();
        __builtin_amdgcn_sched_barrier(0);

        // phase kk=1
        {
            bf16x8 bf[4], af[4];
#pragma unroll
            for (int j = 0; j < 4; ++j) bf[j] = *(const bf16x8*)(&Bs[cur][bOff1] + j * 1024);
#pragma unroll
            for (int i = 0; i < 4; ++i) af[i] = *(const bf16x8*)(&As[cur][aOff1] + i * 1024);
            __builtin_amdgcn_s_setprio(1);
#pragma unroll
            for (int i = 0; i < 4; ++i)
#pragma unroll
                for (int j = 0; j < 4; ++j)
                    acc[i][j] = __builtin_amdgcn_mfma_f32_16x16x32_bf16(af[i], bf[j], acc[i][j], 0, 0, 0);
            __builtin_amdgcn_s_setprio(0);
        }
        cur ^= 1;
    }

#pragma unroll
    for (int i = 0; i < 4; ++i) {
#pragma unroll
        for (int r = 0; r < 4; ++r) {
            int m = m0 + wm * 64 + i * 16 + kg * 4 + r;
#pragma unroll
            for (int j = 0; j < 4; ++j) {
                int n = n0 + wn * 64 + j * 16 + fr;
                float v = acc[i][j][r];
                if (bias) v += bias[n];
                if (OB) ((unsigned short*)Cv)[(size_t)m * N + n] = f2b(v);
                else    ((float*)Cv)[(size_t)m * N + n] = v;
            }
        }
    }
}

// ---------------------------------------------------------------------------
// MERGED prep dispatch (round-12 proven)
// ---------------------------------------------------------------------------
__global__ void prep_kernel(const float* __restrict__ feat, unsigned short* __restrict__ FEAT,
                            const float* __restrict__ vpw, unsigned short* __restrict__ VPW,
                            const float* __restrict__ opw, unsigned short* __restrict__ OPW,
                            const float* __restrict__ finw, unsigned short* __restrict__ FINW,
                            const float* __restrict__ p1, const float* __restrict__ p2,
                            const float* __restrict__ p3, unsigned short* __restrict__ PT,
                            const float* __restrict__ vp_b,
                            const float* __restrict__ pb1, const float* __restrict__ pb2,
                            const float* __restrict__ pb3,
                            float* __restrict__ o1, float* __restrict__ o2, float* __restrict__ o3)
{
    __shared__ float tile[32][33];
    int blk = blockIdx.x;
    if (blk < 15360) {
        const float* in; unsigned short* out;
        if (blk < 13824)       { in = feat; out = FEAT; }
        else if (blk < 14336)  { in = vpw;  out = VPW;  blk -= 13824; }
        else if (blk < 14848)  { in = opw;  out = OPW;  blk -= 14336; }
        else                   { in = finw; out = FINW; blk -= 14848; }
        size_t i = ((size_t)blk * 256 + threadIdx.x) * 8;
        f4 x = *(const f4*)(in + i);
        f4 y = *(const f4*)(in + i + 4);
        ushort8 o;
        o[0] = f2b(x[0]); o[1] = f2b(x[1]); o[2] = f2b(x[2]); o[3] = f2b(x[3]);
        o[4] = f2b(y[0]); o[5] = f2b(y[1]); o[6] = f2b(y[2]); o[7] = f2b(y[3]);
        *(ushort8*)(out + i) = o;
    } else if (blk < 26112) {
        int fl = blk - 15360;
        int bx = fl % 336, byy = fl / 336;
        const float* in; unsigned short* out; int C;
        if (bx < 24)       { in = p1; out = PT;                C = 768; }
        else if (bx < 120) { in = p2; out = PT + 768  * 1024;  C = 3072; bx -= 24; }
        else               { in = p3; out = PT + 3840 * 1024;  C = 6912; bx -= 120; }
        const int R = 1024;
        int c0 = bx * 32, r0 = byy * 32;
        int tx = threadIdx.x & 31, ty = threadIdx.x >> 5;
#pragma unroll
        for (int i = 0; i < 32; i += 8)
            tile[ty + i][tx] = in[(size_t)(r0 + ty + i) * C + c0 + tx];
        __syncthreads();
#pragma unroll
        for (int i = 0; i < 32; i += 8)
            out[(size_t)(c0 + ty + i) * R + r0 + tx] = f2b(tile[tx][ty + i]);
    } else {
        int b = blk - 26112;
        const float* pb; float* bout;
        if (b < 256)      { pb = pb1; bout = o1; }
        else if (b < 512) { pb = pb2; bout = o2; b -= 256; }
        else              { pb = pb3; bout = o3; b -= 512; }
        int e = b * 4 + (threadIdx.x >> 6);
        int lane = threadIdx.x & 63;
        float s = 0.f;
        for (int k = lane; k < EE; k += 64) s += vpw[(size_t)e * EE + k] * pb[k];
#pragma unroll
        for (int o = 32; o > 0; o >>= 1) s += __shfl_down(s, o, 64);
        if (lane == 0) bout[e] = s + vp_b[e];
    }
}

// ---------------------------------------------------------------------------
// Query branch (batch-independent), fp64 — semantics preserved exactly
// ---------------------------------------------------------------------------
__global__ void rg1_kernel(const float* __restrict__ qe, const float* __restrict__ w,
                           const float* __restrict__ b, double* __restrict__ h0)
{
    int o = blockIdx.x * 4 + (threadIdx.x >> 6);
    int lane = threadIdx.x & 63;
    int q = o >> 10, n = o & 1023;
    double s = 0.0;
    for (int k = lane; k < EE; k += 64)
        s += (double)qe[q * EE + k] * (double)w[(size_t)n * EE + k];
#pragma unroll
    for (int off = 32; off > 0; off >>= 1) s += __shfl_down(s, off, 64);
    if (lane == 0) h0[o] = s + (double)b[n];
}

// merged LN+GELU+rp: block q computes gelu(LN(h0[q,:])) into shared, then
// waves 0/1 compute the two rp dots with the exact rp_kernel summation order
__global__ void ln_gelu_rp_kernel(const double* __restrict__ h0, const float* __restrict__ g,
                                  const float* __restrict__ bb, const float* __restrict__ w2,
                                  const float* __restrict__ b2, double* __restrict__ rp)
{
    __shared__ double red[256];
    __shared__ double stats[2];
    __shared__ double hsh[1024];
    int q = blockIdx.x, t = threadIdx.x;
    double x[4];
#pragma unroll
    for (int i = 0; i < 4; ++i) x[i] = h0[q * 1024 + t + i * 256];
    double s = x[0] + x[1] + x[2] + x[3];
    red[t] = s; __syncthreads();
    for (int o = 128; o; o >>= 1) { if (t < o) red[t] += red[t + o]; __syncthreads(); }
    if (t == 0) stats[0] = red[0] / 1024.0;
    __syncthreads();
    double mean = stats[0];
    double d = 0.0;
#pragma unroll
    for (int i = 0; i < 4; ++i) { double dd = x[i] - mean; d += dd * dd; }
    red[t] = d; __syncthreads();
    for (int o = 128; o; o >>= 1) { if (t < o) red[t] += red[t + o]; __syncthreads(); }
    if (t == 0) stats[1] = red[0] / 1024.0;
    __syncthreads();
    double inv = 1.0 / sqrt(stats[1] + 1e-5);
#pragma unroll
    for (int i = 0; i < 4; ++i) {
        int c = t + i * 256;
        double y = (x[i] - mean) * inv * (double)g[c] + (double)bb[c];
        hsh[c] = y * 0.5 * (1.0 + erf(y * 0.70710678118654752440));
    }
    __syncthreads();
    if (t < 128) {
        int r = t >> 6;                 // wave 0 -> r=0, wave 1 -> r=1
        int lane = t & 63;
        double sv = 0.0;
        for (int k = lane; k < EE; k += 64)
            sv += hsh[k] * (double)w2[r * 1024 + k];
#pragma unroll
        for (int off = 32; off > 0; off >>= 1) sv += __shfl_down(sv, off, 64);
        if (lane == 0) rp[q * 2 + r] = 1.0 / (1.0 + exp(-(sv + (double)b2[r])));
    }
}

// wave-parallel so/aw logits (fp64, order-preserving lane-strided sum)
__global__ void offlog_kernel(const float* __restrict__ qe, const float* __restrict__ so_w,
                              const float* __restrict__ so_b, const float* __restrict__ aw_w,
                              const float* __restrict__ aw_b,
                              double* __restrict__ offv_g, double* __restrict__ logit_g)
{
    int o = blockIdx.x * 4 + (threadIdx.x >> 6);
    int lane = threadIdx.x & 63;
    const float* wrow;
    double bias;
    int q;
    if (o < 8192) { q = o >> 7; int j = o & 127; wrow = so_w + (size_t)j * EE; bias = (double)so_b[j]; }
    else          { int r = o - 8192; q = r >> 6; int n = r & 63; wrow = aw_w + (size_t)n * EE; bias = (double)aw_b[n]; }
    double s = 0.0;
    for (int k = lane; k < EE; k += 64)
        s += (double)qe[q * EE + k] * (double)wrow[k];
#pragma unroll
    for (int off = 32; off > 0; off >>= 1) s += __shfl_down(s, off, 64);
    if (lane == 0) {
        if (o < 8192) offv_g[o] = s + bias;
        else          logit_g[o - 8192] = s + bias;
    }
}

// finalize: softmax over p + sampling-point index snap (fp64, exact)
__global__ void offfin_kernel(const double* __restrict__ offv_g, const double* __restrict__ logit_g,
                              const double* __restrict__ rp,
                              float* __restrict__ awf, int* __restrict__ idxv)
{
    int q = blockIdx.x, t = threadIdx.x;   // 64 threads
    int hh = t >> 2, p = t & 3;
    const double* logit = logit_g + q * 64;
    const double* offv  = offv_g + q * 128;
    double l0 = logit[hh * 4 + 0], l1 = logit[hh * 4 + 1];
    double l2 = logit[hh * 4 + 2], l3 = logit[hh * 4 + 3];
    double m = fmax(fmax(l0, l1), fmax(l2, l3));
    double den = exp(l0 - m) + exp(l1 - m) + exp(l2 - m) + exp(l3 - m);
    awf[(q * 16 + hh) * 4 + p] = (float)(exp(logit[hh * 4 + p] - m) / den);
    const int Wss[3] = {24, 12, 8};
    const int starts[3] = {0, 576, 720};
    double ox = offv[(hh * 4 + p) * 2 + 0], oy = offv[(hh * 4 + p) * 2 + 1];
    double rx = rp[q * 2 + 0], ry = rp[q * 2 + 1];
#pragma unroll
    for (int l = 0; l < 3; ++l) {
        int Ws = Wss[l];
        double sx = rx + ox; sx = sx < 0.0 ? 0.0 : (sx > 1.0 ? 1.0 : sx);
        double sy = ry + oy; sy = sy < 0.0 ? 0.0 : (sy > 1.0 ? 1.0 : sy);
        int x0 = (int)floor(sx * (double)(Ws - 1));
        int y0 = (int)floor(sy * (double)(Ws - 1));
        idxv[((l * 64 + q) * 16 + hh) * 4 + p] = starts[l] + y0 * Ws + x0;
    }
}

// vectorized gather: thread = (b,q,h,d8); 16B loads per (l,p) sample
__global__ void gather_kernel(const unsigned short* __restrict__ value, const float* __restrict__ awf,
                              const int* __restrict__ idxv, unsigned short* __restrict__ out0)
{
    int idx = blockIdx.x * 256 + threadIdx.x;     // 524288 threads
    int d8 = idx & 7;
    int h  = (idx >> 3) & 15;
    int bq = idx >> 7;                            // b*64+q
    int b  = bq >> 6, q = bq & 63;
    float s[8] = {0.f};
#pragma unroll
    for (int l = 0; l < 3; ++l)
#pragma unroll
        for (int p = 0; p < 4; ++p) {
            int row = idxv[((l * 64 + q) * 16 + h) * 4 + p];
            float wgt = awf[(q * 16 + h) * 4 + p];
            ushort8 v = *(const ushort8*)(value + ((size_t)(b * ROWS_TOT + row)) * 1024 + h * 64 + d8 * 8);
#pragma unroll
            for (int i = 0; i < 8; ++i) s[i] += wgt * b2f(v[i]);
        }
    ushort8 o;
#pragma unroll
    for (int i = 0; i < 8; ++i) o[i] = f2b(s[i]);
    *(ushort8*)(out0 + (size_t)bq * 1024 + h * 64 + d8 * 8) = o;
}

// LayerNorm over 1024: bf16 in, bf16 out; fp32 stats; us4 vector access
__global__ void ln_b2b_kernel(const unsigned short* __restrict__ x, const float* __restrict__ g,
                              const float* __restrict__ bb, unsigned short* __restrict__ y)
{
    __shared__ float red[256];
    __shared__ float stats[2];
    int r = blockIdx.x, t = threadIdx.x;
    us4 v4 = *(const us4*)(x + (size_t)r * 1024 + t * 4);
    float v[4];
#pragma unroll
    for (int i = 0; i < 4; ++i) v[i] = b2f(v4[i]);
    float s = v[0] + v[1] + v[2] + v[3];
    red[t] = s; __syncthreads();
    for (int o = 128; o; o >>= 1) { if (t < o) red[t] += red[t + o]; __syncthreads(); }
    if (t == 0) stats[0] = red[0] / 1024.f;
    __syncthreads();
    float mean = stats[0];
    float d = 0.f;
#pragma unroll
    for (int i = 0; i < 4; ++i) { float dd = v[i] - mean; d += dd * dd; }
    red[t] = d; __syncthreads();
    for (int o = 128; o; o >>= 1) { if (t < o) red[t] += red[t + o]; __syncthreads(); }
    if (t == 0) stats[1] = red[0] / 1024.f;
    __syncthreads();
    float inv = 1.f / sqrtf(stats[1] + 1e-5f);
    us4 o4;
#pragma unroll
    for (int i = 0; i < 4; ++i) {
        int c = t * 4 + i;
        o4[i] = f2b((v[i] - mean) * inv * g[c] + bb[c]);
    }
    *(us4*)(y + (size_t)r * 1024 + t * 4) = o4;
}

extern "C" void kernel_launch(void* const* d_in, const int* in_sizes, int n_in,
                              void* d_out, int out_size, void* d_ws, size_t ws_size,
                              hipStream_t stream)
{
    const float* features  = (const float*)d_in[0];
    const float* p1_w      = (const float*)d_in[1];
    const float* p1_b      = (const float*)d_in[2];
    const float* p2_w      = (const float*)d_in[3];
    const float* p2_b      = (const float*)d_in[4];
    const float* p3_w      = (const float*)d_in[5];
    const float* p3_b      = (const float*)d_in[6];
    const float* query_emb = (const float*)d_in[7];
    const float* rg_w1     = (const float*)d_in[8];
    const float* rg_b1     = (const float*)d_in[9];
    const float* rg_g      = (const float*)d_in[10];
    const float* rg_b      = (const float*)d_in[11];
    const float* rg_w2     = (const float*)d_in[12];
    const float* rg_b2     = (const float*)d_in[13];
    const float* so_w      = (const float*)d_in[14];
    const float* so_b      = (const float*)d_in[15];
    const float* aw_w      = (const float*)d_in[16];
    const float* aw_b      = (const float*)d_in[17];
    const float* vp_w      = (const float*)d_in[18];
    const float* vp_b      = (const float*)d_in[19];
    const float* op_w      = (const float*)d_in[20];
    const float* op_b      = (const float*)d_in[21];
    const float* fln_g     = (const float*)d_in[22];
    const float* fln_b     = (const float*)d_in[23];
    const float* fin_w     = (const float*)d_in[24];
    const float* fin_b     = (const float*)d_in[25];
    float* out = (float*)d_out;

    // ---- workspace layout (bytes) ----
    char* p = (char*)d_ws;
    unsigned short* FEAT = (unsigned short*)p; p += 56623104;   // bf16 [B*576,768]
    unsigned short* PT   = (unsigned short*)p; p += 22020096;   // [10752,1024] stacked p_w^T
    unsigned short* WW   = (unsigned short*)p; p += 22020096;   // [1024,10752] fused weights
    unsigned short* VPW  = (unsigned short*)p; p += 2097152;
    unsigned short* VAL  = (unsigned short*)p; p += 102760448;  // value bf16 [64*784,1024]
    unsigned short* PART = (unsigned short*)p; p += 75497472;   // bf16 partials (L2: 3x, L3: 4x)
    unsigned short* OPO  = (unsigned short*)p; p += 8388608;    // bf16 [4096,1024] op-proj out
    unsigned short* OUT0 = (unsigned short*)p; p += 8388608;
    unsigned short* LNO  = (unsigned short*)p; p += 8388608;
    unsigned short* OPW  = (unsigned short*)p; p += 2097152;
    unsigned short* FINW = (unsigned short*)p; p += 2097152;
    float* b1p  = (float*)p; p += 4096;
    float* b2p  = (float*)p; p += 4096;
    float* b3p  = (float*)p; p += 4096;
    float* awf  = (float*)p; p += 16384;
    int*   idxv = (int*)p;   p += 49152;
    double* h0  = (double*)p; p += 524288;
    double* rp  = (double*)p; p += 1024;
    double* offv_g  = (double*)p; p += 65536;   // [64,128]
    double* logit_g = (double*)p; p += 32768;   // [64,64]

    dim3 blk(256);

    // ---- query branch (fp64, batch-independent) ----
    rg1_kernel<<<16384, blk, 0, stream>>>(query_emb, rg_w1, rg_b1, h0);
    ln_gelu_rp_kernel<<<64, blk, 0, stream>>>(h0, rg_g, rg_b, rg_w2, rg_b2, rp);
    offlog_kernel<<<3072, blk, 0, stream>>>(query_emb, so_w, so_b, aw_w, aw_b, offv_g, logit_g);
    offfin_kernel<<<64, 64, 0, stream>>>(offv_g, logit_g, rp, awf, idxv);

    // ---- merged prep: all conversions + transposes + fused biases ----
    prep_kernel<<<26880, blk, 0, stream>>>(features, FEAT, vp_w, VPW, op_w, OPW, fin_w, FINW,
                                           p1_w, p2_w, p3_w, PT,
                                           vp_b, p1_b, p2_b, p3_b, b1p, b2p, b3p);

    // ---- fused weights: WW[1024,10752] = VPW @ PT^T ----
    gemm2w<true><<<dim3(84, 8), blk, 0, stream>>>(VPW, PT, nullptr, WW, 1024, WWN, 1024);

    // ---- value GEMMs: merged LPT dispatch (L3 first, then L2, then L1) ----
    gemm_val_merged<<<1264, 512, 0, stream>>>(FEAT, WW, b1p, VAL, PART, PART + 3 * 9437184);
    reduce_both_kernel<<<6656, blk, 0, stream>>>(PART, PART + 3 * 9437184, b2p, b3p, VAL);

    // ---- deformable gather (vectorized 16B/lane) ----
    gather_kernel<<<2048, blk, 0, stream>>>(VAL, awf, idxv, OUT0);

    // ---- output projection (bf16 out) + LN (bf16->bf16) + final projection ----
    gemm2w<true><<<dim3(8, 32), blk, 0, stream>>>(OUT0, OPW, op_b, OPO, 4096, 1024, 1024);
    ln_b2b_kernel<<<4096, blk, 0, stream>>>(OPO, fln_g, fln_b, LNO);
    gemm2w<false><<<dim3(8, 32), blk, 0, stream>>>(LNO, FINW, fin_b, out, 4096, 1024, 1024);
}

// Round 17
// 455.525 us; speedup vs baseline: 1.4314x; 1.0142x over previous
//
#include <hip/hip_runtime.h>
#include <math.h>

#define EE 1024
#define ROWS_TOT 784   // 576 + 144 + 64
#define WWN 10752      // 768 + 3072 + 6912

typedef __attribute__((ext_vector_type(4))) float f4;
typedef __attribute__((ext_vector_type(4))) float f32x4;
typedef __attribute__((ext_vector_type(8))) __bf16 bf16x8;
typedef __attribute__((ext_vector_type(8))) unsigned short ushort8;
typedef __attribute__((ext_vector_type(4))) unsigned short us4;

__device__ __forceinline__ unsigned short f2b(float x) {
    unsigned int u = __float_as_uint(x);
    unsigned int r = (u + 0x7fffu + ((u >> 16) & 1u)) >> 16;
    return (unsigned short)r;
}
__device__ __forceinline__ float b2f(unsigned short u) {
    unsigned int v = ((unsigned int)u) << 16;
    return __uint_as_float(v);
}

#define GLOAD16(g, l) __builtin_amdgcn_global_load_lds( \
    (const __attribute__((address_space(1))) unsigned int*)(g), \
    (__attribute__((address_space(3))) unsigned int*)(l), 16, 0, 0)

// ---------------------------------------------------------------------------
// Value-GEMM body: 256x256, BK=64, 8 waves (2m x 4n), per-wave 128x64.
// Round-10/12 proven K-loop (T3/T4/T5 schedule, 128B-row swizzle s^(r&7)).
// Fully compile-time specialized per (MODE, SPLIT, KT). LDS passed in.
// SPLIT: outp = bf16 partial slice (pre-offset by caller), no bias.
// ---------------------------------------------------------------------------
template<int MODE, bool SPLIT, int KT>
__device__ __forceinline__ void gemm_body(
    unsigned short* __restrict__ AsB, unsigned short* __restrict__ BsB,
    const unsigned short* __restrict__ FEAT, const unsigned short* __restrict__ WW,
    const float* __restrict__ bias, void* __restrict__ outp,
    int by, int bx, int ktBase)
{
    constexpr int gw = (MODE == 1) ? 24 : (MODE == 2 ? 12 : 8);
    constexpr int Rl = gw * gw;                                   // 576/144/64
    constexpr int colOff = (MODE == 1) ? 0 : (MODE == 2 ? 768 : 3840);
    constexpr int rowOff = (MODE == 1) ? 0 : (MODE == 2 ? 576 : 720);

    const int t = threadIdx.x;
    const int lane = t & 63;
    const int w = t >> 6;                // 0..7
    const int wm = w >> 2;               // 0..1  (128-row half)
    const int wn = w & 3;                // 0..3  (64-col quarter)
    const int m0 = by * 256, n0 = bx * 256;

    f32x4 acc[8][4] = {};

    // ---- staging roles: 4 gloads per operand per wave (32 rows x 128B) ----
    const int srow = lane >> 3;                  // 0..7 row within 8-row gload
    const int sseg = lane & 7;                   // stored 16B slot 0..7
    const int sgx  = sseg ^ srow;                // pre-swizzled global chunk
    int rbA[4];
#pragma unroll
    for (int g = 0; g < 4; ++g) {
        int gr = m0 + w * 32 + g * 8 + srow;
        if (MODE == 1) rbA[g] = gr;
        else {
            int b_ = gr / Rl, rl = gr - b_ * Rl;
            rbA[g] = b_ * 576 + (MODE * (rl / gw)) * 24 + MODE * (rl % gw);
        }
    }
    const unsigned short* gBbase = WW + (size_t)(n0 + w * 32 + srow) * WWN + colOff + sgx * 8;

    // ---- fragment-read roles ----
    const int fr = lane & 15;
    const int kg = lane >> 4;
    const int kgx0 = kg ^ (fr & 7);              // kk=0 slot
    const int kgx1 = kgx0 ^ 4;                   // kk=1 slot
    const int aOff0 = (wm * 128 + fr) * 64 + kgx0 * 8;
    const int aOff1 = (wm * 128 + fr) * 64 + kgx1 * 8;
    const int bOff0 = (wn * 64 + fr) * 64 + kgx0 * 8;
    const int bOff1 = (wn * 64 + fr) * 64 + kgx1 * 8;

    auto STAGE = [&](int buf, int ktl) {
        int kt = ktBase + ktl;                   // BK=64 tile index
        int s = kt / 12;                         // which 768-chunk of K
        int within = (kt - s * 12) * 64;         // + sgx*8 stays within the chunk
        int add = 0;
        if (MODE == 2)      add = (s >> 1) * 24 + (s & 1);
        else if (MODE == 3) { int di = s / 3; add = di * 24 + (s - 3 * di); }
        unsigned short* Asb = AsB + buf * 16384;
        unsigned short* Bsb = BsB + buf * 16384;
#pragma unroll
        for (int g = 0; g < 4; ++g)
            GLOAD16(FEAT + (size_t)(rbA[g] + add) * 768 + within + sgx * 8,
                    Asb + (w * 32 + g * 8) * 64);
#pragma unroll
        for (int g = 0; g < 4; ++g)
            GLOAD16(gBbase + (size_t)(g * 8) * WWN + (size_t)kt * 64,
                    Bsb + (w * 32 + g * 8) * 64);
    };

    int cur = 0;
    STAGE(0, 0);

    for (int tt = 0; tt < KT; ++tt) {
        // boundary: wait only for the stage issued one full iteration ago
        asm volatile("s_waitcnt vmcnt(0)" ::: "memory");
        __builtin_amdgcn_s_barrier();
        __builtin_amdgcn_sched_barrier(0);

        if (tt + 1 < KT) STAGE(cur ^ 1, tt + 1);        // in flight across phases
        __builtin_amdgcn_sched_barrier(0);

        const unsigned short* Asc = AsB + cur * 16384;
        const unsigned short* Bsc = BsB + cur * 16384;

        // ---- phase kk=0: K elems [0,32), 32 MFMA ----
        {
            bf16x8 bf[4], af[8];
#pragma unroll
            for (int j = 0; j < 4; ++j) bf[j] = *(const bf16x8*)(Bsc + bOff0 + j * 1024);
#pragma unroll
            for (int i = 0; i < 8; ++i) af[i] = *(const bf16x8*)(Asc + aOff0 + i * 1024);
            __builtin_amdgcn_s_setprio(1);
#pragma unroll
            for (int i = 0; i < 8; ++i)
#pragma unroll
                for (int j = 0; j < 4; ++j)
                    acc[i][j] = __builtin_amdgcn_mfma_f32_16x16x32_bf16(af[i], bf[j], acc[i][j], 0, 0, 0);
            __builtin_amdgcn_s_setprio(0);
        }
        __builtin_amdgcn_s_barrier();
        __builtin_amdgcn_sched_barrier(0);

        // ---- phase kk=1: K elems [32,64), 32 MFMA ----
        {
            bf16x8 bf[4], af[8];
#pragma unroll
            for (int j = 0; j < 4; ++j) bf[j] = *(const bf16x8*)(Bsc + bOff1 + j * 1024);
#pragma unroll
            for (int i = 0; i < 8; ++i) af[i] = *(const bf16x8*)(Asc + aOff1 + i * 1024);
            __builtin_amdgcn_s_setprio(1);
#pragma unroll
            for (int i = 0; i < 8; ++i)
#pragma unroll
                for (int j = 0; j < 4; ++j)
                    acc[i][j] = __builtin_amdgcn_mfma_f32_16x16x32_bf16(af[i], bf[j], acc[i][j], 0, 0, 0);
            __builtin_amdgcn_s_setprio(0);
        }
        cur ^= 1;
    }

#pragma unroll
    for (int i = 0; i < 8; ++i) {
#pragma unroll
        for (int r = 0; r < 4; ++r) {
            int m = m0 + wm * 128 + i * 16 + kg * 4 + r;   // local level row
#pragma unroll
            for (int j = 0; j < 4; ++j) {
                int n = n0 + wn * 64 + j * 16 + fr;
                if (SPLIT) {
                    ((unsigned short*)outp)[(size_t)m * EE + n] = f2b(acc[i][j][r]);
                } else {
                    int b_o = m / Rl, rl_o = m - b_o * Rl;
                    int crow = b_o * ROWS_TOT + rowOff + rl_o;
                    ((unsigned short*)outp)[(size_t)crow * EE + n] = f2b(acc[i][j][r] + bias[n]);
                }
            }
        }
    }
}

// ---------------------------------------------------------------------------
// MERGED value GEMM dispatch, LPT order with per-segment bijective XCD
// swizzle. hw blocks [0,256)=L3 (27 steps, z=4), [256,544)=L2 (24 steps,
// z=2), [544,1120)=L1 (12 steps). Compile-time specialized paths.
// ---------------------------------------------------------------------------
__global__ __launch_bounds__(512, 2) void gemm_val_merged(
    const unsigned short* __restrict__ FEAT, const unsigned short* __restrict__ WW,
    const float* __restrict__ b1, unsigned short* __restrict__ VAL,
    unsigned short* __restrict__ PART2, unsigned short* __restrict__ PART3)
{
    __shared__ unsigned short As[2 * 256 * 64];   // 64KB
    __shared__ unsigned short Bs[2 * 256 * 64];   // 64KB

    int bid = blockIdx.x;
    if (bid < 256) {
        // L3: 4 z-slices x 64 tiles; chunk = 256/8 = 32
        int s = ((bid & 7) << 5) | (bid >> 3);
        int z = s >> 6, r = s & 63;
        gemm_body<3, true, 27>(As, Bs, FEAT, WW, nullptr,
                               PART3 + (size_t)z * 4194304, r >> 2, r & 3, z * 27);
    } else if (bid < 544) {
        // L2: 2 z-slices x 144 tiles; chunk = 288/8 = 36
        int j = bid - 256;
        int s = (j & 7) * 36 + (j >> 3);
        int z = s / 144, r = s - z * 144;
        gemm_body<2, true, 24>(As, Bs, FEAT, WW, nullptr,
                               PART2 + (size_t)z * 9437184, r >> 2, r & 3, z * 24);
    } else {
        // L1: 576 tiles; chunk = 576/8 = 72
        int j = bid - 544;
        int s = (j & 7) * 72 + (j >> 3);
        gemm_body<1, false, 12>(As, Bs, FEAT, WW, b1, VAL, s >> 2, s & 3, 0);
    }
}

// ---------------------------------------------------------------------------
// Fused gather + split-K reduce + bias: level known per unrolled l-loop, so
// level-1 samples read VAL, level-2 sum 2 PART2 slices (+b2), level-3 sum
// 4 PART3 slices (+b3). Zero divergence; 16B loads throughout.
// ---------------------------------------------------------------------------
__global__ void gather_fused_kernel(const unsigned short* __restrict__ VAL,
                                    const unsigned short* __restrict__ P2,
                                    const unsigned short* __restrict__ P3,
                                    const float* __restrict__ b2, const float* __restrict__ b3,
                                    const float* __restrict__ awf, const int* __restrict__ idxv,
                                    unsigned short* __restrict__ out0)
{
    int idx = blockIdx.x * 256 + threadIdx.x;     // 524288 threads
    int d8 = idx & 7;
    int h  = (idx >> 3) & 15;
    int bq = idx >> 7;                            // b*64+q
    int b  = bq >> 6, q = bq & 63;
    int n0 = h * 64 + d8 * 8;
    float s[8] = {0.f};

    // ---- level 1: rows [0,576) from VAL (bias already applied) ----
#pragma unroll
    for (int p = 0; p < 4; ++p) {
        int row = idxv[((0 * 64 + q) * 16 + h) * 4 + p];
        float wgt = awf[(q * 16 + h) * 4 + p];
        ushort8 v = *(const ushort8*)(VAL + ((size_t)(b * ROWS_TOT + row)) * 1024 + n0);
#pragma unroll
        for (int i = 0; i < 8; ++i) s[i] += wgt * b2f(v[i]);
    }

    // ---- level 2: 2 partial slices + b2 ----
    float bias2[8];
#pragma unroll
    for (int i = 0; i < 8; ++i) bias2[i] = b2[n0 + i];
#pragma unroll
    for (int p = 0; p < 4; ++p) {
        int rl = idxv[((1 * 64 + q) * 16 + h) * 4 + p] - 576;
        float wgt = awf[(q * 16 + h) * 4 + p];
        size_t mo = ((size_t)(b * 144 + rl)) * 1024 + n0;
        ushort8 va = *(const ushort8*)(P2 + mo);
        ushort8 vb = *(const ushort8*)(P2 + 9437184 + mo);
#pragma unroll
        for (int i = 0; i < 8; ++i) s[i] += wgt * (b2f(va[i]) + b2f(vb[i]) + bias2[i]);
    }

    // ---- level 3: 4 partial slices + b3 ----
    float bias3[8];
#pragma unroll
    for (int i = 0; i < 8; ++i) bias3[i] = b3[n0 + i];
#pragma unroll
    for (int p = 0; p < 4; ++p) {
        int rl = idxv[((2 * 64 + q) * 16 + h) * 4 + p] - 720;
        float wgt = awf[(q * 16 + h) * 4 + p];
        size_t mo = ((size_t)(b * 64 + rl)) * 1024 + n0;
        float a8[8] = {0.f};
#pragma unroll
        for (int k = 0; k < 4; ++k) {
            ushort8 v = *(const ushort8*)(P3 + (size_t)k * 4194304 + mo);
#pragma unroll
            for (int i = 0; i < 8; ++i) a8[i] += b2f(v[i]);
        }
#pragma unroll
        for (int i = 0; i < 8; ++i) s[i] += wgt * (a8[i] + bias3[i]);
    }

    ushort8 o;
#pragma unroll
    for (int i = 0; i < 8; ++i) o[i] = f2b(s[i]);
    *(ushort8*)(out0 + (size_t)bq * 1024 + n0) = o;
}

// ---------------------------------------------------------------------------
// 128x128 GEMM, BK=64, 4 waves (2x2) — round-15 proven.
// ---------------------------------------------------------------------------
template<bool OB>
__global__ __launch_bounds__(256, 2) void gemm2w(
    const unsigned short* __restrict__ A, const unsigned short* __restrict__ Bw,
    const float* __restrict__ bias, void* __restrict__ Cv,
    int M, int N, int K)
{
    __shared__ unsigned short As[2][128 * 64];   // 16KB each
    __shared__ unsigned short Bs[2][128 * 64];

    const int t = threadIdx.x;
    const int lane = t & 63;
    const int w = t >> 6;                // 0..3
    const int wm = w >> 1, wn = w & 1;

    int nwg = gridDim.x * gridDim.y;
    int bid = blockIdx.y * gridDim.x + blockIdx.x;
    int chunk = nwg >> 3;
    int swz = (bid & 7) * chunk + (bid >> 3);
    int by = swz / gridDim.x, bx = swz % gridDim.x;
    const int m0 = by * 128, n0 = bx * 128;

    f32x4 acc[4][4] = {};

    const int srow = lane >> 3;                  // 0..7
    const int sseg = lane & 7;
    const int sgx  = sseg ^ srow;
    const unsigned short* gA = A + (size_t)(m0 + w * 32 + srow) * K + sgx * 8;
    const unsigned short* gB = Bw + (size_t)(n0 + w * 32 + srow) * K + sgx * 8;

    const int fr = lane & 15;
    const int kg = lane >> 4;
    const int kgx0 = kg ^ (fr & 7);
    const int kgx1 = kgx0 ^ 4;
    const int aOff0 = (wm * 64 + fr) * 64 + kgx0 * 8;
    const int aOff1 = (wm * 64 + fr) * 64 + kgx1 * 8;
    const int bOff0 = (wn * 64 + fr) * 64 + kgx0 * 8;
    const int bOff1 = (wn * 64 + fr) * 64 + kgx1 * 8;

    auto STAGE = [&](int buf, int kt) {
        size_t k0 = (size_t)kt * 64;
#pragma unroll
        for (int g = 0; g < 4; ++g)
            GLOAD16(gA + (size_t)(g * 8) * K + k0, &As[buf][(w * 32 + g * 8) * 64]);
#pragma unroll
        for (int g = 0; g < 4; ++g)
            GLOAD16(gB + (size_t)(g * 8) * K + k0, &Bs[buf][(w * 32 + g * 8) * 64]);
    };

    const int nt = K >> 6;
    int cur = 0;
    STAGE(0, 0);

    for (int tt = 0; tt < nt; ++tt) {
        asm volatile("s_waitcnt vmcnt(0)" ::: "memory");
        __builtin_amdgcn_s_barrier();
        __builtin_amdgcn_sched_barrier(0);

        if (tt + 1 < nt) STAGE(cur ^ 1, tt + 1);
        __builtin_amdgcn_sched_barrier(0);

        // phase kk=0
        {
            bf16x8 bf[4], af[4];
#pragma unroll
            for (int j = 0; j < 4; ++j) bf[j] = *(const bf16x8*)(&Bs[cur][bOff0] + j * 1024);
#pragma unroll
            for (int i = 0; i < 4; ++i) af[i] = *(const bf16x8*)(&As[cur][aOff0] + i * 1024);
            __builtin_amdgcn_s_setprio(1);
#pragma unroll
            for (int i = 0; i < 4; ++i)
#pragma unroll
                for (int j = 0; j < 4; ++j)
                    acc[i][j] = __builtin_amdgcn_mfma_f32_16x16x32_bf16(af[i], bf[j], acc[i][j], 0, 0, 0);
            __builtin_amdgcn_s_setprio(0);
        }
        __builtin_amdgcn_s_barrier();
        __builtin_amdgcn_sched_barrier(0);

        // phase kk=1
        {
            bf16x8 bf[4], af[4];
#pragma unroll
            for (int j = 0; j < 4; ++j) bf[j] = *(const bf16x8*)(&Bs[cur][bOff1] + j * 1024);
#pragma unroll
            for (int i = 0; i < 4; ++i) af[i] = *(const bf16x8*)(&As[cur][aOff1] + i * 1024);
            __builtin_amdgcn_s_setprio(1);
#pragma unroll
            for (int i = 0; i < 4; ++i)
#pragma unroll
                for (int j = 0; j < 4; ++j)
                    acc[i][j] = __builtin_amdgcn_mfma_f32_16x16x32_bf16(af[i], bf[j], acc[i][j], 0, 0, 0);
            __builtin_amdgcn_s_setprio(0);
        }
        cur ^= 1;
    }

#pragma unroll
    for (int i = 0; i < 4; ++i) {
#pragma unroll
        for (int r = 0; r < 4; ++r) {
            int m = m0 + wm * 64 + i * 16 + kg * 4 + r;
#pragma unroll
            for (int j = 0; j < 4; ++j) {
                int n = n0 + wn * 64 + j * 16 + fr;
                float v = acc[i][j][r];
                if (bias) v += bias[n];
                if (OB) ((unsigned short*)Cv)[(size_t)m * N + n] = f2b(v);
                else    ((float*)Cv)[(size_t)m * N + n] = v;
            }
        }
    }
}

// ---------------------------------------------------------------------------
// MERGED prep dispatch (round-12 proven)
// ---------------------------------------------------------------------------
__global__ void prep_kernel(const float* __restrict__ feat, unsigned short* __restrict__ FEAT,
                            const float* __restrict__ vpw, unsigned short* __restrict__ VPW,
                            const float* __restrict__ opw, unsigned short* __restrict__ OPW,
                            const float* __restrict__ finw, unsigned short* __restrict__ FINW,
                            const float* __restrict__ p1, const float* __restrict__ p2,
                            const float* __restrict__ p3, unsigned short* __restrict__ PT,
                            const float* __restrict__ vp_b,
                            const float* __restrict__ pb1, const float* __restrict__ pb2,
                            const float* __restrict__ pb3,
                            float* __restrict__ o1, float* __restrict__ o2, float* __restrict__ o3)
{
    __shared__ float tile[32][33];
    int blk = blockIdx.x;
    if (blk < 15360) {
        const float* in; unsigned short* out;
        if (blk < 13824)       { in = feat; out = FEAT; }
        else if (blk < 14336)  { in = vpw;  out = VPW;  blk -= 13824; }
        else if (blk < 14848)  { in = opw;  out = OPW;  blk -= 14336; }
        else                   { in = finw; out = FINW; blk -= 14848; }
        size_t i = ((size_t)blk * 256 + threadIdx.x) * 8;
        f4 x = *(const f4*)(in + i);
        f4 y = *(const f4*)(in + i + 4);
        ushort8 o;
        o[0] = f2b(x[0]); o[1] = f2b(x[1]); o[2] = f2b(x[2]); o[3] = f2b(x[3]);
        o[4] = f2b(y[0]); o[5] = f2b(y[1]); o[6] = f2b(y[2]); o[7] = f2b(y[3]);
        *(ushort8*)(out + i) = o;
    } else if (blk < 26112) {
        int fl = blk - 15360;
        int bx = fl % 336, byy = fl / 336;
        const float* in; unsigned short* out; int C;
        if (bx < 24)       { in = p1; out = PT;                C = 768; }
        else if (bx < 120) { in = p2; out = PT + 768  * 1024;  C = 3072; bx -= 24; }
        else               { in = p3; out = PT + 3840 * 1024;  C = 6912; bx -= 120; }
        const int R = 1024;
        int c0 = bx * 32, r0 = byy * 32;
        int tx = threadIdx.x & 31, ty = threadIdx.x >> 5;
#pragma unroll
        for (int i = 0; i < 32; i += 8)
            tile[ty + i][tx] = in[(size_t)(r0 + ty + i) * C + c0 + tx];
        __syncthreads();
#pragma unroll
        for (int i = 0; i < 32; i += 8)
            out[(size_t)(c0 + ty + i) * R + r0 + tx] = f2b(tile[tx][ty + i]);
    } else {
        int b = blk - 26112;
        const float* pb; float* bout;
        if (b < 256)      { pb = pb1; bout = o1; }
        else if (b < 512) { pb = pb2; bout = o2; b -= 256; }
        else              { pb = pb3; bout = o3; b -= 512; }
        int e = b * 4 + (threadIdx.x >> 6);
        int lane = threadIdx.x & 63;
        float s = 0.f;
        for (int k = lane; k < EE; k += 64) s += vpw[(size_t)e * EE + k] * pb[k];
#pragma unroll
        for (int o = 32; o > 0; o >>= 1) s += __shfl_down(s, o, 64);
        if (lane == 0) bout[e] = s + vp_b[e];
    }
}

// ---------------------------------------------------------------------------
// Query branch (batch-independent), fp64 — semantics preserved exactly
// ---------------------------------------------------------------------------
__global__ void rg1_kernel(const float* __restrict__ qe, const float* __restrict__ w,
                           const float* __restrict__ b, double* __restrict__ h0)
{
    int o = blockIdx.x * 4 + (threadIdx.x >> 6);
    int lane = threadIdx.x & 63;
    int q = o >> 10, n = o & 1023;
    double s = 0.0;
    for (int k = lane; k < EE; k += 64)
        s += (double)qe[q * EE + k] * (double)w[(size_t)n * EE + k];
#pragma unroll
    for (int off = 32; off > 0; off >>= 1) s += __shfl_down(s, off, 64);
    if (lane == 0) h0[o] = s + (double)b[n];
}

// merged LN+GELU+rp (round-16 proven)
__global__ void ln_gelu_rp_kernel(const double* __restrict__ h0, const float* __restrict__ g,
                                  const float* __restrict__ bb, const float* __restrict__ w2,
                                  const float* __restrict__ b2, double* __restrict__ rp)
{
    __shared__ double red[256];
    __shared__ double stats[2];
    __shared__ double hsh[1024];
    int q = blockIdx.x, t = threadIdx.x;
    double x[4];
#pragma unroll
    for (int i = 0; i < 4; ++i) x[i] = h0[q * 1024 + t + i * 256];
    double s = x[0] + x[1] + x[2] + x[3];
    red[t] = s; __syncthreads();
    for (int o = 128; o; o >>= 1) { if (t < o) red[t] += red[t + o]; __syncthreads(); }
    if (t == 0) stats[0] = red[0] / 1024.0;
    __syncthreads();
    double mean = stats[0];
    double d = 0.0;
#pragma unroll
    for (int i = 0; i < 4; ++i) { double dd = x[i] - mean; d += dd * dd; }
    red[t] = d; __syncthreads();
    for (int o = 128; o; o >>= 1) { if (t < o) red[t] += red[t + o]; __syncthreads(); }
    if (t == 0) stats[1] = red[0] / 1024.0;
    __syncthreads();
    double inv = 1.0 / sqrt(stats[1] + 1e-5);
#pragma unroll
    for (int i = 0; i < 4; ++i) {
        int c = t + i * 256;
        double y = (x[i] - mean) * inv * (double)g[c] + (double)bb[c];
        hsh[c] = y * 0.5 * (1.0 + erf(y * 0.70710678118654752440));
    }
    __syncthreads();
    if (t < 128) {
        int r = t >> 6;
        int lane = t & 63;
        double sv = 0.0;
        for (int k = lane; k < EE; k += 64)
            sv += hsh[k] * (double)w2[r * 1024 + k];
#pragma unroll
        for (int off = 32; off > 0; off >>= 1) sv += __shfl_down(sv, off, 64);
        if (lane == 0) rp[q * 2 + r] = 1.0 / (1.0 + exp(-(sv + (double)b2[r])));
    }
}

// wave-parallel so/aw logits (fp64, order-preserving lane-strided sum)
__global__ void offlog_kernel(const float* __restrict__ qe, const float* __restrict__ so_w,
                              const float* __restrict__ so_b, const float* __restrict__ aw_w,
                              const float* __restrict__ aw_b,
                              double* __restrict__ offv_g, double* __restrict__ logit_g)
{
    int o = blockIdx.x * 4 + (threadIdx.x >> 6);
    int lane = threadIdx.x & 63;
    const float* wrow;
    double bias;
    int q;
    if (o < 8192) { q = o >> 7; int j = o & 127; wrow = so_w + (size_t)j * EE; bias = (double)so_b[j]; }
    else          { int r = o - 8192; q = r >> 6; int n = r & 63; wrow = aw_w + (size_t)n * EE; bias = (double)aw_b[n]; }
    double s = 0.0;
    for (int k = lane; k < EE; k += 64)
        s += (double)qe[q * EE + k] * (double)wrow[k];
#pragma unroll
    for (int off = 32; off > 0; off >>= 1) s += __shfl_down(s, off, 64);
    if (lane == 0) {
        if (o < 8192) offv_g[o] = s + bias;
        else          logit_g[o - 8192] = s + bias;
    }
}

// finalize: softmax over p + sampling-point index snap (fp64, exact)
__global__ void offfin_kernel(const double* __restrict__ offv_g, const double* __restrict__ logit_g,
                              const double* __restrict__ rp,
                              float* __restrict__ awf, int* __restrict__ idxv)
{
    int q = blockIdx.x, t = threadIdx.x;   // 64 threads
    int hh = t >> 2, p = t & 3;
    const double* logit = logit_g + q * 64;
    const double* offv  = offv_g + q * 128;
    double l0 = logit[hh * 4 + 0], l1 = logit[hh * 4 + 1];
    double l2 = logit[hh * 4 + 2], l3 = logit[hh * 4 + 3];
    double m = fmax(fmax(l0, l1), fmax(l2, l3));
    double den = exp(l0 - m) + exp(l1 - m) + exp(l2 - m) + exp(l3 - m);
    awf[(q * 16 + hh) * 4 + p] = (float)(exp(logit[hh * 4 + p] - m) / den);
    const int Wss[3] = {24, 12, 8};
    const int starts[3] = {0, 576, 720};
    double ox = offv[(hh * 4 + p) * 2 + 0], oy = offv[(hh * 4 + p) * 2 + 1];
    double rx = rp[q * 2 + 0], ry = rp[q * 2 + 1];
#pragma unroll
    for (int l = 0; l < 3; ++l) {
        int Ws = Wss[l];
        double sx = rx + ox; sx = sx < 0.0 ? 0.0 : (sx > 1.0 ? 1.0 : sx);
        double sy = ry + oy; sy = sy < 0.0 ? 0.0 : (sy > 1.0 ? 1.0 : sy);
        int x0 = (int)floor(sx * (double)(Ws - 1));
        int y0 = (int)floor(sy * (double)(Ws - 1));
        idxv[((l * 64 + q) * 16 + hh) * 4 + p] = starts[l] + y0 * Ws + x0;
    }
}

// LayerNorm over 1024: bf16 in, bf16 out; fp32 stats; us4 vector access
__global__ void ln_b2b_kernel(const unsigned short* __restrict__ x, const float* __restrict__ g,
                              const float* __restrict__ bb, unsigned short* __restrict__ y)
{
    __shared__ float red[256];
    __shared__ float stats[2];
    int r = blockIdx.x, t = threadIdx.x;
    us4 v4 = *(const us4*)(x + (size_t)r * 1024 + t * 4);
    float v[4];
#pragma unroll
    for (int i = 0; i < 4; ++i) v[i] = b2f(v4[i]);
    float s = v[0] + v[1] + v[2] + v[3];
    red[t] = s; __syncthreads();
    for (int o = 128; o; o >>= 1) { if (t < o) red[t] += red[t + o]; __syncthreads(); }
    if (t == 0) stats[0] = red[0] / 1024.f;
    __syncthreads();
    float mean = stats[0];
    float d = 0.f;
#pragma unroll
    for (int i = 0; i < 4; ++i) { float dd = v[i] - mean; d += dd * dd; }
    red[t] = d; __syncthreads();
    for (int o = 128; o; o >>= 1) { if (t < o) red[t] += red[t + o]; __syncthreads(); }
    if (t == 0) stats[1] = red[0] / 1024.f;
    __syncthreads();
    float inv = 1.f / sqrtf(stats[1] + 1e-5f);
    us4 o4;
#pragma unroll
    for (int i = 0; i < 4; ++i) {
        int c = t * 4 + i;
        o4[i] = f2b((v[i] - mean) * inv * g[c] + bb[c]);
    }
    *(us4*)(y + (size_t)r * 1024 + t * 4) = o4;
}

extern "C" void kernel_launch(void* const* d_in, const int* in_sizes, int n_in,
                              void* d_out, int out_size, void* d_ws, size_t ws_size,
                              hipStream_t stream)
{
    const float* features  = (const float*)d_in[0];
    const float* p1_w      = (const float*)d_in[1];
    const float* p1_b      = (const float*)d_in[2];
    const float* p2_w      = (const float*)d_in[3];
    const float* p2_b      = (const float*)d_in[4];
    const float* p3_w      = (const float*)d_in[5];
    const float* p3_b      = (const float*)d_in[6];
    const float* query_emb = (const float*)d_in[7];
    const float* rg_w1     = (const float*)d_in[8];
    const float* rg_b1     = (const float*)d_in[9];
    const float* rg_g      = (const float*)d_in[10];
    const float* rg_b      = (const float*)d_in[11];
    const float* rg_w2     = (const float*)d_in[12];
    const float* rg_b2     = (const float*)d_in[13];
    const float* so_w      = (const float*)d_in[14];
    const float* so_b      = (const float*)d_in[15];
    const float* aw_w      = (const float*)d_in[16];
    const float* aw_b      = (const float*)d_in[17];
    const float* vp_w      = (const float*)d_in[18];
    const float* vp_b      = (const float*)d_in[19];
    const float* op_w      = (const float*)d_in[20];
    const float* op_b      = (const float*)d_in[21];
    const float* fln_g     = (const float*)d_in[22];
    const float* fln_b     = (const float*)d_in[23];
    const float* fin_w     = (const float*)d_in[24];
    const float* fin_b     = (const float*)d_in[25];
    float* out = (float*)d_out;

    // ---- workspace layout (bytes) ----
    char* p = (char*)d_ws;
    unsigned short* FEAT = (unsigned short*)p; p += 56623104;   // bf16 [B*576,768]
    unsigned short* PT   = (unsigned short*)p; p += 22020096;   // [10752,1024] stacked p_w^T
    unsigned short* WW   = (unsigned short*)p; p += 22020096;   // [1024,10752] fused weights
    unsigned short* VPW  = (unsigned short*)p; p += 2097152;
    unsigned short* VAL  = (unsigned short*)p; p += 102760448;  // value bf16 (rows 0..575/batch used)
    unsigned short* PART = (unsigned short*)p; p += 71303168;   // bf16 partials (L2: 2x9437184, L3: 4x4194304)
    unsigned short* OPO  = (unsigned short*)p; p += 8388608;    // bf16 [4096,1024] op-proj out
    unsigned short* OUT0 = (unsigned short*)p; p += 8388608;
    unsigned short* LNO  = (unsigned short*)p; p += 8388608;
    unsigned short* OPW  = (unsigned short*)p; p += 2097152;
    unsigned short* FINW = (unsigned short*)p; p += 2097152;
    float* b1p  = (float*)p; p += 4096;
    float* b2p  = (float*)p; p += 4096;
    float* b3p  = (float*)p; p += 4096;
    float* awf  = (float*)p; p += 16384;
    int*   idxv = (int*)p;   p += 49152;
    double* h0  = (double*)p; p += 524288;
    double* rp  = (double*)p; p += 1024;
    double* offv_g  = (double*)p; p += 65536;   // [64,128]
    double* logit_g = (double*)p; p += 32768;   // [64,64]

    unsigned short* PART2 = PART;                       // 2 x 9437184 elems
    unsigned short* PART3 = PART + 2 * 9437184;         // 4 x 4194304 elems

    dim3 blk(256);

    // ---- query branch (fp64, batch-independent) ----
    rg1_kernel<<<16384, blk, 0, stream>>>(query_emb, rg_w1, rg_b1, h0);
    ln_gelu_rp_kernel<<<64, blk, 0, stream>>>(h0, rg_g, rg_b, rg_w2, rg_b2, rp);
    offlog_kernel<<<3072, blk, 0, stream>>>(query_emb, so_w, so_b, aw_w, aw_b, offv_g, logit_g);
    offfin_kernel<<<64, 64, 0, stream>>>(offv_g, logit_g, rp, awf, idxv);

    // ---- merged prep: all conversions + transposes + fused biases ----
    prep_kernel<<<26880, blk, 0, stream>>>(features, FEAT, vp_w, VPW, op_w, OPW, fin_w, FINW,
                                           p1_w, p2_w, p3_w, PT,
                                           vp_b, p1_b, p2_b, p3_b, b1p, b2p, b3p);

    // ---- fused weights: WW[1024,10752] = VPW @ PT^T ----
    gemm2w<true><<<dim3(84, 8), blk, 0, stream>>>(VPW, PT, nullptr, WW, 1024, WWN, 1024);

    // ---- value GEMMs: merged LPT dispatch (L3 z=4, L2 z=2, L1) ----
    gemm_val_merged<<<1120, 512, 0, stream>>>(FEAT, WW, b1p, VAL, PART2, PART3);

    // ---- fused gather + split-K reduce + bias ----
    gather_fused_kernel<<<2048, blk, 0, stream>>>(VAL, PART2, PART3, b2p, b3p, awf, idxv, OUT0);

    // ---- output projection (bf16 out) + LN (bf16->bf16) + final projection ----
    gemm2w<true><<<dim3(8, 32), blk, 0, stream>>>(OUT0, OPW, op_b, OPO, 4096, 1024, 1024);
    ln_b2b_kernel<<<4096, blk, 0, stream>>>(OPO, fln_g, fln_b, LNO);
    gemm2w<false><<<dim3(8, 32), blk, 0, stream>>>(LNO, FINW, fin_b, out, 4096, 1024, 1024);
}

// Round 18
// 451.741 us; speedup vs baseline: 1.4434x; 1.0084x over previous
//
#include <hip/hip_runtime.h>
#include <math.h>

#define EE 1024
#define WWN 10752      // 768 + 3072 + 6912

typedef __attribute__((ext_vector_type(4))) float f4;
typedef __attribute__((ext_vector_type(4))) float f32x4;
typedef __attribute__((ext_vector_type(8))) __bf16 bf16x8;
typedef __attribute__((ext_vector_type(8))) unsigned short ushort8;
typedef __attribute__((ext_vector_type(4))) unsigned short us4;

__device__ __forceinline__ unsigned short f2b(float x) {
    unsigned int u = __float_as_uint(x);
    unsigned int r = (u + 0x7fffu + ((u >> 16) & 1u)) >> 16;
    return (unsigned short)r;
}
__device__ __forceinline__ float b2f(unsigned short u) {
    unsigned int v = ((unsigned int)u) << 16;
    return __uint_as_float(v);
}

#define GLOAD16(g, l) __builtin_amdgcn_global_load_lds( \
    (const __attribute__((address_space(1))) unsigned int*)(g), \
    (__attribute__((address_space(3))) unsigned int*)(l), 16, 0, 0)

// ---------------------------------------------------------------------------
// Value-GEMM body: 256x256, BK=64, 8 waves (2m x 4n), per-wave 128x64.
// Round-10/12 proven K-loop (T3/T4/T5 schedule, 128B-row swizzle s^(r&7)).
// Fully compile-time specialized per (MODE, SPLIT, KT). LDS passed in.
// SPLIT: outp = bf16 partial slice (pre-offset by caller), no bias.
// non-SPLIT (MODE=1 only): writes VAL with row stride 576 (+bias).
// ---------------------------------------------------------------------------
template<int MODE, bool SPLIT, int KT>
__device__ __forceinline__ void gemm_body(
    unsigned short* __restrict__ AsB, unsigned short* __restrict__ BsB,
    const unsigned short* __restrict__ FEAT, const unsigned short* __restrict__ WW,
    const float* __restrict__ bias, void* __restrict__ outp,
    int by, int bx, int ktBase)
{
    constexpr int gw = (MODE == 1) ? 24 : (MODE == 2 ? 12 : 8);
    constexpr int Rl = gw * gw;                                   // 576/144/64
    constexpr int colOff = (MODE == 1) ? 0 : (MODE == 2 ? 768 : 3840);

    const int t = threadIdx.x;
    const int lane = t & 63;
    const int w = t >> 6;                // 0..7
    const int wm = w >> 2;               // 0..1  (128-row half)
    const int wn = w & 3;                // 0..3  (64-col quarter)
    const int m0 = by * 256, n0 = bx * 256;

    f32x4 acc[8][4] = {};

    // ---- staging roles: 4 gloads per operand per wave (32 rows x 128B) ----
    const int srow = lane >> 3;                  // 0..7 row within 8-row gload
    const int sseg = lane & 7;                   // stored 16B slot 0..7
    const int sgx  = sseg ^ srow;                // pre-swizzled global chunk
    int rbA[4];
#pragma unroll
    for (int g = 0; g < 4; ++g) {
        int gr = m0 + w * 32 + g * 8 + srow;
        if (MODE == 1) rbA[g] = gr;
        else {
            int b_ = gr / Rl, rl = gr - b_ * Rl;
            rbA[g] = b_ * 576 + (MODE * (rl / gw)) * 24 + MODE * (rl % gw);
        }
    }
    const unsigned short* gBbase = WW + (size_t)(n0 + w * 32 + srow) * WWN + colOff + sgx * 8;

    // ---- fragment-read roles ----
    const int fr = lane & 15;
    const int kg = lane >> 4;
    const int kgx0 = kg ^ (fr & 7);              // kk=0 slot
    const int kgx1 = kgx0 ^ 4;                   // kk=1 slot
    const int aOff0 = (wm * 128 + fr) * 64 + kgx0 * 8;
    const int aOff1 = (wm * 128 + fr) * 64 + kgx1 * 8;
    const int bOff0 = (wn * 64 + fr) * 64 + kgx0 * 8;
    const int bOff1 = (wn * 64 + fr) * 64 + kgx1 * 8;

    auto STAGE = [&](int buf, int ktl) {
        int kt = ktBase + ktl;                   // BK=64 tile index
        int s = kt / 12;                         // which 768-chunk of K
        int within = (kt - s * 12) * 64;         // + sgx*8 stays within the chunk
        int add = 0;
        if (MODE == 2)      add = (s >> 1) * 24 + (s & 1);
        else if (MODE == 3) { int di = s / 3; add = di * 24 + (s - 3 * di); }
        unsigned short* Asb = AsB + buf * 16384;
        unsigned short* Bsb = BsB + buf * 16384;
#pragma unroll
        for (int g = 0; g < 4; ++g)
            GLOAD16(FEAT + (size_t)(rbA[g] + add) * 768 + within + sgx * 8,
                    Asb + (w * 32 + g * 8) * 64);
#pragma unroll
        for (int g = 0; g < 4; ++g)
            GLOAD16(gBbase + (size_t)(g * 8) * WWN + (size_t)kt * 64,
                    Bsb + (w * 32 + g * 8) * 64);
    };

    int cur = 0;
    STAGE(0, 0);

    for (int tt = 0; tt < KT; ++tt) {
        // boundary: wait only for the stage issued one full iteration ago
        asm volatile("s_waitcnt vmcnt(0)" ::: "memory");
        __builtin_amdgcn_s_barrier();
        __builtin_amdgcn_sched_barrier(0);

        if (tt + 1 < KT) STAGE(cur ^ 1, tt + 1);        // in flight across phases
        __builtin_amdgcn_sched_barrier(0);

        const unsigned short* Asc = AsB + cur * 16384;
        const unsigned short* Bsc = BsB + cur * 16384;

        // ---- phase kk=0: K elems [0,32), 32 MFMA ----
        {
            bf16x8 bf[4], af[8];
#pragma unroll
            for (int j = 0; j < 4; ++j) bf[j] = *(const bf16x8*)(Bsc + bOff0 + j * 1024);
#pragma unroll
            for (int i = 0; i < 8; ++i) af[i] = *(const bf16x8*)(Asc + aOff0 + i * 1024);
            __builtin_amdgcn_s_setprio(1);
#pragma unroll
            for (int i = 0; i < 8; ++i)
#pragma unroll
                for (int j = 0; j < 4; ++j)
                    acc[i][j] = __builtin_amdgcn_mfma_f32_16x16x32_bf16(af[i], bf[j], acc[i][j], 0, 0, 0);
            __builtin_amdgcn_s_setprio(0);
        }
        __builtin_amdgcn_s_barrier();
        __builtin_amdgcn_sched_barrier(0);

        // ---- phase kk=1: K elems [32,64), 32 MFMA ----
        {
            bf16x8 bf[4], af[8];
#pragma unroll
            for (int j = 0; j < 4; ++j) bf[j] = *(const bf16x8*)(Bsc + bOff1 + j * 1024);
#pragma unroll
            for (int i = 0; i < 8; ++i) af[i] = *(const bf16x8*)(Asc + aOff1 + i * 1024);
            __builtin_amdgcn_s_setprio(1);
#pragma unroll
            for (int i = 0; i < 8; ++i)
#pragma unroll
                for (int j = 0; j < 4; ++j)
                    acc[i][j] = __builtin_amdgcn_mfma_f32_16x16x32_bf16(af[i], bf[j], acc[i][j], 0, 0, 0);
            __builtin_amdgcn_s_setprio(0);
        }
        cur ^= 1;
    }

#pragma unroll
    for (int i = 0; i < 8; ++i) {
#pragma unroll
        for (int r = 0; r < 4; ++r) {
            int m = m0 + wm * 128 + i * 16 + kg * 4 + r;   // local level row
#pragma unroll
            for (int j = 0; j < 4; ++j) {
                int n = n0 + wn * 64 + j * 16 + fr;
                if (SPLIT) {
                    ((unsigned short*)outp)[(size_t)m * EE + n] = f2b(acc[i][j][r]);
                } else {
                    // MODE==1 only: VAL stride 576 rows/batch
                    ((unsigned short*)outp)[(size_t)m * EE + n] = f2b(acc[i][j][r] + bias[n]);
                }
            }
        }
    }
}

// ---------------------------------------------------------------------------
// MERGED value GEMM dispatch, LPT order (round-16 proven geometry) with
// per-segment bijective XCD swizzle. hw blocks [0,256)=L3 (27 steps, z=4),
// [256,688)=L2 (16 steps, z=3), [688,1264)=L1 (12 steps).
// ---------------------------------------------------------------------------
__global__ __launch_bounds__(512, 2) void gemm_val_merged(
    const unsigned short* __restrict__ FEAT, const unsigned short* __restrict__ WW,
    const float* __restrict__ b1, unsigned short* __restrict__ VAL,
    unsigned short* __restrict__ PART2, unsigned short* __restrict__ PART3)
{
    __shared__ unsigned short As[2 * 256 * 64];   // 64KB
    __shared__ unsigned short Bs[2 * 256 * 64];   // 64KB

    int bid = blockIdx.x;
    if (bid < 256) {
        // L3: 4 z-slices x 64 tiles; chunk = 256/8 = 32
        int s = ((bid & 7) << 5) | (bid >> 3);
        int z = s >> 6, r = s & 63;
        gemm_body<3, true, 27>(As, Bs, FEAT, WW, nullptr,
                               PART3 + (size_t)z * 4194304, r >> 2, r & 3, z * 27);
    } else if (bid < 688) {
        // L2: 3 z-slices x 144 tiles; chunk = 432/8 = 54
        int j = bid - 256;
        int s = (j & 7) * 54 + (j >> 3);
        int z = s / 144, r = s - z * 144;
        gemm_body<2, true, 16>(As, Bs, FEAT, WW, nullptr,
                               PART2 + (size_t)z * 9437184, r >> 2, r & 3, z * 16);
    } else {
        // L1: 576 tiles; chunk = 576/8 = 72
        int j = bid - 688;
        int s = (j & 7) * 72 + (j >> 3);
        gemm_body<1, false, 12>(As, Bs, FEAT, WW, b1, VAL, s >> 2, s & 3, 0);
    }
}

// ---------------------------------------------------------------------------
// Fused gather + split-K reduce + bias: level-1 reads VAL (stride 576),
// level-2 sums 3 PART2 slices (+b2), level-3 sums 4 PART3 slices (+b3).
// Zero divergence; 16B loads throughout.
// ---------------------------------------------------------------------------
__global__ void gather_fused_kernel(const unsigned short* __restrict__ VAL,
                                    const unsigned short* __restrict__ P2,
                                    const unsigned short* __restrict__ P3,
                                    const float* __restrict__ b2, const float* __restrict__ b3,
                                    const float* __restrict__ awf, const int* __restrict__ idxv,
                                    unsigned short* __restrict__ out0)
{
    int idx = blockIdx.x * 256 + threadIdx.x;     // 524288 threads
    int d8 = idx & 7;
    int h  = (idx >> 3) & 15;
    int bq = idx >> 7;                            // b*64+q
    int b  = bq >> 6, q = bq & 63;
    int n0 = h * 64 + d8 * 8;
    float s[8] = {0.f};

    // ---- level 1: rows [0,576) from VAL (bias already applied) ----
#pragma unroll
    for (int p = 0; p < 4; ++p) {
        int row = idxv[((0 * 64 + q) * 16 + h) * 4 + p];
        float wgt = awf[(q * 16 + h) * 4 + p];
        ushort8 v = *(const ushort8*)(VAL + ((size_t)(b * 576 + row)) * 1024 + n0);
#pragma unroll
        for (int i = 0; i < 8; ++i) s[i] += wgt * b2f(v[i]);
    }

    // ---- level 2: 3 partial slices + b2 ----
    float bias2[8];
#pragma unroll
    for (int i = 0; i < 8; ++i) bias2[i] = b2[n0 + i];
#pragma unroll
    for (int p = 0; p < 4; ++p) {
        int rl = idxv[((1 * 64 + q) * 16 + h) * 4 + p] - 576;
        float wgt = awf[(q * 16 + h) * 4 + p];
        size_t mo = ((size_t)(b * 144 + rl)) * 1024 + n0;
        ushort8 va = *(const ushort8*)(P2 + mo);
        ushort8 vb = *(const ushort8*)(P2 + 9437184 + mo);
        ushort8 vc = *(const ushort8*)(P2 + 2 * 9437184 + mo);
#pragma unroll
        for (int i = 0; i < 8; ++i)
            s[i] += wgt * (b2f(va[i]) + b2f(vb[i]) + b2f(vc[i]) + bias2[i]);
    }

    // ---- level 3: 4 partial slices + b3 ----
    float bias3[8];
#pragma unroll
    for (int i = 0; i < 8; ++i) bias3[i] = b3[n0 + i];
#pragma unroll
    for (int p = 0; p < 4; ++p) {
        int rl = idxv[((2 * 64 + q) * 16 + h) * 4 + p] - 720;
        float wgt = awf[(q * 16 + h) * 4 + p];
        size_t mo = ((size_t)(b * 64 + rl)) * 1024 + n0;
        float a8[8] = {0.f};
#pragma unroll
        for (int k = 0; k < 4; ++k) {
            ushort8 v = *(const ushort8*)(P3 + (size_t)k * 4194304 + mo);
#pragma unroll
            for (int i = 0; i < 8; ++i) a8[i] += b2f(v[i]);
        }
#pragma unroll
        for (int i = 0; i < 8; ++i) s[i] += wgt * (a8[i] + bias3[i]);
    }

    ushort8 o;
#pragma unroll
    for (int i = 0; i < 8; ++i) o[i] = f2b(s[i]);
    *(ushort8*)(out0 + (size_t)bq * 1024 + n0) = o;
}

// ---------------------------------------------------------------------------
// 128x128 GEMM, BK=64, 4 waves (2x2) — round-15 proven.
// ---------------------------------------------------------------------------
template<bool OB>
__global__ __launch_bounds__(256, 2) void gemm2w(
    const unsigned short* __restrict__ A, const unsigned short* __restrict__ Bw,
    const float* __restrict__ bias, void* __restrict__ Cv,
    int M, int N, int K)
{
    __shared__ unsigned short As[2][128 * 64];   // 16KB each
    __shared__ unsigned short Bs[2][128 * 64];

    const int t = threadIdx.x;
    const int lane = t & 63;
    const int w = t >> 6;                // 0..3
    const int wm = w >> 1, wn = w & 1;

    int nwg = gridDim.x * gridDim.y;
    int bid = blockIdx.y * gridDim.x + blockIdx.x;
    int chunk = nwg >> 3;
    int swz = (bid & 7) * chunk + (bid >> 3);
    int by = swz / gridDim.x, bx = swz % gridDim.x;
    const int m0 = by * 128, n0 = bx * 128;

    f32x4 acc[4][4] = {};

    const int srow = lane >> 3;                  // 0..7
    const int sseg = lane & 7;
    const int sgx  = sseg ^ srow;
    const unsigned short* gA = A + (size_t)(m0 + w * 32 + srow) * K + sgx * 8;
    const unsigned short* gB = Bw + (size_t)(n0 + w * 32 + srow) * K + sgx * 8;

    const int fr = lane & 15;
    const int kg = lane >> 4;
    const int kgx0 = kg ^ (fr & 7);
    const int kgx1 = kgx0 ^ 4;
    const int aOff0 = (wm * 64 + fr) * 64 + kgx0 * 8;
    const int aOff1 = (wm * 64 + fr) * 64 + kgx1 * 8;
    const int bOff0 = (wn * 64 + fr) * 64 + kgx0 * 8;
    const int bOff1 = (wn * 64 + fr) * 64 + kgx1 * 8;

    auto STAGE = [&](int buf, int kt) {
        size_t k0 = (size_t)kt * 64;
#pragma unroll
        for (int g = 0; g < 4; ++g)
            GLOAD16(gA + (size_t)(g * 8) * K + k0, &As[buf][(w * 32 + g * 8) * 64]);
#pragma unroll
        for (int g = 0; g < 4; ++g)
            GLOAD16(gB + (size_t)(g * 8) * K + k0, &Bs[buf][(w * 32 + g * 8) * 64]);
    };

    const int nt = K >> 6;
    int cur = 0;
    STAGE(0, 0);

    for (int tt = 0; tt < nt; ++tt) {
        asm volatile("s_waitcnt vmcnt(0)" ::: "memory");
        __builtin_amdgcn_s_barrier();
        __builtin_amdgcn_sched_barrier(0);

        if (tt + 1 < nt) STAGE(cur ^ 1, tt + 1);
        __builtin_amdgcn_sched_barrier(0);

        // phase kk=0
        {
            bf16x8 bf[4], af[4];
#pragma unroll
            for (int j = 0; j < 4; ++j) bf[j] = *(const bf16x8*)(&Bs[cur][bOff0] + j * 1024);
#pragma unroll
            for (int i = 0; i < 4; ++i) af[i] = *(const bf16x8*)(&As[cur][aOff0] + i * 1024);
            __builtin_amdgcn_s_setprio(1);
#pragma unroll
            for (int i = 0; i < 4; ++i)
#pragma unroll
                for (int j = 0; j < 4; ++j)
                    acc[i][j] = __builtin_amdgcn_mfma_f32_16x16x32_bf16(af[i], bf[j], acc[i][j], 0, 0, 0);
            __builtin_amdgcn_s_setprio(0);
        }
        __builtin_amdgcn_s_barrier();
        __builtin_amdgcn_sched_barrier(0);

        // phase kk=1
        {
            bf16x8 bf[4], af[4];
#pragma unroll
            for (int j = 0; j < 4; ++j) bf[j] = *(const bf16x8*)(&Bs[cur][bOff1] + j * 1024);
#pragma unroll
            for (int i = 0; i < 4; ++i) af[i] = *(const bf16x8*)(&As[cur][aOff1] + i * 1024);
            __builtin_amdgcn_s_setprio(1);
#pragma unroll
            for (int i = 0; i < 4; ++i)
#pragma unroll
                for (int j = 0; j < 4; ++j)
                    acc[i][j] = __builtin_amdgcn_mfma_f32_16x16x32_bf16(af[i], bf[j], acc[i][j], 0, 0, 0);
            __builtin_amdgcn_s_setprio(0);
        }
        cur ^= 1;
    }

#pragma unroll
    for (int i = 0; i < 4; ++i) {
#pragma unroll
        for (int r = 0; r < 4; ++r) {
            int m = m0 + wm * 64 + i * 16 + kg * 4 + r;
#pragma unroll
            for (int j = 0; j < 4; ++j) {
                int n = n0 + wn * 64 + j * 16 + fr;
                float v = acc[i][j][r];
                if (bias) v += bias[n];
                if (OB) ((unsigned short*)Cv)[(size_t)m * N + n] = f2b(v);
                else    ((float*)Cv)[(size_t)m * N + n] = v;
            }
        }
    }
}

// ---------------------------------------------------------------------------
// MERGED prep dispatch (round-12 proven)
// ---------------------------------------------------------------------------
__global__ void prep_kernel(const float* __restrict__ feat, unsigned short* __restrict__ FEAT,
                            const float* __restrict__ vpw, unsigned short* __restrict__ VPW,
                            const float* __restrict__ opw, unsigned short* __restrict__ OPW,
                            const float* __restrict__ finw, unsigned short* __restrict__ FINW,
                            const float* __restrict__ p1, const float* __restrict__ p2,
                            const float* __restrict__ p3, unsigned short* __restrict__ PT,
                            const float* __restrict__ vp_b,
                            const float* __restrict__ pb1, const float* __restrict__ pb2,
                            const float* __restrict__ pb3,
                            float* __restrict__ o1, float* __restrict__ o2, float* __restrict__ o3)
{
    __shared__ float tile[32][33];
    int blk = blockIdx.x;
    if (blk < 15360) {
        const float* in; unsigned short* out;
        if (blk < 13824)       { in = feat; out = FEAT; }
        else if (blk < 14336)  { in = vpw;  out = VPW;  blk -= 13824; }
        else if (blk < 14848)  { in = opw;  out = OPW;  blk -= 14336; }
        else                   { in = finw; out = FINW; blk -= 14848; }
        size_t i = ((size_t)blk * 256 + threadIdx.x) * 8;
        f4 x = *(const f4*)(in + i);
        f4 y = *(const f4*)(in + i + 4);
        ushort8 o;
        o[0] = f2b(x[0]); o[1] = f2b(x[1]); o[2] = f2b(x[2]); o[3] = f2b(x[3]);
        o[4] = f2b(y[0]); o[5] = f2b(y[1]); o[6] = f2b(y[2]); o[7] = f2b(y[3]);
        *(ushort8*)(out + i) = o;
    } else if (blk < 26112) {
        int fl = blk - 15360;
        int bx = fl % 336, byy = fl / 336;
        const float* in; unsigned short* out; int C;
        if (bx < 24)       { in = p1; out = PT;                C = 768; }
        else if (bx < 120) { in = p2; out = PT + 768  * 1024;  C = 3072; bx -= 24; }
        else               { in = p3; out = PT + 3840 * 1024;  C = 6912; bx -= 120; }
        const int R = 1024;
        int c0 = bx * 32, r0 = byy * 32;
        int tx = threadIdx.x & 31, ty = threadIdx.x >> 5;
#pragma unroll
        for (int i = 0; i < 32; i += 8)
            tile[ty + i][tx] = in[(size_t)(r0 + ty + i) * C + c0 + tx];
        __syncthreads();
#pragma unroll
        for (int i = 0; i < 32; i += 8)
            out[(size_t)(c0 + ty + i) * R + r0 + tx] = f2b(tile[tx][ty + i]);
    } else {
        int b = blk - 26112;
        const float* pb; float* bout;
        if (b < 256)      { pb = pb1; bout = o1; }
        else if (b < 512) { pb = pb2; bout = o2; b -= 256; }
        else              { pb = pb3; bout = o3; b -= 512; }
        int e = b * 4 + (threadIdx.x >> 6);
        int lane = threadIdx.x & 63;
        float s = 0.f;
        for (int k = lane; k < EE; k += 64) s += vpw[(size_t)e * EE + k] * pb[k];
#pragma unroll
        for (int o = 32; o > 0; o >>= 1) s += __shfl_down(s, o, 64);
        if (lane == 0) bout[e] = s + vp_b[e];
    }
}

// ---------------------------------------------------------------------------
// Query branch (batch-independent), fp64 — semantics preserved exactly
// ---------------------------------------------------------------------------
__global__ void rg1_kernel(const float* __restrict__ qe, const float* __restrict__ w,
                           const float* __restrict__ b, double* __restrict__ h0)
{
    int o = blockIdx.x * 4 + (threadIdx.x >> 6);
    int lane = threadIdx.x & 63;
    int q = o >> 10, n = o & 1023;
    double s = 0.0;
    for (int k = lane; k < EE; k += 64)
        s += (double)qe[q * EE + k] * (double)w[(size_t)n * EE + k];
#pragma unroll
    for (int off = 32; off > 0; off >>= 1) s += __shfl_down(s, off, 64);
    if (lane == 0) h0[o] = s + (double)b[n];
}

// merged LN+GELU+rp (round-16 proven)
__global__ void ln_gelu_rp_kernel(const double* __restrict__ h0, const float* __restrict__ g,
                                  const float* __restrict__ bb, const float* __restrict__ w2,
                                  const float* __restrict__ b2, double* __restrict__ rp)
{
    __shared__ double red[256];
    __shared__ double stats[2];
    __shared__ double hsh[1024];
    int q = blockIdx.x, t = threadIdx.x;
    double x[4];
#pragma unroll
    for (int i = 0; i < 4; ++i) x[i] = h0[q * 1024 + t + i * 256];
    double s = x[0] + x[1] + x[2] + x[3];
    red[t] = s; __syncthreads();
    for (int o = 128; o; o >>= 1) { if (t < o) red[t] += red[t + o]; __syncthreads(); }
    if (t == 0) stats[0] = red[0] / 1024.0;
    __syncthreads();
    double mean = stats[0];
    double d = 0.0;
#pragma unroll
    for (int i = 0; i < 4; ++i) { double dd = x[i] - mean; d += dd * dd; }
    red[t] = d; __syncthreads();
    for (int o = 128; o; o >>= 1) { if (t < o) red[t] += red[t + o]; __syncthreads(); }
    if (t == 0) stats[1] = red[0] / 1024.0;
    __syncthreads();
    double inv = 1.0 / sqrt(stats[1] + 1e-5);
#pragma unroll
    for (int i = 0; i < 4; ++i) {
        int c = t + i * 256;
        double y = (x[i] - mean) * inv * (double)g[c] + (double)bb[c];
        hsh[c] = y * 0.5 * (1.0 + erf(y * 0.70710678118654752440));
    }
    __syncthreads();
    if (t < 128) {
        int r = t >> 6;
        int lane = t & 63;
        double sv = 0.0;
        for (int k = lane; k < EE; k += 64)
            sv += hsh[k] * (double)w2[r * 1024 + k];
#pragma unroll
        for (int off = 32; off > 0; off >>= 1) sv += __shfl_down(sv, off, 64);
        if (lane == 0) rp[q * 2 + r] = 1.0 / (1.0 + exp(-(sv + (double)b2[r])));
    }
}

// wave-parallel so/aw logits (fp64, order-preserving lane-strided sum)
__global__ void offlog_kernel(const float* __restrict__ qe, const float* __restrict__ so_w,
                              const float* __restrict__ so_b, const float* __restrict__ aw_w,
                              const float* __restrict__ aw_b,
                              double* __restrict__ offv_g, double* __restrict__ logit_g)
{
    int o = blockIdx.x * 4 + (threadIdx.x >> 6);
    int lane = threadIdx.x & 63;
    const float* wrow;
    double bias;
    int q;
    if (o < 8192) { q = o >> 7; int j = o & 127; wrow = so_w + (size_t)j * EE; bias = (double)so_b[j]; }
    else          { int r = o - 8192; q = r >> 6; int n = r & 63; wrow = aw_w + (size_t)n * EE; bias = (double)aw_b[n]; }
    double s = 0.0;
    for (int k = lane; k < EE; k += 64)
        s += (double)qe[q * EE + k] * (double)wrow[k];
#pragma unroll
    for (int off = 32; off > 0; off >>= 1) s += __shfl_down(s, off, 64);
    if (lane == 0) {
        if (o < 8192) offv_g[o] = s + bias;
        else          logit_g[o - 8192] = s + bias;
    }
}

// finalize: softmax over p + sampling-point index snap (fp64, exact)
__global__ void offfin_kernel(const double* __restrict__ offv_g, const double* __restrict__ logit_g,
                              const double* __restrict__ rp,
                              float* __restrict__ awf, int* __restrict__ idxv)
{
    int q = blockIdx.x, t = threadIdx.x;   // 64 threads
    int hh = t >> 2, p = t & 3;
    const double* logit = logit_g + q * 64;
    const double* offv  = offv_g + q * 128;
    double l0 = logit[hh * 4 + 0], l1 = logit[hh * 4 + 1];
    double l2 = logit[hh * 4 + 2], l3 = logit[hh * 4 + 3];
    double m = fmax(fmax(l0, l1), fmax(l2, l3));
    double den = exp(l0 - m) + exp(l1 - m) + exp(l2 - m) + exp(l3 - m);
    awf[(q * 16 + hh) * 4 + p] = (float)(exp(logit[hh * 4 + p] - m) / den);
    const int Wss[3] = {24, 12, 8};
    const int starts[3] = {0, 576, 720};
    double ox = offv[(hh * 4 + p) * 2 + 0], oy = offv[(hh * 4 + p) * 2 + 1];
    double rx = rp[q * 2 + 0], ry = rp[q * 2 + 1];
#pragma unroll
    for (int l = 0; l < 3; ++l) {
        int Ws = Wss[l];
        double sx = rx + ox; sx = sx < 0.0 ? 0.0 : (sx > 1.0 ? 1.0 : sx);
        double sy = ry + oy; sy = sy < 0.0 ? 0.0 : (sy > 1.0 ? 1.0 : sy);
        int x0 = (int)floor(sx * (double)(Ws - 1));
        int y0 = (int)floor(sy * (double)(Ws - 1));
        idxv[((l * 64 + q) * 16 + hh) * 4 + p] = starts[l] + y0 * Ws + x0;
    }
}

// LayerNorm over 1024: bf16 in, bf16 out; fp32 stats; us4 vector access
__global__ void ln_b2b_kernel(const unsigned short* __restrict__ x, const float* __restrict__ g,
                              const float* __restrict__ bb, unsigned short* __restrict__ y)
{
    __shared__ float red[256];
    __shared__ float stats[2];
    int r = blockIdx.x, t = threadIdx.x;
    us4 v4 = *(const us4*)(x + (size_t)r * 1024 + t * 4);
    float v[4];
#pragma unroll
    for (int i = 0; i < 4; ++i) v[i] = b2f(v4[i]);
    float s = v[0] + v[1] + v[2] + v[3];
    red[t] = s; __syncthreads();
    for (int o = 128; o; o >>= 1) { if (t < o) red[t] += red[t + o]; __syncthreads(); }
    if (t == 0) stats[0] = red[0] / 1024.f;
    __syncthreads();
    float mean = stats[0];
    float d = 0.f;
#pragma unroll
    for (int i = 0; i < 4; ++i) { float dd = v[i] - mean; d += dd * dd; }
    red[t] = d; __syncthreads();
    for (int o = 128; o; o >>= 1) { if (t < o) red[t] += red[t + o]; __syncthreads(); }
    if (t == 0) stats[1] = red[0] / 1024.f;
    __syncthreads();
    float inv = 1.f / sqrtf(stats[1] + 1e-5f);
    us4 o4;
#pragma unroll
    for (int i = 0; i < 4; ++i) {
        int c = t * 4 + i;
        o4[i] = f2b((v[i] - mean) * inv * g[c] + bb[c]);
    }
    *(us4*)(y + (size_t)r * 1024 + t * 4) = o4;
}

extern "C" void kernel_launch(void* const* d_in, const int* in_sizes, int n_in,
                              void* d_out, int out_size, void* d_ws, size_t ws_size,
                              hipStream_t stream)
{
    const float* features  = (const float*)d_in[0];
    const float* p1_w      = (const float*)d_in[1];
    const float* p1_b      = (const float*)d_in[2];
    const float* p2_w      = (const float*)d_in[3];
    const float* p2_b      = (const float*)d_in[4];
    const float* p3_w      = (const float*)d_in[5];
    const float* p3_b      = (const float*)d_in[6];
    const float* query_emb = (const float*)d_in[7];
    const float* rg_w1     = (const float*)d_in[8];
    const float* rg_b1     = (const float*)d_in[9];
    const float* rg_g      = (const float*)d_in[10];
    const float* rg_b      = (const float*)d_in[11];
    const float* rg_w2     = (const float*)d_in[12];
    const float* rg_b2     = (const float*)d_in[13];
    const float* so_w      = (const float*)d_in[14];
    const float* so_b      = (const float*)d_in[15];
    const float* aw_w      = (const float*)d_in[16];
    const float* aw_b      = (const float*)d_in[17];
    const float* vp_w      = (const float*)d_in[18];
    const float* vp_b      = (const float*)d_in[19];
    const float* op_w      = (const float*)d_in[20];
    const float* op_b      = (const float*)d_in[21];
    const float* fln_g     = (const float*)d_in[22];
    const float* fln_b     = (const float*)d_in[23];
    const float* fin_w     = (const float*)d_in[24];
    const float* fin_b     = (const float*)d_in[25];
    float* out = (float*)d_out;

    // ---- workspace layout (bytes) ----
    char* p = (char*)d_ws;
    unsigned short* FEAT = (unsigned short*)p; p += 56623104;   // bf16 [B*576,768]
    unsigned short* PT   = (unsigned short*)p; p += 22020096;   // [10752,1024] stacked p_w^T
    unsigned short* WW   = (unsigned short*)p; p += 22020096;   // [1024,10752] fused weights
    unsigned short* VPW  = (unsigned short*)p; p += 2097152;
    unsigned short* VAL  = (unsigned short*)p; p += 75497472;   // bf16 [64*576,1024] (L1 only)
    unsigned short* PART = (unsigned short*)p; p += 90177536;   // bf16 partials (L2: 3x9437184, L3: 4x4194304)
    unsigned short* OPO  = (unsigned short*)p; p += 8388608;    // bf16 [4096,1024] op-proj out
    unsigned short* OUT0 = (unsigned short*)p; p += 8388608;
    unsigned short* LNO  = (unsigned short*)p; p += 8388608;
    unsigned short* OPW  = (unsigned short*)p; p += 2097152;
    unsigned short* FINW = (unsigned short*)p; p += 2097152;
    float* b1p  = (float*)p; p += 4096;
    float* b2p  = (float*)p; p += 4096;
    float* b3p  = (float*)p; p += 4096;
    float* awf  = (float*)p; p += 16384;
    int*   idxv = (int*)p;   p += 49152;
    double* h0  = (double*)p; p += 524288;
    double* rp  = (double*)p; p += 1024;
    double* offv_g  = (double*)p; p += 65536;   // [64,128]
    double* logit_g = (double*)p; p += 32768;   // [64,64]

    unsigned short* PART2 = PART;                       // 3 x 9437184 elems
    unsigned short* PART3 = PART + 3 * 9437184;         // 4 x 4194304 elems

    dim3 blk(256);

    // ---- query branch (fp64, batch-independent) ----
    rg1_kernel<<<16384, blk, 0, stream>>>(query_emb, rg_w1, rg_b1, h0);
    ln_gelu_rp_kernel<<<64, blk, 0, stream>>>(h0, rg_g, rg_b, rg_w2, rg_b2, rp);
    offlog_kernel<<<3072, blk, 0, stream>>>(query_emb, so_w, so_b, aw_w, aw_b, offv_g, logit_g);
    offfin_kernel<<<64, 64, 0, stream>>>(offv_g, logit_g, rp, awf, idxv);

    // ---- merged prep: all conversions + transposes + fused biases ----
    prep_kernel<<<26880, blk, 0, stream>>>(features, FEAT, vp_w, VPW, op_w, OPW, fin_w, FINW,
                                           p1_w, p2_w, p3_w, PT,
                                           vp_b, p1_b, p2_b, p3_b, b1p, b2p, b3p);

    // ---- fused weights: WW[1024,10752] = VPW @ PT^T ----
    gemm2w<true><<<dim3(84, 8), blk, 0, stream>>>(VPW, PT, nullptr, WW, 1024, WWN, 1024);

    // ---- value GEMMs: merged LPT dispatch (round-16 geometry: L3 z=4, L2 z=3, L1) ----
    gemm_val_merged<<<1264, 512, 0, stream>>>(FEAT, WW, b1p, VAL, PART2, PART3);

    // ---- fused gather + split-K reduce + bias ----
    gather_fused_kernel<<<2048, blk, 0, stream>>>(VAL, PART2, PART3, b2p, b3p, awf, idxv, OUT0);

    // ---- output projection (bf16 out) + LN (bf16->bf16) + final projection ----
    gemm2w<true><<<dim3(8, 32), blk, 0, stream>>>(OUT0, OPW, op_b, OPO, 4096, 1024, 1024);
    ln_b2b_kernel<<<4096, blk, 0, stream>>>(OPO, fln_g, fln_b, LNO);
    gemm2w<false><<<dim3(8, 32), blk, 0, stream>>>(LNO, FINW, fin_b, out, 4096, 1024, 1024);
}

// Round 19
// 436.519 us; speedup vs baseline: 1.4938x; 1.0349x over previous
//
#include <hip/hip_runtime.h>
#include <math.h>

#define EE 1024
#define WWN 10752      // 768 + 3072 + 6912

typedef __attribute__((ext_vector_type(4))) float f4;
typedef __attribute__((ext_vector_type(4))) float f32x4;
typedef __attribute__((ext_vector_type(8))) __bf16 bf16x8;
typedef __attribute__((ext_vector_type(8))) unsigned short ushort8;
typedef __attribute__((ext_vector_type(4))) unsigned short us4;

__device__ __forceinline__ unsigned short f2b(float x) {
    unsigned int u = __float_as_uint(x);
    unsigned int r = (u + 0x7fffu + ((u >> 16) & 1u)) >> 16;
    return (unsigned short)r;
}
__device__ __forceinline__ float b2f(unsigned short u) {
    unsigned int v = ((unsigned int)u) << 16;
    return __uint_as_float(v);
}

#define GLOAD16(g, l) __builtin_amdgcn_global_load_lds( \
    (const __attribute__((address_space(1))) unsigned int*)(g), \
    (__attribute__((address_space(3))) unsigned int*)(l), 16, 0, 0)

// ---------------------------------------------------------------------------
// Value-GEMM body: 256x256, BK=64, 8 waves (2m x 4n), per-wave 128x64.
// Round-10/12 proven K-loop (T3/T4/T5 schedule, 128B-row swizzle s^(r&7)).
// Fully compile-time specialized per (MODE, SPLIT, KT). LDS passed in.
// SPLIT: outp = bf16 partial slice (pre-offset by caller), no bias.
// non-SPLIT (MODE=1 only): writes VAL with row stride 576 (+bias).
// ---------------------------------------------------------------------------
template<int MODE, bool SPLIT, int KT>
__device__ __forceinline__ void gemm_body(
    unsigned short* __restrict__ AsB, unsigned short* __restrict__ BsB,
    const unsigned short* __restrict__ FEAT, const unsigned short* __restrict__ WW,
    const float* __restrict__ bias, void* __restrict__ outp,
    int by, int bx, int ktBase)
{
    constexpr int gw = (MODE == 1) ? 24 : (MODE == 2 ? 12 : 8);
    constexpr int Rl = gw * gw;                                   // 576/144/64
    constexpr int colOff = (MODE == 1) ? 0 : (MODE == 2 ? 768 : 3840);

    const int t = threadIdx.x;
    const int lane = t & 63;
    const int w = t >> 6;                // 0..7
    const int wm = w >> 2;               // 0..1  (128-row half)
    const int wn = w & 3;                // 0..3  (64-col quarter)
    const int m0 = by * 256, n0 = bx * 256;

    f32x4 acc[8][4] = {};

    // ---- staging roles: 4 gloads per operand per wave (32 rows x 128B) ----
    const int srow = lane >> 3;                  // 0..7 row within 8-row gload
    const int sseg = lane & 7;                   // stored 16B slot 0..7
    const int sgx  = sseg ^ srow;                // pre-swizzled global chunk
    int rbA[4];
#pragma unroll
    for (int g = 0; g < 4; ++g) {
        int gr = m0 + w * 32 + g * 8 + srow;
        if (MODE == 1) rbA[g] = gr;
        else {
            int b_ = gr / Rl, rl = gr - b_ * Rl;
            rbA[g] = b_ * 576 + (MODE * (rl / gw)) * 24 + MODE * (rl % gw);
        }
    }
    const unsigned short* gBbase = WW + (size_t)(n0 + w * 32 + srow) * WWN + colOff + sgx * 8;

    // ---- fragment-read roles ----
    const int fr = lane & 15;
    const int kg = lane >> 4;
    const int kgx0 = kg ^ (fr & 7);              // kk=0 slot
    const int kgx1 = kgx0 ^ 4;                   // kk=1 slot
    const int aOff0 = (wm * 128 + fr) * 64 + kgx0 * 8;
    const int aOff1 = (wm * 128 + fr) * 64 + kgx1 * 8;
    const int bOff0 = (wn * 64 + fr) * 64 + kgx0 * 8;
    const int bOff1 = (wn * 64 + fr) * 64 + kgx1 * 8;

    auto STAGE = [&](int buf, int ktl) {
        int kt = ktBase + ktl;                   // BK=64 tile index
        int s = kt / 12;                         // which 768-chunk of K
        int within = (kt - s * 12) * 64;         // + sgx*8 stays within the chunk
        int add = 0;
        if (MODE == 2)      add = (s >> 1) * 24 + (s & 1);
        else if (MODE == 3) { int di = s / 3; add = di * 24 + (s - 3 * di); }
        unsigned short* Asb = AsB + buf * 16384;
        unsigned short* Bsb = BsB + buf * 16384;
#pragma unroll
        for (int g = 0; g < 4; ++g)
            GLOAD16(FEAT + (size_t)(rbA[g] + add) * 768 + within + sgx * 8,
                    Asb + (w * 32 + g * 8) * 64);
#pragma unroll
        for (int g = 0; g < 4; ++g)
            GLOAD16(gBbase + (size_t)(g * 8) * WWN + (size_t)kt * 64,
                    Bsb + (w * 32 + g * 8) * 64);
    };

    int cur = 0;
    STAGE(0, 0);

    for (int tt = 0; tt < KT; ++tt) {
        // boundary: wait only for the stage issued one full iteration ago
        asm volatile("s_waitcnt vmcnt(0)" ::: "memory");
        __builtin_amdgcn_s_barrier();
        __builtin_amdgcn_sched_barrier(0);

        if (tt + 1 < KT) STAGE(cur ^ 1, tt + 1);        // in flight across phases
        __builtin_amdgcn_sched_barrier(0);

        const unsigned short* Asc = AsB + cur * 16384;
        const unsigned short* Bsc = BsB + cur * 16384;

        // ---- phase kk=0: K elems [0,32), 32 MFMA ----
        {
            bf16x8 bf[4], af[8];
#pragma unroll
            for (int j = 0; j < 4; ++j) bf[j] = *(const bf16x8*)(Bsc + bOff0 + j * 1024);
#pragma unroll
            for (int i = 0; i < 8; ++i) af[i] = *(const bf16x8*)(Asc + aOff0 + i * 1024);
            __builtin_amdgcn_s_setprio(1);
#pragma unroll
            for (int i = 0; i < 8; ++i)
#pragma unroll
                for (int j = 0; j < 4; ++j)
                    acc[i][j] = __builtin_amdgcn_mfma_f32_16x16x32_bf16(af[i], bf[j], acc[i][j], 0, 0, 0);
            __builtin_amdgcn_s_setprio(0);
        }
        __builtin_amdgcn_s_barrier();
        __builtin_amdgcn_sched_barrier(0);

        // ---- phase kk=1: K elems [32,64), 32 MFMA ----
        {
            bf16x8 bf[4], af[8];
#pragma unroll
            for (int j = 0; j < 4; ++j) bf[j] = *(const bf16x8*)(Bsc + bOff1 + j * 1024);
#pragma unroll
            for (int i = 0; i < 8; ++i) af[i] = *(const bf16x8*)(Asc + aOff1 + i * 1024);
            __builtin_amdgcn_s_setprio(1);
#pragma unroll
            for (int i = 0; i < 8; ++i)
#pragma unroll
                for (int j = 0; j < 4; ++j)
                    acc[i][j] = __builtin_amdgcn_mfma_f32_16x16x32_bf16(af[i], bf[j], acc[i][j], 0, 0, 0);
            __builtin_amdgcn_s_setprio(0);
        }
        cur ^= 1;
    }

#pragma unroll
    for (int i = 0; i < 8; ++i) {
#pragma unroll
        for (int r = 0; r < 4; ++r) {
            int m = m0 + wm * 128 + i * 16 + kg * 4 + r;   // local level row
#pragma unroll
            for (int j = 0; j < 4; ++j) {
                int n = n0 + wn * 64 + j * 16 + fr;
                if (SPLIT) {
                    ((unsigned short*)outp)[(size_t)m * EE + n] = f2b(acc[i][j][r]);
                } else {
                    // MODE==1 only: VAL stride 576 rows/batch
                    ((unsigned short*)outp)[(size_t)m * EE + n] = f2b(acc[i][j][r] + bias[n]);
                }
            }
        }
    }
}

// ---------------------------------------------------------------------------
// MERGED value GEMM dispatch, LPT order (round-16 proven geometry) with
// per-segment bijective XCD swizzle. hw blocks [0,256)=L3 (27 steps, z=4),
// [256,688)=L2 (16 steps, z=3), [688,1264)=L1 (12 steps).
// ---------------------------------------------------------------------------
__global__ __launch_bounds__(512, 2) void gemm_val_merged(
    const unsigned short* __restrict__ FEAT, const unsigned short* __restrict__ WW,
    const float* __restrict__ b1, unsigned short* __restrict__ VAL,
    unsigned short* __restrict__ PART2, unsigned short* __restrict__ PART3)
{
    __shared__ unsigned short As[2 * 256 * 64];   // 64KB
    __shared__ unsigned short Bs[2 * 256 * 64];   // 64KB

    int bid = blockIdx.x;
    if (bid < 256) {
        // L3: 4 z-slices x 64 tiles; chunk = 256/8 = 32
        int s = ((bid & 7) << 5) | (bid >> 3);
        int z = s >> 6, r = s & 63;
        gemm_body<3, true, 27>(As, Bs, FEAT, WW, nullptr,
                               PART3 + (size_t)z * 4194304, r >> 2, r & 3, z * 27);
    } else if (bid < 688) {
        // L2: 3 z-slices x 144 tiles; chunk = 432/8 = 54
        int j = bid - 256;
        int s = (j & 7) * 54 + (j >> 3);
        int z = s / 144, r = s - z * 144;
        gemm_body<2, true, 16>(As, Bs, FEAT, WW, nullptr,
                               PART2 + (size_t)z * 9437184, r >> 2, r & 3, z * 16);
    } else {
        // L1: 576 tiles; chunk = 576/8 = 72
        int j = bid - 688;
        int s = (j & 7) * 72 + (j >> 3);
        gemm_body<1, false, 12>(As, Bs, FEAT, WW, b1, VAL, s >> 2, s & 3, 0);
    }
}

// ---------------------------------------------------------------------------
// Fused gather + split-K reduce + bias (round-17/18 proven)
// ---------------------------------------------------------------------------
__global__ void gather_fused_kernel(const unsigned short* __restrict__ VAL,
                                    const unsigned short* __restrict__ P2,
                                    const unsigned short* __restrict__ P3,
                                    const float* __restrict__ b2, const float* __restrict__ b3,
                                    const float* __restrict__ awf, const int* __restrict__ idxv,
                                    unsigned short* __restrict__ out0)
{
    int idx = blockIdx.x * 256 + threadIdx.x;     // 524288 threads
    int d8 = idx & 7;
    int h  = (idx >> 3) & 15;
    int bq = idx >> 7;                            // b*64+q
    int b  = bq >> 6, q = bq & 63;
    int n0 = h * 64 + d8 * 8;
    float s[8] = {0.f};

    // ---- level 1: rows [0,576) from VAL (bias already applied) ----
#pragma unroll
    for (int p = 0; p < 4; ++p) {
        int row = idxv[((0 * 64 + q) * 16 + h) * 4 + p];
        float wgt = awf[(q * 16 + h) * 4 + p];
        ushort8 v = *(const ushort8*)(VAL + ((size_t)(b * 576 + row)) * 1024 + n0);
#pragma unroll
        for (int i = 0; i < 8; ++i) s[i] += wgt * b2f(v[i]);
    }

    // ---- level 2: 3 partial slices + b2 ----
    float bias2[8];
#pragma unroll
    for (int i = 0; i < 8; ++i) bias2[i] = b2[n0 + i];
#pragma unroll
    for (int p = 0; p < 4; ++p) {
        int rl = idxv[((1 * 64 + q) * 16 + h) * 4 + p] - 576;
        float wgt = awf[(q * 16 + h) * 4 + p];
        size_t mo = ((size_t)(b * 144 + rl)) * 1024 + n0;
        ushort8 va = *(const ushort8*)(P2 + mo);
        ushort8 vb = *(const ushort8*)(P2 + 9437184 + mo);
        ushort8 vc = *(const ushort8*)(P2 + 2 * 9437184 + mo);
#pragma unroll
        for (int i = 0; i < 8; ++i)
            s[i] += wgt * (b2f(va[i]) + b2f(vb[i]) + b2f(vc[i]) + bias2[i]);
    }

    // ---- level 3: 4 partial slices + b3 ----
    float bias3[8];
#pragma unroll
    for (int i = 0; i < 8; ++i) bias3[i] = b3[n0 + i];
#pragma unroll
    for (int p = 0; p < 4; ++p) {
        int rl = idxv[((2 * 64 + q) * 16 + h) * 4 + p] - 720;
        float wgt = awf[(q * 16 + h) * 4 + p];
        size_t mo = ((size_t)(b * 64 + rl)) * 1024 + n0;
        float a8[8] = {0.f};
#pragma unroll
        for (int k = 0; k < 4; ++k) {
            ushort8 v = *(const ushort8*)(P3 + (size_t)k * 4194304 + mo);
#pragma unroll
            for (int i = 0; i < 8; ++i) a8[i] += b2f(v[i]);
        }
#pragma unroll
        for (int i = 0; i < 8; ++i) s[i] += wgt * (a8[i] + bias3[i]);
    }

    ushort8 o;
#pragma unroll
    for (int i = 0; i < 8; ++i) o[i] = f2b(s[i]);
    *(ushort8*)(out0 + (size_t)bq * 1024 + n0) = o;
}

// ---------------------------------------------------------------------------
// 128x128 GEMM, BK=64, 4 waves (2x2) — round-15 proven.
// ---------------------------------------------------------------------------
template<bool OB>
__global__ __launch_bounds__(256, 2) void gemm2w(
    const unsigned short* __restrict__ A, const unsigned short* __restrict__ Bw,
    const float* __restrict__ bias, void* __restrict__ Cv,
    int M, int N, int K)
{
    __shared__ unsigned short As[2][128 * 64];   // 16KB each
    __shared__ unsigned short Bs[2][128 * 64];

    const int t = threadIdx.x;
    const int lane = t & 63;
    const int w = t >> 6;                // 0..3
    const int wm = w >> 1, wn = w & 1;

    int nwg = gridDim.x * gridDim.y;
    int bid = blockIdx.y * gridDim.x + blockIdx.x;
    int chunk = nwg >> 3;
    int swz = (bid & 7) * chunk + (bid >> 3);
    int by = swz / gridDim.x, bx = swz % gridDim.x;
    const int m0 = by * 128, n0 = bx * 128;

    f32x4 acc[4][4] = {};

    const int srow = lane >> 3;                  // 0..7
    const int sseg = lane & 7;
    const int sgx  = sseg ^ srow;
    const unsigned short* gA = A + (size_t)(m0 + w * 32 + srow) * K + sgx * 8;
    const unsigned short* gB = Bw + (size_t)(n0 + w * 32 + srow) * K + sgx * 8;

    const int fr = lane & 15;
    const int kg = lane >> 4;
    const int kgx0 = kg ^ (fr & 7);
    const int kgx1 = kgx0 ^ 4;
    const int aOff0 = (wm * 64 + fr) * 64 + kgx0 * 8;
    const int aOff1 = (wm * 64 + fr) * 64 + kgx1 * 8;
    const int bOff0 = (wn * 64 + fr) * 64 + kgx0 * 8;
    const int bOff1 = (wn * 64 + fr) * 64 + kgx1 * 8;

    auto STAGE = [&](int buf, int kt) {
        size_t k0 = (size_t)kt * 64;
#pragma unroll
        for (int g = 0; g < 4; ++g)
            GLOAD16(gA + (size_t)(g * 8) * K + k0, &As[buf][(w * 32 + g * 8) * 64]);
#pragma unroll
        for (int g = 0; g < 4; ++g)
            GLOAD16(gB + (size_t)(g * 8) * K + k0, &Bs[buf][(w * 32 + g * 8) * 64]);
    };

    const int nt = K >> 6;
    int cur = 0;
    STAGE(0, 0);

    for (int tt = 0; tt < nt; ++tt) {
        asm volatile("s_waitcnt vmcnt(0)" ::: "memory");
        __builtin_amdgcn_s_barrier();
        __builtin_amdgcn_sched_barrier(0);

        if (tt + 1 < nt) STAGE(cur ^ 1, tt + 1);
        __builtin_amdgcn_sched_barrier(0);

        // phase kk=0
        {
            bf16x8 bf[4], af[4];
#pragma unroll
            for (int j = 0; j < 4; ++j) bf[j] = *(const bf16x8*)(&Bs[cur][bOff0] + j * 1024);
#pragma unroll
            for (int i = 0; i < 4; ++i) af[i] = *(const bf16x8*)(&As[cur][aOff0] + i * 1024);
            __builtin_amdgcn_s_setprio(1);
#pragma unroll
            for (int i = 0; i < 4; ++i)
#pragma unroll
                for (int j = 0; j < 4; ++j)
                    acc[i][j] = __builtin_amdgcn_mfma_f32_16x16x32_bf16(af[i], bf[j], acc[i][j], 0, 0, 0);
            __builtin_amdgcn_s_setprio(0);
        }
        __builtin_amdgcn_s_barrier();
        __builtin_amdgcn_sched_barrier(0);

        // phase kk=1
        {
            bf16x8 bf[4], af[4];
#pragma unroll
            for (int j = 0; j < 4; ++j) bf[j] = *(const bf16x8*)(&Bs[cur][bOff1] + j * 1024);
#pragma unroll
            for (int i = 0; i < 4; ++i) af[i] = *(const bf16x8*)(&As[cur][aOff1] + i * 1024);
            __builtin_amdgcn_s_setprio(1);
#pragma unroll
            for (int i = 0; i < 4; ++i)
#pragma unroll
                for (int j = 0; j < 4; ++j)
                    acc[i][j] = __builtin_amdgcn_mfma_f32_16x16x32_bf16(af[i], bf[j], acc[i][j], 0, 0, 0);
            __builtin_amdgcn_s_setprio(0);
        }
        cur ^= 1;
    }

#pragma unroll
    for (int i = 0; i < 4; ++i) {
#pragma unroll
        for (int r = 0; r < 4; ++r) {
            int m = m0 + wm * 64 + i * 16 + kg * 4 + r;
#pragma unroll
            for (int j = 0; j < 4; ++j) {
                int n = n0 + wn * 64 + j * 16 + fr;
                float v = acc[i][j][r];
                if (bias) v += bias[n];
                if (OB) ((unsigned short*)Cv)[(size_t)m * N + n] = f2b(v);
                else    ((float*)Cv)[(size_t)m * N + n] = v;
            }
        }
    }
}

// ---------------------------------------------------------------------------
// MEGA-HEAD dispatch: rg1 + offlog + prep (all independent producers).
//   blocks [0,16384): rg1 fp64 dots (h0)
//   [16384,19456): offlog fp64 dots (offv_g, logit_g)
//   [19456,...): prep — conversions / transposes / fused biases
// fp64 summation order identical to the separate kernels.
// ---------------------------------------------------------------------------
__global__ void mega_head_kernel(
    const float* __restrict__ qe, const float* __restrict__ rg_w1, const float* __restrict__ rg_b1,
    double* __restrict__ h0,
    const float* __restrict__ so_w, const float* __restrict__ so_b,
    const float* __restrict__ aw_w, const float* __restrict__ aw_b,
    double* __restrict__ offv_g, double* __restrict__ logit_g,
    const float* __restrict__ feat, unsigned short* __restrict__ FEAT,
    const float* __restrict__ vpw, unsigned short* __restrict__ VPW,
    const float* __restrict__ opw, unsigned short* __restrict__ OPW,
    const float* __restrict__ finw, unsigned short* __restrict__ FINW,
    const float* __restrict__ p1, const float* __restrict__ p2,
    const float* __restrict__ p3, unsigned short* __restrict__ PT,
    const float* __restrict__ vp_b,
    const float* __restrict__ pb1, const float* __restrict__ pb2, const float* __restrict__ pb3,
    float* __restrict__ o1, float* __restrict__ o2, float* __restrict__ o3)
{
    __shared__ float tile[32][33];
    int B = blockIdx.x;
    if (B < 16384) {
        // ---- rg1 ----
        int o = B * 4 + (threadIdx.x >> 6);
        int lane = threadIdx.x & 63;
        int q = o >> 10, n = o & 1023;
        double s = 0.0;
        for (int k = lane; k < EE; k += 64)
            s += (double)qe[q * EE + k] * (double)rg_w1[(size_t)n * EE + k];
#pragma unroll
        for (int off = 32; off > 0; off >>= 1) s += __shfl_down(s, off, 64);
        if (lane == 0) h0[o] = s + (double)rg_b1[n];
    } else if (B < 19456) {
        // ---- offlog ----
        int o = (B - 16384) * 4 + (threadIdx.x >> 6);
        int lane = threadIdx.x & 63;
        const float* wrow;
        double bias;
        int q;
        if (o < 8192) { q = o >> 7; int j = o & 127; wrow = so_w + (size_t)j * EE; bias = (double)so_b[j]; }
        else          { int r = o - 8192; q = r >> 6; int n = r & 63; wrow = aw_w + (size_t)n * EE; bias = (double)aw_b[n]; }
        double s = 0.0;
        for (int k = lane; k < EE; k += 64)
            s += (double)qe[q * EE + k] * (double)wrow[k];
#pragma unroll
        for (int off = 32; off > 0; off >>= 1) s += __shfl_down(s, off, 64);
        if (lane == 0) {
            if (o < 8192) offv_g[o] = s + bias;
            else          logit_g[o - 8192] = s + bias;
        }
    } else {
        int blk = B - 19456;
        if (blk < 15360) {
            const float* in; unsigned short* out;
            if (blk < 13824)       { in = feat; out = FEAT; }
            else if (blk < 14336)  { in = vpw;  out = VPW;  blk -= 13824; }
            else if (blk < 14848)  { in = opw;  out = OPW;  blk -= 14336; }
            else                   { in = finw; out = FINW; blk -= 14848; }
            size_t i = ((size_t)blk * 256 + threadIdx.x) * 8;
            f4 x = *(const f4*)(in + i);
            f4 y = *(const f4*)(in + i + 4);
            ushort8 o;
            o[0] = f2b(x[0]); o[1] = f2b(x[1]); o[2] = f2b(x[2]); o[3] = f2b(x[3]);
            o[4] = f2b(y[0]); o[5] = f2b(y[1]); o[6] = f2b(y[2]); o[7] = f2b(y[3]);
            *(ushort8*)(out + i) = o;
        } else if (blk < 26112) {
            int fl = blk - 15360;
            int bx = fl % 336, byy = fl / 336;
            const float* in; unsigned short* out; int C;
            if (bx < 24)       { in = p1; out = PT;                C = 768; }
            else if (bx < 120) { in = p2; out = PT + 768  * 1024;  C = 3072; bx -= 24; }
            else               { in = p3; out = PT + 3840 * 1024;  C = 6912; bx -= 120; }
            const int R = 1024;
            int c0 = bx * 32, r0 = byy * 32;
            int tx = threadIdx.x & 31, ty = threadIdx.x >> 5;
#pragma unroll
            for (int i = 0; i < 32; i += 8)
                tile[ty + i][tx] = in[(size_t)(r0 + ty + i) * C + c0 + tx];
            __syncthreads();
#pragma unroll
            for (int i = 0; i < 32; i += 8)
                out[(size_t)(c0 + ty + i) * R + r0 + tx] = f2b(tile[tx][ty + i]);
        } else {
            int b = blk - 26112;
            const float* pb; float* bout;
            if (b < 256)      { pb = pb1; bout = o1; }
            else if (b < 512) { pb = pb2; bout = o2; b -= 256; }
            else              { pb = pb3; bout = o3; b -= 512; }
            int e = b * 4 + (threadIdx.x >> 6);
            int lane = threadIdx.x & 63;
            float s = 0.f;
            for (int k = lane; k < EE; k += 64) s += vpw[(size_t)e * EE + k] * pb[k];
#pragma unroll
            for (int o = 32; o > 0; o >>= 1) s += __shfl_down(s, o, 64);
            if (lane == 0) bout[e] = s + vp_b[e];
        }
    }
}

// ---------------------------------------------------------------------------
// qfin: per-query LN+GELU (fp64, exact) -> rp in shared -> softmax + index
// snap. Merges ln_gelu_rp + offfin; identical fp64 summation order.
// ---------------------------------------------------------------------------
__global__ void qfin_kernel(const double* __restrict__ h0, const float* __restrict__ g,
                            const float* __restrict__ bb, const float* __restrict__ w2,
                            const float* __restrict__ b2,
                            const double* __restrict__ offv_g, const double* __restrict__ logit_g,
                            float* __restrict__ awf, int* __restrict__ idxv)
{
    __shared__ double red[256];
    __shared__ double stats[2];
    __shared__ double hsh[1024];
    __shared__ double rps[2];
    int q = blockIdx.x, t = threadIdx.x;
    double x[4];
#pragma unroll
    for (int i = 0; i < 4; ++i) x[i] = h0[q * 1024 + t + i * 256];
    double s = x[0] + x[1] + x[2] + x[3];
    red[t] = s; __syncthreads();
    for (int o = 128; o; o >>= 1) { if (t < o) red[t] += red[t + o]; __syncthreads(); }
    if (t == 0) stats[0] = red[0] / 1024.0;
    __syncthreads();
    double mean = stats[0];
    double d = 0.0;
#pragma unroll
    for (int i = 0; i < 4; ++i) { double dd = x[i] - mean; d += dd * dd; }
    red[t] = d; __syncthreads();
    for (int o = 128; o; o >>= 1) { if (t < o) red[t] += red[t + o]; __syncthreads(); }
    if (t == 0) stats[1] = red[0] / 1024.0;
    __syncthreads();
    double inv = 1.0 / sqrt(stats[1] + 1e-5);
#pragma unroll
    for (int i = 0; i < 4; ++i) {
        int c = t + i * 256;
        double y = (x[i] - mean) * inv * (double)g[c] + (double)bb[c];
        hsh[c] = y * 0.5 * (1.0 + erf(y * 0.70710678118654752440));
    }
    __syncthreads();
    if (t < 128) {
        int r = t >> 6;
        int lane = t & 63;
        double sv = 0.0;
        for (int k = lane; k < EE; k += 64)
            sv += hsh[k] * (double)w2[r * 1024 + k];
#pragma unroll
        for (int off = 32; off > 0; off >>= 1) sv += __shfl_down(sv, off, 64);
        if (lane == 0) rps[r] = 1.0 / (1.0 + exp(-(sv + (double)b2[r])));
    }
    __syncthreads();
    if (t < 64) {
        int hh = t >> 2, p = t & 3;
        const double* logit = logit_g + q * 64;
        const double* offv  = offv_g + q * 128;
        double l0 = logit[hh * 4 + 0], l1 = logit[hh * 4 + 1];
        double l2 = logit[hh * 4 + 2], l3 = logit[hh * 4 + 3];
        double m = fmax(fmax(l0, l1), fmax(l2, l3));
        double den = exp(l0 - m) + exp(l1 - m) + exp(l2 - m) + exp(l3 - m);
        awf[(q * 16 + hh) * 4 + p] = (float)(exp(logit[hh * 4 + p] - m) / den);
        const int Wss[3] = {24, 12, 8};
        const int starts[3] = {0, 576, 720};
        double ox = offv[(hh * 4 + p) * 2 + 0], oy = offv[(hh * 4 + p) * 2 + 1];
        double rx = rps[0], ry = rps[1];
#pragma unroll
        for (int l = 0; l < 3; ++l) {
            int Ws = Wss[l];
            double sx = rx + ox; sx = sx < 0.0 ? 0.0 : (sx > 1.0 ? 1.0 : sx);
            double sy = ry + oy; sy = sy < 0.0 ? 0.0 : (sy > 1.0 ? 1.0 : sy);
            int x0 = (int)floor(sx * (double)(Ws - 1));
            int y0 = (int)floor(sy * (double)(Ws - 1));
            idxv[((l * 64 + q) * 16 + hh) * 4 + p] = starts[l] + y0 * Ws + x0;
        }
    }
}

// LayerNorm over 1024: bf16 in, bf16 out; fp32 stats; us4 vector access
__global__ void ln_b2b_kernel(const unsigned short* __restrict__ x, const float* __restrict__ g,
                              const float* __restrict__ bb, unsigned short* __restrict__ y)
{
    __shared__ float red[256];
    __shared__ float stats[2];
    int r = blockIdx.x, t = threadIdx.x;
    us4 v4 = *(const us4*)(x + (size_t)r * 1024 + t * 4);
    float v[4];
#pragma unroll
    for (int i = 0; i < 4; ++i) v[i] = b2f(v4[i]);
    float s = v[0] + v[1] + v[2] + v[3];
    red[t] = s; __syncthreads();
    for (int o = 128; o; o >>= 1) { if (t < o) red[t] += red[t + o]; __syncthreads(); }
    if (t == 0) stats[0] = red[0] / 1024.f;
    __syncthreads();
    float mean = stats[0];
    float d = 0.f;
#pragma unroll
    for (int i = 0; i < 4; ++i) { float dd = v[i] - mean; d += dd * dd; }
    red[t] = d; __syncthreads();
    for (int o = 128; o; o >>= 1) { if (t < o) red[t] += red[t + o]; __syncthreads(); }
    if (t == 0) stats[1] = red[0] / 1024.f;
    __syncthreads();
    float inv = 1.f / sqrtf(stats[1] + 1e-5f);
    us4 o4;
#pragma unroll
    for (int i = 0; i < 4; ++i) {
        int c = t * 4 + i;
        o4[i] = f2b((v[i] - mean) * inv * g[c] + bb[c]);
    }
    *(us4*)(y + (size_t)r * 1024 + t * 4) = o4;
}

extern "C" void kernel_launch(void* const* d_in, const int* in_sizes, int n_in,
                              void* d_out, int out_size, void* d_ws, size_t ws_size,
                              hipStream_t stream)
{
    const float* features  = (const float*)d_in[0];
    const float* p1_w      = (const float*)d_in[1];
    const float* p1_b      = (const float*)d_in[2];
    const float* p2_w      = (const float*)d_in[3];
    const float* p2_b      = (const float*)d_in[4];
    const float* p3_w      = (const float*)d_in[5];
    const float* p3_b      = (const float*)d_in[6];
    const float* query_emb = (const float*)d_in[7];
    const float* rg_w1     = (const float*)d_in[8];
    const float* rg_b1     = (const float*)d_in[9];
    const float* rg_g      = (const float*)d_in[10];
    const float* rg_b      = (const float*)d_in[11];
    const float* rg_w2     = (const float*)d_in[12];
    const float* rg_b2     = (const float*)d_in[13];
    const float* so_w      = (const float*)d_in[14];
    const float* so_b      = (const float*)d_in[15];
    const float* aw_w      = (const float*)d_in[16];
    const float* aw_b      = (const float*)d_in[17];
    const float* vp_w      = (const float*)d_in[18];
    const float* vp_b      = (const float*)d_in[19];
    const float* op_w      = (const float*)d_in[20];
    const float* op_b      = (const float*)d_in[21];
    const float* fln_g     = (const float*)d_in[22];
    const float* fln_b     = (const float*)d_in[23];
    const float* fin_w     = (const float*)d_in[24];
    const float* fin_b     = (const float*)d_in[25];
    float* out = (float*)d_out;

    // ---- workspace layout (bytes) ----
    char* p = (char*)d_ws;
    unsigned short* FEAT = (unsigned short*)p; p += 56623104;   // bf16 [B*576,768]
    unsigned short* PT   = (unsigned short*)p; p += 22020096;   // [10752,1024] stacked p_w^T
    unsigned short* WW   = (unsigned short*)p; p += 22020096;   // [1024,10752] fused weights
    unsigned short* VPW  = (unsigned short*)p; p += 2097152;
    unsigned short* VAL  = (unsigned short*)p; p += 75497472;   // bf16 [64*576,1024] (L1 only)
    unsigned short* PART = (unsigned short*)p; p += 90177536;   // bf16 partials (L2: 3x9437184, L3: 4x4194304)
    unsigned short* OPO  = (unsigned short*)p; p += 8388608;    // bf16 [4096,1024] op-proj out
    unsigned short* OUT0 = (unsigned short*)p; p += 8388608;
    unsigned short* LNO  = (unsigned short*)p; p += 8388608;
    unsigned short* OPW  = (unsigned short*)p; p += 2097152;
    unsigned short* FINW = (unsigned short*)p; p += 2097152;
    float* b1p  = (float*)p; p += 4096;
    float* b2p  = (float*)p; p += 4096;
    float* b3p  = (float*)p; p += 4096;
    float* awf  = (float*)p; p += 16384;
    int*   idxv = (int*)p;   p += 49152;
    double* h0  = (double*)p; p += 524288;
    double* offv_g  = (double*)p; p += 65536;   // [64,128]
    double* logit_g = (double*)p; p += 32768;   // [64,64]

    unsigned short* PART2 = PART;                       // 3 x 9437184 elems
    unsigned short* PART3 = PART + 3 * 9437184;         // 4 x 4194304 elems

    dim3 blk(256);

    // ---- mega head: rg1 + offlog + prep (independent producers) ----
    mega_head_kernel<<<46336, blk, 0, stream>>>(
        query_emb, rg_w1, rg_b1, h0,
        so_w, so_b, aw_w, aw_b, offv_g, logit_g,
        features, FEAT, vp_w, VPW, op_w, OPW, fin_w, FINW,
        p1_w, p2_w, p3_w, PT,
        vp_b, p1_b, p2_b, p3_b, b1p, b2p, b3p);

    // ---- qfin: LN+GELU -> rp -> softmax + index snap (one 64-block kernel) ----
    qfin_kernel<<<64, blk, 0, stream>>>(h0, rg_g, rg_b, rg_w2, rg_b2,
                                        offv_g, logit_g, awf, idxv);

    // ---- fused weights: WW[1024,10752] = VPW @ PT^T ----
    gemm2w<true><<<dim3(84, 8), blk, 0, stream>>>(VPW, PT, nullptr, WW, 1024, WWN, 1024);

    // ---- value GEMMs: merged LPT dispatch (L3 z=4, L2 z=3, L1) ----
    gemm_val_merged<<<1264, 512, 0, stream>>>(FEAT, WW, b1p, VAL, PART2, PART3);

    // ---- fused gather + split-K reduce + bias ----
    gather_fused_kernel<<<2048, blk, 0, stream>>>(VAL, PART2, PART3, b2p, b3p, awf, idxv, OUT0);

    // ---- output projection (bf16 out) + LN (bf16->bf16) + final projection ----
    gemm2w<true><<<dim3(8, 32), blk, 0, stream>>>(OUT0, OPW, op_b, OPO, 4096, 1024, 1024);
    ln_b2b_kernel<<<4096, blk, 0, stream>>>(OPO, fln_g, fln_b, LNO);
    gemm2w<false><<<dim3(8, 32), blk, 0, stream>>>(LNO, FINW, fin_b, out, 4096, 1024, 1024);
}

// Round 20
// 410.802 us; speedup vs baseline: 1.5873x; 1.0626x over previous
//
#include <hip/hip_runtime.h>
#include <math.h>

#define EE 1024
#define WWN 10752      // 768 + 3072 + 6912

typedef __attribute__((ext_vector_type(4))) float f4;
typedef __attribute__((ext_vector_type(4))) float f32x4;
typedef __attribute__((ext_vector_type(8))) __bf16 bf16x8;
typedef __attribute__((ext_vector_type(8))) unsigned short ushort8;
typedef __attribute__((ext_vector_type(4))) unsigned short us4;

__device__ __forceinline__ unsigned short f2b(float x) {
    unsigned int u = __float_as_uint(x);
    unsigned int r = (u + 0x7fffu + ((u >> 16) & 1u)) >> 16;
    return (unsigned short)r;
}
__device__ __forceinline__ float b2f(unsigned short u) {
    unsigned int v = ((unsigned int)u) << 16;
    return __uint_as_float(v);
}

#define GLOAD16(g, l) __builtin_amdgcn_global_load_lds( \
    (const __attribute__((address_space(1))) unsigned int*)(g), \
    (__attribute__((address_space(3))) unsigned int*)(l), 16, 0, 0)

// ---------------------------------------------------------------------------
// Value-GEMM body: 256x256, BK=64, 8 waves (2m x 4n), per-wave 128x64.
// Round-10/12 proven K-loop (T3/T4/T5 schedule, 128B-row swizzle s^(r&7)).
// ---------------------------------------------------------------------------
template<int MODE, bool SPLIT, int KT>
__device__ __forceinline__ void gemm_body(
    unsigned short* __restrict__ AsB, unsigned short* __restrict__ BsB,
    const unsigned short* __restrict__ FEAT, const unsigned short* __restrict__ WW,
    const float* __restrict__ bias, void* __restrict__ outp,
    int by, int bx, int ktBase)
{
    constexpr int gw = (MODE == 1) ? 24 : (MODE == 2 ? 12 : 8);
    constexpr int Rl = gw * gw;                                   // 576/144/64
    constexpr int colOff = (MODE == 1) ? 0 : (MODE == 2 ? 768 : 3840);

    const int t = threadIdx.x;
    const int lane = t & 63;
    const int w = t >> 6;                // 0..7
    const int wm = w >> 2;               // 0..1  (128-row half)
    const int wn = w & 3;                // 0..3  (64-col quarter)
    const int m0 = by * 256, n0 = bx * 256;

    f32x4 acc[8][4] = {};

    const int srow = lane >> 3;                  // 0..7 row within 8-row gload
    const int sseg = lane & 7;                   // stored 16B slot 0..7
    const int sgx  = sseg ^ srow;                // pre-swizzled global chunk
    int rbA[4];
#pragma unroll
    for (int g = 0; g < 4; ++g) {
        int gr = m0 + w * 32 + g * 8 + srow;
        if (MODE == 1) rbA[g] = gr;
        else {
            int b_ = gr / Rl, rl = gr - b_ * Rl;
            rbA[g] = b_ * 576 + (MODE * (rl / gw)) * 24 + MODE * (rl % gw);
        }
    }
    const unsigned short* gBbase = WW + (size_t)(n0 + w * 32 + srow) * WWN + colOff + sgx * 8;

    const int fr = lane & 15;
    const int kg = lane >> 4;
    const int kgx0 = kg ^ (fr & 7);              // kk=0 slot
    const int kgx1 = kgx0 ^ 4;                   // kk=1 slot
    const int aOff0 = (wm * 128 + fr) * 64 + kgx0 * 8;
    const int aOff1 = (wm * 128 + fr) * 64 + kgx1 * 8;
    const int bOff0 = (wn * 64 + fr) * 64 + kgx0 * 8;
    const int bOff1 = (wn * 64 + fr) * 64 + kgx1 * 8;

    auto STAGE = [&](int buf, int ktl) {
        int kt = ktBase + ktl;                   // BK=64 tile index
        int s = kt / 12;                         // which 768-chunk of K
        int within = (kt - s * 12) * 64;
        int add = 0;
        if (MODE == 2)      add = (s >> 1) * 24 + (s & 1);
        else if (MODE == 3) { int di = s / 3; add = di * 24 + (s - 3 * di); }
        unsigned short* Asb = AsB + buf * 16384;
        unsigned short* Bsb = BsB + buf * 16384;
#pragma unroll
        for (int g = 0; g < 4; ++g)
            GLOAD16(FEAT + (size_t)(rbA[g] + add) * 768 + within + sgx * 8,
                    Asb + (w * 32 + g * 8) * 64);
#pragma unroll
        for (int g = 0; g < 4; ++g)
            GLOAD16(gBbase + (size_t)(g * 8) * WWN + (size_t)kt * 64,
                    Bsb + (w * 32 + g * 8) * 64);
    };

    int cur = 0;
    STAGE(0, 0);

    for (int tt = 0; tt < KT; ++tt) {
        asm volatile("s_waitcnt vmcnt(0)" ::: "memory");
        __builtin_amdgcn_s_barrier();
        __builtin_amdgcn_sched_barrier(0);

        if (tt + 1 < KT) STAGE(cur ^ 1, tt + 1);
        __builtin_amdgcn_sched_barrier(0);

        const unsigned short* Asc = AsB + cur * 16384;
        const unsigned short* Bsc = BsB + cur * 16384;

        {
            bf16x8 bf[4], af[8];
#pragma unroll
            for (int j = 0; j < 4; ++j) bf[j] = *(const bf16x8*)(Bsc + bOff0 + j * 1024);
#pragma unroll
            for (int i = 0; i < 8; ++i) af[i] = *(const bf16x8*)(Asc + aOff0 + i * 1024);
            __builtin_amdgcn_s_setprio(1);
#pragma unroll
            for (int i = 0; i < 8; ++i)
#pragma unroll
                for (int j = 0; j < 4; ++j)
                    acc[i][j] = __builtin_amdgcn_mfma_f32_16x16x32_bf16(af[i], bf[j], acc[i][j], 0, 0, 0);
            __builtin_amdgcn_s_setprio(0);
        }
        __builtin_amdgcn_s_barrier();
        __builtin_amdgcn_sched_barrier(0);

        {
            bf16x8 bf[4], af[8];
#pragma unroll
            for (int j = 0; j < 4; ++j) bf[j] = *(const bf16x8*)(Bsc + bOff1 + j * 1024);
#pragma unroll
            for (int i = 0; i < 8; ++i) af[i] = *(const bf16x8*)(Asc + aOff1 + i * 1024);
            __builtin_amdgcn_s_setprio(1);
#pragma unroll
            for (int i = 0; i < 8; ++i)
#pragma unroll
                for (int j = 0; j < 4; ++j)
                    acc[i][j] = __builtin_amdgcn_mfma_f32_16x16x32_bf16(af[i], bf[j], acc[i][j], 0, 0, 0);
            __builtin_amdgcn_s_setprio(0);
        }
        cur ^= 1;
    }

#pragma unroll
    for (int i = 0; i < 8; ++i) {
#pragma unroll
        for (int r = 0; r < 4; ++r) {
            int m = m0 + wm * 128 + i * 16 + kg * 4 + r;
#pragma unroll
            for (int j = 0; j < 4; ++j) {
                int n = n0 + wn * 64 + j * 16 + fr;
                if (SPLIT) {
                    ((unsigned short*)outp)[(size_t)m * EE + n] = f2b(acc[i][j][r]);
                } else {
                    ((unsigned short*)outp)[(size_t)m * EE + n] = f2b(acc[i][j][r] + bias[n]);
                }
            }
        }
    }
}

// ---------------------------------------------------------------------------
// MERGED value GEMM dispatch, LPT order (round-16/18 proven geometry).
// ---------------------------------------------------------------------------
__global__ __launch_bounds__(512, 2) void gemm_val_merged(
    const unsigned short* __restrict__ FEAT, const unsigned short* __restrict__ WW,
    const float* __restrict__ b1, unsigned short* __restrict__ VAL,
    unsigned short* __restrict__ PART2, unsigned short* __restrict__ PART3)
{
    __shared__ unsigned short As[2 * 256 * 64];   // 64KB
    __shared__ unsigned short Bs[2 * 256 * 64];   // 64KB

    int bid = blockIdx.x;
    if (bid < 256) {
        int s = ((bid & 7) << 5) | (bid >> 3);
        int z = s >> 6, r = s & 63;
        gemm_body<3, true, 27>(As, Bs, FEAT, WW, nullptr,
                               PART3 + (size_t)z * 4194304, r >> 2, r & 3, z * 27);
    } else if (bid < 688) {
        int j = bid - 256;
        int s = (j & 7) * 54 + (j >> 3);
        int z = s / 144, r = s - z * 144;
        gemm_body<2, true, 16>(As, Bs, FEAT, WW, nullptr,
                               PART2 + (size_t)z * 9437184, r >> 2, r & 3, z * 16);
    } else {
        int j = bid - 688;
        int s = (j & 7) * 72 + (j >> 3);
        gemm_body<1, false, 12>(As, Bs, FEAT, WW, b1, VAL, s >> 2, s & 3, 0);
    }
}

// ---------------------------------------------------------------------------
// Fused gather + split-K reduce + bias (round-18 proven)
// ---------------------------------------------------------------------------
__global__ void gather_fused_kernel(const unsigned short* __restrict__ VAL,
                                    const unsigned short* __restrict__ P2,
                                    const unsigned short* __restrict__ P3,
                                    const float* __restrict__ b2, const float* __restrict__ b3,
                                    const float* __restrict__ awf, const int* __restrict__ idxv,
                                    unsigned short* __restrict__ out0)
{
    int idx = blockIdx.x * 256 + threadIdx.x;     // 524288 threads
    int d8 = idx & 7;
    int h  = (idx >> 3) & 15;
    int bq = idx >> 7;                            // b*64+q
    int b  = bq >> 6, q = bq & 63;
    int n0 = h * 64 + d8 * 8;
    float s[8] = {0.f};

#pragma unroll
    for (int p = 0; p < 4; ++p) {
        int row = idxv[((0 * 64 + q) * 16 + h) * 4 + p];
        float wgt = awf[(q * 16 + h) * 4 + p];
        ushort8 v = *(const ushort8*)(VAL + ((size_t)(b * 576 + row)) * 1024 + n0);
#pragma unroll
        for (int i = 0; i < 8; ++i) s[i] += wgt * b2f(v[i]);
    }

    float bias2[8];
#pragma unroll
    for (int i = 0; i < 8; ++i) bias2[i] = b2[n0 + i];
#pragma unroll
    for (int p = 0; p < 4; ++p) {
        int rl = idxv[((1 * 64 + q) * 16 + h) * 4 + p] - 576;
        float wgt = awf[(q * 16 + h) * 4 + p];
        size_t mo = ((size_t)(b * 144 + rl)) * 1024 + n0;
        ushort8 va = *(const ushort8*)(P2 + mo);
        ushort8 vb = *(const ushort8*)(P2 + 9437184 + mo);
        ushort8 vc = *(const ushort8*)(P2 + 2 * 9437184 + mo);
#pragma unroll
        for (int i = 0; i < 8; ++i)
            s[i] += wgt * (b2f(va[i]) + b2f(vb[i]) + b2f(vc[i]) + bias2[i]);
    }

    float bias3[8];
#pragma unroll
    for (int i = 0; i < 8; ++i) bias3[i] = b3[n0 + i];
#pragma unroll
    for (int p = 0; p < 4; ++p) {
        int rl = idxv[((2 * 64 + q) * 16 + h) * 4 + p] - 720;
        float wgt = awf[(q * 16 + h) * 4 + p];
        size_t mo = ((size_t)(b * 64 + rl)) * 1024 + n0;
        float a8[8] = {0.f};
#pragma unroll
        for (int k = 0; k < 4; ++k) {
            ushort8 v = *(const ushort8*)(P3 + (size_t)k * 4194304 + mo);
#pragma unroll
            for (int i = 0; i < 8; ++i) a8[i] += b2f(v[i]);
        }
#pragma unroll
        for (int i = 0; i < 8; ++i) s[i] += wgt * (a8[i] + bias3[i]);
    }

    ushort8 o;
#pragma unroll
    for (int i = 0; i < 8; ++i) o[i] = f2b(s[i]);
    *(ushort8*)(out0 + (size_t)bq * 1024 + n0) = o;
}

// ---------------------------------------------------------------------------
// 128x128 GEMM body, BK=64, 4 waves (2x2) — round-15 proven K-loop; now a
// device function with explicit (by,bx,kBase,nt). OB: bf16 out; else fp32.
// ---------------------------------------------------------------------------
template<bool OB>
__device__ __forceinline__ void gemm2w_body(
    unsigned short* __restrict__ AsB, unsigned short* __restrict__ BsB,
    const unsigned short* __restrict__ A, const unsigned short* __restrict__ Bw,
    const float* __restrict__ bias, void* __restrict__ Cv,
    int M, int N, int K, int by, int bx, int kBase, int nt)
{
    const int t = threadIdx.x;
    const int lane = t & 63;
    const int w = t >> 6;                // 0..3
    const int wm = w >> 1, wn = w & 1;
    const int m0 = by * 128, n0 = bx * 128;

    f32x4 acc[4][4] = {};

    const int srow = lane >> 3;                  // 0..7
    const int sseg = lane & 7;
    const int sgx  = sseg ^ srow;
    const unsigned short* gA = A + (size_t)(m0 + w * 32 + srow) * K + kBase + sgx * 8;
    const unsigned short* gB = Bw + (size_t)(n0 + w * 32 + srow) * K + kBase + sgx * 8;

    const int fr = lane & 15;
    const int kg = lane >> 4;
    const int kgx0 = kg ^ (fr & 7);
    const int kgx1 = kgx0 ^ 4;
    const int aOff0 = (wm * 64 + fr) * 64 + kgx0 * 8;
    const int aOff1 = (wm * 64 + fr) * 64 + kgx1 * 8;
    const int bOff0 = (wn * 64 + fr) * 64 + kgx0 * 8;
    const int bOff1 = (wn * 64 + fr) * 64 + kgx1 * 8;

    auto STAGE = [&](int buf, int kt) {
        size_t k0 = (size_t)kt * 64;
        unsigned short* Asb = AsB + buf * 8192;
        unsigned short* Bsb = BsB + buf * 8192;
#pragma unroll
        for (int g = 0; g < 4; ++g)
            GLOAD16(gA + (size_t)(g * 8) * K + k0, Asb + (w * 32 + g * 8) * 64);
#pragma unroll
        for (int g = 0; g < 4; ++g)
            GLOAD16(gB + (size_t)(g * 8) * K + k0, Bsb + (w * 32 + g * 8) * 64);
    };

    int cur = 0;
    STAGE(0, 0);

    for (int tt = 0; tt < nt; ++tt) {
        asm volatile("s_waitcnt vmcnt(0)" ::: "memory");
        __builtin_amdgcn_s_barrier();
        __builtin_amdgcn_sched_barrier(0);

        if (tt + 1 < nt) STAGE(cur ^ 1, tt + 1);
        __builtin_amdgcn_sched_barrier(0);

        const unsigned short* Asc = AsB + cur * 8192;
        const unsigned short* Bsc = BsB + cur * 8192;

        {
            bf16x8 bf[4], af[4];
#pragma unroll
            for (int j = 0; j < 4; ++j) bf[j] = *(const bf16x8*)(Bsc + bOff0 + j * 1024);
#pragma unroll
            for (int i = 0; i < 4; ++i) af[i] = *(const bf16x8*)(Asc + aOff0 + i * 1024);
            __builtin_amdgcn_s_setprio(1);
#pragma unroll
            for (int i = 0; i < 4; ++i)
#pragma unroll
                for (int j = 0; j < 4; ++j)
                    acc[i][j] = __builtin_amdgcn_mfma_f32_16x16x32_bf16(af[i], bf[j], acc[i][j], 0, 0, 0);
            __builtin_amdgcn_s_setprio(0);
        }
        __builtin_amdgcn_s_barrier();
        __builtin_amdgcn_sched_barrier(0);

        {
            bf16x8 bf[4], af[4];
#pragma unroll
            for (int j = 0; j < 4; ++j) bf[j] = *(const bf16x8*)(Bsc + bOff1 + j * 1024);
#pragma unroll
            for (int i = 0; i < 4; ++i) af[i] = *(const bf16x8*)(Asc + aOff1 + i * 1024);
            __builtin_amdgcn_s_setprio(1);
#pragma unroll
            for (int i = 0; i < 4; ++i)
#pragma unroll
                for (int j = 0; j < 4; ++j)
                    acc[i][j] = __builtin_amdgcn_mfma_f32_16x16x32_bf16(af[i], bf[j], acc[i][j], 0, 0, 0);
            __builtin_amdgcn_s_setprio(0);
        }
        cur ^= 1;
    }

#pragma unroll
    for (int i = 0; i < 4; ++i) {
#pragma unroll
        for (int r = 0; r < 4; ++r) {
            int m = m0 + wm * 64 + i * 16 + kg * 4 + r;
#pragma unroll
            for (int j = 0; j < 4; ++j) {
                int n = n0 + wn * 64 + j * 16 + fr;
                float v = acc[i][j][r];
                if (bias) v += bias[n];
                if (OB) ((unsigned short*)Cv)[(size_t)m * N + n] = f2b(v);
                else    ((float*)Cv)[(size_t)m * N + n] = v;
            }
        }
    }
}

// ---------------------------------------------------------------------------
// qfin body: per-query LN+GELU (fp64, exact) -> rp in shared -> softmax +
// index snap. 256 threads. Shared arrays passed in.
// ---------------------------------------------------------------------------
__device__ __forceinline__ void qfin_body(
    int q, double* red, double* stats, double* hsh, double* rps,
    const double* __restrict__ h0, const float* __restrict__ g,
    const float* __restrict__ bb, const float* __restrict__ w2,
    const float* __restrict__ b2,
    const double* __restrict__ offv_g, const double* __restrict__ logit_g,
    float* __restrict__ awf, int* __restrict__ idxv)
{
    int t = threadIdx.x;
    double x[4];
#pragma unroll
    for (int i = 0; i < 4; ++i) x[i] = h0[q * 1024 + t + i * 256];
    double s = x[0] + x[1] + x[2] + x[3];
    red[t] = s; __syncthreads();
    for (int o = 128; o; o >>= 1) { if (t < o) red[t] += red[t + o]; __syncthreads(); }
    if (t == 0) stats[0] = red[0] / 1024.0;
    __syncthreads();
    double mean = stats[0];
    double d = 0.0;
#pragma unroll
    for (int i = 0; i < 4; ++i) { double dd = x[i] - mean; d += dd * dd; }
    red[t] = d; __syncthreads();
    for (int o = 128; o; o >>= 1) { if (t < o) red[t] += red[t + o]; __syncthreads(); }
    if (t == 0) stats[1] = red[0] / 1024.0;
    __syncthreads();
    double inv = 1.0 / sqrt(stats[1] + 1e-5);
#pragma unroll
    for (int i = 0; i < 4; ++i) {
        int c = t + i * 256;
        double y = (x[i] - mean) * inv * (double)g[c] + (double)bb[c];
        hsh[c] = y * 0.5 * (1.0 + erf(y * 0.70710678118654752440));
    }
    __syncthreads();
    if (t < 128) {
        int r = t >> 6;
        int lane = t & 63;
        double sv = 0.0;
        for (int k = lane; k < EE; k += 64)
            sv += hsh[k] * (double)w2[r * 1024 + k];
#pragma unroll
        for (int off = 32; off > 0; off >>= 1) sv += __shfl_down(sv, off, 64);
        if (lane == 0) rps[r] = 1.0 / (1.0 + exp(-(sv + (double)b2[r])));
    }
    __syncthreads();
    if (t < 64) {
        int hh = t >> 2, p = t & 3;
        const double* logit = logit_g + q * 64;
        const double* offv  = offv_g + q * 128;
        double l0 = logit[hh * 4 + 0], l1 = logit[hh * 4 + 1];
        double l2 = logit[hh * 4 + 2], l3 = logit[hh * 4 + 3];
        double m = fmax(fmax(l0, l1), fmax(l2, l3));
        double den = exp(l0 - m) + exp(l1 - m) + exp(l2 - m) + exp(l3 - m);
        awf[(q * 16 + hh) * 4 + p] = (float)(exp(logit[hh * 4 + p] - m) / den);
        const int Wss[3] = {24, 12, 8};
        const int starts[3] = {0, 576, 720};
        double ox = offv[(hh * 4 + p) * 2 + 0], oy = offv[(hh * 4 + p) * 2 + 1];
        double rx = rps[0], ry = rps[1];
#pragma unroll
        for (int l = 0; l < 3; ++l) {
            int Ws = Wss[l];
            double sx = rx + ox; sx = sx < 0.0 ? 0.0 : (sx > 1.0 ? 1.0 : sx);
            double sy = ry + oy; sy = sy < 0.0 ? 0.0 : (sy > 1.0 ? 1.0 : sy);
            int x0 = (int)floor(sx * (double)(Ws - 1));
            int y0 = (int)floor(sy * (double)(Ws - 1));
            idxv[((l * 64 + q) * 16 + hh) * 4 + p] = starts[l] + y0 * Ws + x0;
        }
    }
}

// ---------------------------------------------------------------------------
// WW GEMM + qfin merged dispatch: blocks [0,672) = WW (1024x10752, K=1024);
// [672,736) = qfin. Both depend only on mega_head.
// ---------------------------------------------------------------------------
__global__ __launch_bounds__(256, 2) void ww_qfin_kernel(
    const unsigned short* __restrict__ VPW, const unsigned short* __restrict__ PT,
    unsigned short* __restrict__ WW,
    const double* __restrict__ h0, const float* __restrict__ rg_g,
    const float* __restrict__ rg_b, const float* __restrict__ rg_w2,
    const float* __restrict__ rg_b2,
    const double* __restrict__ offv_g, const double* __restrict__ logit_g,
    float* __restrict__ awf, int* __restrict__ idxv)
{
    __shared__ unsigned short As[2 * 128 * 64];   // 32KB
    __shared__ unsigned short Bs[2 * 128 * 64];   // 32KB
    __shared__ double qsh[256 + 2 + 1024 + 2];    // ~10KB (red/stats/hsh/rps)

    int bid = blockIdx.x;
    if (bid < 672) {
        int swz = (bid & 7) * 84 + (bid >> 3);    // bijective over 672
        int by = swz / 84, bx = swz % 84;         // by in [0,8), bx in [0,84)
        gemm2w_body<true>(As, Bs, VPW, PT, nullptr, WW, 1024, WWN, 1024, by, bx, 0, 16);
    } else {
        qfin_body(bid - 672, qsh, qsh + 256, qsh + 258, qsh + 1282,
                  h0, rg_g, rg_b, rg_w2, rg_b2, offv_g, logit_g, awf, idxv);
    }
}

// ---------------------------------------------------------------------------
// split-K (z in {0,1}) partial 4096x1024x1024 GEMM, fp32 partials.
// ---------------------------------------------------------------------------
__global__ __launch_bounds__(256, 2) void gemm_pk_kernel(
    const unsigned short* __restrict__ A, const unsigned short* __restrict__ Bw,
    float* __restrict__ P)
{
    __shared__ unsigned short As[2 * 128 * 64];
    __shared__ unsigned short Bs[2 * 128 * 64];
    int nwg = gridDim.x * gridDim.y;              // 256
    int bid = blockIdx.y * gridDim.x + blockIdx.x;
    int chunk = nwg >> 3;
    int swz = (bid & 7) * chunk + (bid >> 3);
    int by = swz / gridDim.x, bx = swz % gridDim.x;
    gemm2w_body<false>(As, Bs, A, Bw, nullptr,
                       P + (size_t)blockIdx.z * 4194304,
                       4096, 1024, 1024, by, bx, blockIdx.z * 512, 8);
}

// ---------------------------------------------------------------------------
// LN over (p0 + p1 + op_b), bf16 out (round-4 lnsum numerics + us4 layout)
// ---------------------------------------------------------------------------
__global__ void lnsum_b2b_kernel(const float* __restrict__ p0, const float* __restrict__ p1,
                                 const float* __restrict__ opb, const float* __restrict__ g,
                                 const float* __restrict__ bb, unsigned short* __restrict__ y)
{
    __shared__ float red[256];
    __shared__ float stats[2];
    int r = blockIdx.x, t = threadIdx.x;
    f4 a = *(const f4*)(p0 + (size_t)r * 1024 + t * 4);
    f4 bvec = *(const f4*)(p1 + (size_t)r * 1024 + t * 4);
    float v[4];
#pragma unroll
    for (int i = 0; i < 4; ++i) v[i] = a[i] + bvec[i] + opb[t * 4 + i];
    float s = v[0] + v[1] + v[2] + v[3];
    red[t] = s; __syncthreads();
    for (int o = 128; o; o >>= 1) { if (t < o) red[t] += red[t + o]; __syncthreads(); }
    if (t == 0) stats[0] = red[0] / 1024.f;
    __syncthreads();
    float mean = stats[0];
    float d = 0.f;
#pragma unroll
    for (int i = 0; i < 4; ++i) { float dd = v[i] - mean; d += dd * dd; }
    red[t] = d; __syncthreads();
    for (int o = 128; o; o >>= 1) { if (t < o) red[t] += red[t + o]; __syncthreads(); }
    if (t == 0) stats[1] = red[0] / 1024.f;
    __syncthreads();
    float inv = 1.f / sqrtf(stats[1] + 1e-5f);
    us4 o4;
#pragma unroll
    for (int i = 0; i < 4; ++i) {
        int c = t * 4 + i;
        o4[i] = f2b((v[i] - mean) * inv * g[c] + bb[c]);
    }
    *(us4*)(y + (size_t)r * 1024 + t * 4) = o4;
}

// out = p0 + p1 + fin_b (fp32) — round-4 proven
__global__ void finred_kernel(const float* __restrict__ p0, const float* __restrict__ p1,
                              const float* __restrict__ fb, float* __restrict__ out)
{
    int idx = blockIdx.x * 256 + threadIdx.x;
    size_t e0 = (size_t)idx * 8;
    int n = (int)(e0 & 1023);
    f4 a0 = *(const f4*)(p0 + e0);
    f4 a1 = *(const f4*)(p0 + e0 + 4);
    f4 b0 = *(const f4*)(p1 + e0);
    f4 b1 = *(const f4*)(p1 + e0 + 4);
    f4 o0, o1;
#pragma unroll
    for (int i = 0; i < 4; ++i) { o0[i] = a0[i] + b0[i] + fb[n + i]; o1[i] = a1[i] + b1[i] + fb[n + 4 + i]; }
    *(f4*)(out + e0) = o0;
    *(f4*)(out + e0 + 4) = o1;
}

// ---------------------------------------------------------------------------
// MEGA-HEAD dispatch (round-19 proven): rg1 + offlog + prep.
// ---------------------------------------------------------------------------
__global__ void mega_head_kernel(
    const float* __restrict__ qe, const float* __restrict__ rg_w1, const float* __restrict__ rg_b1,
    double* __restrict__ h0,
    const float* __restrict__ so_w, const float* __restrict__ so_b,
    const float* __restrict__ aw_w, const float* __restrict__ aw_b,
    double* __restrict__ offv_g, double* __restrict__ logit_g,
    const float* __restrict__ feat, unsigned short* __restrict__ FEAT,
    const float* __restrict__ vpw, unsigned short* __restrict__ VPW,
    const float* __restrict__ opw, unsigned short* __restrict__ OPW,
    const float* __restrict__ finw, unsigned short* __restrict__ FINW,
    const float* __restrict__ p1, const float* __restrict__ p2,
    const float* __restrict__ p3, unsigned short* __restrict__ PT,
    const float* __restrict__ vp_b,
    const float* __restrict__ pb1, const float* __restrict__ pb2, const float* __restrict__ pb3,
    float* __restrict__ o1, float* __restrict__ o2, float* __restrict__ o3)
{
    __shared__ float tile[32][33];
    int B = blockIdx.x;
    if (B < 16384) {
        int o = B * 4 + (threadIdx.x >> 6);
        int lane = threadIdx.x & 63;
        int q = o >> 10, n = o & 1023;
        double s = 0.0;
        for (int k = lane; k < EE; k += 64)
            s += (double)qe[q * EE + k] * (double)rg_w1[(size_t)n * EE + k];
#pragma unroll
        for (int off = 32; off > 0; off >>= 1) s += __shfl_down(s, off, 64);
        if (lane == 0) h0[o] = s + (double)rg_b1[n];
    } else if (B < 19456) {
        int o = (B - 16384) * 4 + (threadIdx.x >> 6);
        int lane = threadIdx.x & 63;
        const float* wrow;
        double bias;
        int q;
        if (o < 8192) { q = o >> 7; int j = o & 127; wrow = so_w + (size_t)j * EE; bias = (double)so_b[j]; }
        else          { int r = o - 8192; q = r >> 6; int n = r & 63; wrow = aw_w + (size_t)n * EE; bias = (double)aw_b[n]; }
        double s = 0.0;
        for (int k = lane; k < EE; k += 64)
            s += (double)qe[q * EE + k] * (double)wrow[k];
#pragma unroll
        for (int off = 32; off > 0; off >>= 1) s += __shfl_down(s, off, 64);
        if (lane == 0) {
            if (o < 8192) offv_g[o] = s + bias;
            else          logit_g[o - 8192] = s + bias;
        }
    } else {
        int blk = B - 19456;
        if (blk < 15360) {
            const float* in; unsigned short* out;
            if (blk < 13824)       { in = feat; out = FEAT; }
            else if (blk < 14336)  { in = vpw;  out = VPW;  blk -= 13824; }
            else if (blk < 14848)  { in = opw;  out = OPW;  blk -= 14336; }
            else                   { in = finw; out = FINW; blk -= 14848; }
            size_t i = ((size_t)blk * 256 + threadIdx.x) * 8;
            f4 x = *(const f4*)(in + i);
            f4 y = *(const f4*)(in + i + 4);
            ushort8 o;
            o[0] = f2b(x[0]); o[1] = f2b(x[1]); o[2] = f2b(x[2]); o[3] = f2b(x[3]);
            o[4] = f2b(y[0]); o[5] = f2b(y[1]); o[6] = f2b(y[2]); o[7] = f2b(y[3]);
            *(ushort8*)(out + i) = o;
        } else if (blk < 26112) {
            int fl = blk - 15360;
            int bx = fl % 336, byy = fl / 336;
            const float* in; unsigned short* out; int C;
            if (bx < 24)       { in = p1; out = PT;                C = 768; }
            else if (bx < 120) { in = p2; out = PT + 768  * 1024;  C = 3072; bx -= 24; }
            else               { in = p3; out = PT + 3840 * 1024;  C = 6912; bx -= 120; }
            const int R = 1024;
            int c0 = bx * 32, r0 = byy * 32;
            int tx = threadIdx.x & 31, ty = threadIdx.x >> 5;
#pragma unroll
            for (int i = 0; i < 32; i += 8)
                tile[ty + i][tx] = in[(size_t)(r0 + ty + i) * C + c0 + tx];
            __syncthreads();
#pragma unroll
            for (int i = 0; i < 32; i += 8)
                out[(size_t)(c0 + ty + i) * R + r0 + tx] = f2b(tile[tx][ty + i]);
        } else {
            int b = blk - 26112;
            const float* pb; float* bout;
            if (b < 256)      { pb = pb1; bout = o1; }
            else if (b < 512) { pb = pb2; bout = o2; b -= 256; }
            else              { pb = pb3; bout = o3; b -= 512; }
            int e = b * 4 + (threadIdx.x >> 6);
            int lane = threadIdx.x & 63;
            float s = 0.f;
            for (int k = lane; k < EE; k += 64) s += vpw[(size_t)e * EE + k] * pb[k];
#pragma unroll
            for (int o = 32; o > 0; o >>= 1) s += __shfl_down(s, o, 64);
            if (lane == 0) bout[e] = s + vp_b[e];
        }
    }
}

extern "C" void kernel_launch(void* const* d_in, const int* in_sizes, int n_in,
                              void* d_out, int out_size, void* d_ws, size_t ws_size,
                              hipStream_t stream)
{
    const float* features  = (const float*)d_in[0];
    const float* p1_w      = (const float*)d_in[1];
    const float* p1_b      = (const float*)d_in[2];
    const float* p2_w      = (const float*)d_in[3];
    const float* p2_b      = (const float*)d_in[4];
    const float* p3_w      = (const float*)d_in[5];
    const float* p3_b      = (const float*)d_in[6];
    const float* query_emb = (const float*)d_in[7];
    const float* rg_w1     = (const float*)d_in[8];
    const float* rg_b1     = (const float*)d_in[9];
    const float* rg_g      = (const float*)d_in[10];
    const float* rg_b      = (const float*)d_in[11];
    const float* rg_w2     = (const float*)d_in[12];
    const float* rg_b2     = (const float*)d_in[13];
    const float* so_w      = (const float*)d_in[14];
    const float* so_b      = (const float*)d_in[15];
    const float* aw_w      = (const float*)d_in[16];
    const float* aw_b      = (const float*)d_in[17];
    const float* vp_w      = (const float*)d_in[18];
    const float* vp_b      = (const float*)d_in[19];
    const float* op_w      = (const float*)d_in[20];
    const float* op_b      = (const float*)d_in[21];
    const float* fln_g     = (const float*)d_in[22];
    const float* fln_b     = (const float*)d_in[23];
    const float* fin_w     = (const float*)d_in[24];
    const float* fin_b     = (const float*)d_in[25];
    float* out = (float*)d_out;

    // ---- workspace layout (bytes) ----
    char* p = (char*)d_ws;
    unsigned short* FEAT = (unsigned short*)p; p += 56623104;   // bf16 [B*576,768]
    unsigned short* PT   = (unsigned short*)p; p += 22020096;   // [10752,1024] stacked p_w^T
    unsigned short* WW   = (unsigned short*)p; p += 22020096;   // [1024,10752] fused weights
    unsigned short* VPW  = (unsigned short*)p; p += 2097152;
    unsigned short* VAL  = (unsigned short*)p; p += 75497472;   // bf16 [64*576,1024] (L1 only)
    unsigned short* PART = (unsigned short*)p; p += 90177536;   // bf16 partials; reused as fp32 POUT/PFIN
    unsigned short* OUT0 = (unsigned short*)p; p += 8388608;
    unsigned short* LNO  = (unsigned short*)p; p += 8388608;
    unsigned short* OPW  = (unsigned short*)p; p += 2097152;
    unsigned short* FINW = (unsigned short*)p; p += 2097152;
    float* b1p  = (float*)p; p += 4096;
    float* b2p  = (float*)p; p += 4096;
    float* b3p  = (float*)p; p += 4096;
    float* awf  = (float*)p; p += 16384;
    int*   idxv = (int*)p;   p += 49152;
    double* h0  = (double*)p; p += 524288;
    double* offv_g  = (double*)p; p += 65536;   // [64,128]
    double* logit_g = (double*)p; p += 32768;   // [64,64]

    unsigned short* PART2 = PART;                       // 3 x 9437184 elems
    unsigned short* PART3 = PART + 3 * 9437184;         // 4 x 4194304 elems
    float* PPK = (float*)PART;                          // 2 x 4194304 f32 (epilogue partials)

    dim3 blk(256);

    // ---- mega head: rg1 + offlog + prep (independent producers) ----
    mega_head_kernel<<<46336, blk, 0, stream>>>(
        query_emb, rg_w1, rg_b1, h0,
        so_w, so_b, aw_w, aw_b, offv_g, logit_g,
        features, FEAT, vp_w, VPW, op_w, OPW, fin_w, FINW,
        p1_w, p2_w, p3_w, PT,
        vp_b, p1_b, p2_b, p3_b, b1p, b2p, b3p);

    // ---- WW GEMM + qfin merged ----
    ww_qfin_kernel<<<736, blk, 0, stream>>>(VPW, PT, WW,
                                            h0, rg_g, rg_b, rg_w2, rg_b2,
                                            offv_g, logit_g, awf, idxv);

    // ---- value GEMMs: merged LPT dispatch (L3 z=4, L2 z=3, L1) ----
    gemm_val_merged<<<1264, 512, 0, stream>>>(FEAT, WW, b1p, VAL, PART2, PART3);

    // ---- fused gather + split-K reduce + bias ----
    gather_fused_kernel<<<2048, blk, 0, stream>>>(VAL, PART2, PART3, b2p, b3p, awf, idxv, OUT0);

    // ---- output projection (split-K x2, fp32 partials) + LN(sum) ----
    gemm_pk_kernel<<<dim3(8, 32, 2), blk, 0, stream>>>(OUT0, OPW, PPK);
    lnsum_b2b_kernel<<<4096, blk, 0, stream>>>(PPK, PPK + 4194304, op_b, fln_g, fln_b, LNO);

    // ---- final projection (split-K x2) + reduce ----
    gemm_pk_kernel<<<dim3(8, 32, 2), blk, 0, stream>>>(LNO, FINW, PPK);
    finred_kernel<<<2048, blk, 0, stream>>>(PPK, PPK + 4194304, fin_b, out);
}

// Round 21
// 407.202 us; speedup vs baseline: 1.6013x; 1.0088x over previous
//
#include <hip/hip_runtime.h>
#include <math.h>

#define EE 1024
#define WWN 10752      // 768 + 3072 + 6912

typedef __attribute__((ext_vector_type(4))) float f4;
typedef __attribute__((ext_vector_type(4))) float f32x4;
typedef __attribute__((ext_vector_type(8))) __bf16 bf16x8;
typedef __attribute__((ext_vector_type(8))) unsigned short ushort8;
typedef __attribute__((ext_vector_type(4))) unsigned short us4;

__device__ __forceinline__ unsigned short f2b(float x) {
    unsigned int u = __float_as_uint(x);
    unsigned int r = (u + 0x7fffu + ((u >> 16) & 1u)) >> 16;
    return (unsigned short)r;
}
__device__ __forceinline__ float b2f(unsigned short u) {
    unsigned int v = ((unsigned int)u) << 16;
    return __uint_as_float(v);
}

#define GLOAD16(g, l) __builtin_amdgcn_global_load_lds( \
    (const __attribute__((address_space(1))) unsigned int*)(g), \
    (__attribute__((address_space(3))) unsigned int*)(l), 16, 0, 0)

// ---------------------------------------------------------------------------
// Value-GEMM body: 256x256, BK=64, 8 waves (2m x 4n), per-wave 128x64.
// Round-10/12 proven K-loop; round-21 change: mid-phase barrier REMOVED
// (both phases read buf[cur]; only the boundary barrier carries the hazard).
// ---------------------------------------------------------------------------
template<int MODE, bool SPLIT, int KT>
__device__ __forceinline__ void gemm_body(
    unsigned short* __restrict__ AsB, unsigned short* __restrict__ BsB,
    const unsigned short* __restrict__ FEAT, const unsigned short* __restrict__ WW,
    const float* __restrict__ bias, void* __restrict__ outp,
    int by, int bx, int ktBase)
{
    constexpr int gw = (MODE == 1) ? 24 : (MODE == 2 ? 12 : 8);
    constexpr int Rl = gw * gw;                                   // 576/144/64
    constexpr int colOff = (MODE == 1) ? 0 : (MODE == 2 ? 768 : 3840);

    const int t = threadIdx.x;
    const int lane = t & 63;
    const int w = t >> 6;                // 0..7
    const int wm = w >> 2;               // 0..1  (128-row half)
    const int wn = w & 3;                // 0..3  (64-col quarter)
    const int m0 = by * 256, n0 = bx * 256;

    f32x4 acc[8][4] = {};

    const int srow = lane >> 3;                  // 0..7 row within 8-row gload
    const int sseg = lane & 7;                   // stored 16B slot 0..7
    const int sgx  = sseg ^ srow;                // pre-swizzled global chunk
    int rbA[4];
#pragma unroll
    for (int g = 0; g < 4; ++g) {
        int gr = m0 + w * 32 + g * 8 + srow;
        if (MODE == 1) rbA[g] = gr;
        else {
            int b_ = gr / Rl, rl = gr - b_ * Rl;
            rbA[g] = b_ * 576 + (MODE * (rl / gw)) * 24 + MODE * (rl % gw);
        }
    }
    const unsigned short* gBbase = WW + (size_t)(n0 + w * 32 + srow) * WWN + colOff + sgx * 8;

    const int fr = lane & 15;
    const int kg = lane >> 4;
    const int kgx0 = kg ^ (fr & 7);              // kk=0 slot
    const int kgx1 = kgx0 ^ 4;                   // kk=1 slot
    const int aOff0 = (wm * 128 + fr) * 64 + kgx0 * 8;
    const int aOff1 = (wm * 128 + fr) * 64 + kgx1 * 8;
    const int bOff0 = (wn * 64 + fr) * 64 + kgx0 * 8;
    const int bOff1 = (wn * 64 + fr) * 64 + kgx1 * 8;

    auto STAGE = [&](int buf, int ktl) {
        int kt = ktBase + ktl;                   // BK=64 tile index
        int s = kt / 12;                         // which 768-chunk of K
        int within = (kt - s * 12) * 64;
        int add = 0;
        if (MODE == 2)      add = (s >> 1) * 24 + (s & 1);
        else if (MODE == 3) { int di = s / 3; add = di * 24 + (s - 3 * di); }
        unsigned short* Asb = AsB + buf * 16384;
        unsigned short* Bsb = BsB + buf * 16384;
#pragma unroll
        for (int g = 0; g < 4; ++g)
            GLOAD16(FEAT + (size_t)(rbA[g] + add) * 768 + within + sgx * 8,
                    Asb + (w * 32 + g * 8) * 64);
#pragma unroll
        for (int g = 0; g < 4; ++g)
            GLOAD16(gBbase + (size_t)(g * 8) * WWN + (size_t)kt * 64,
                    Bsb + (w * 32 + g * 8) * 64);
    };

    int cur = 0;
    STAGE(0, 0);

    for (int tt = 0; tt < KT; ++tt) {
        asm volatile("s_waitcnt vmcnt(0)" ::: "memory");
        __builtin_amdgcn_s_barrier();
        __builtin_amdgcn_sched_barrier(0);

        if (tt + 1 < KT) STAGE(cur ^ 1, tt + 1);
        __builtin_amdgcn_sched_barrier(0);

        const unsigned short* Asc = AsB + cur * 16384;
        const unsigned short* Bsc = BsB + cur * 16384;

        // ---- phase kk=0: K elems [0,32), 32 MFMA ----
        {
            bf16x8 bf[4], af[8];
#pragma unroll
            for (int j = 0; j < 4; ++j) bf[j] = *(const bf16x8*)(Bsc + bOff0 + j * 1024);
#pragma unroll
            for (int i = 0; i < 8; ++i) af[i] = *(const bf16x8*)(Asc + aOff0 + i * 1024);
            __builtin_amdgcn_s_setprio(1);
#pragma unroll
            for (int i = 0; i < 8; ++i)
#pragma unroll
                for (int j = 0; j < 4; ++j)
                    acc[i][j] = __builtin_amdgcn_mfma_f32_16x16x32_bf16(af[i], bf[j], acc[i][j], 0, 0, 0);
            __builtin_amdgcn_s_setprio(0);
        }
        // (mid-phase barrier removed: both phases read buf[cur]; no hazard)

        // ---- phase kk=1: K elems [32,64), 32 MFMA ----
        {
            bf16x8 bf[4], af[8];
#pragma unroll
            for (int j = 0; j < 4; ++j) bf[j] = *(const bf16x8*)(Bsc + bOff1 + j * 1024);
#pragma unroll
            for (int i = 0; i < 8; ++i) af[i] = *(const bf16x8*)(Asc + aOff1 + i * 1024);
            __builtin_amdgcn_s_setprio(1);
#pragma unroll
            for (int i = 0; i < 8; ++i)
#pragma unroll
                for (int j = 0; j < 4; ++j)
                    acc[i][j] = __builtin_amdgcn_mfma_f32_16x16x32_bf16(af[i], bf[j], acc[i][j], 0, 0, 0);
            __builtin_amdgcn_s_setprio(0);
        }
        cur ^= 1;
    }

#pragma unroll
    for (int i = 0; i < 8; ++i) {
#pragma unroll
        for (int r = 0; r < 4; ++r) {
            int m = m0 + wm * 128 + i * 16 + kg * 4 + r;
#pragma unroll
            for (int j = 0; j < 4; ++j) {
                int n = n0 + wn * 64 + j * 16 + fr;
                if (SPLIT) {
                    ((unsigned short*)outp)[(size_t)m * EE + n] = f2b(acc[i][j][r]);
                } else {
                    ((unsigned short*)outp)[(size_t)m * EE + n] = f2b(acc[i][j][r] + bias[n]);
                }
            }
        }
    }
}

// ---------------------------------------------------------------------------
// MERGED value GEMM dispatch, LPT order (round-16/18 proven geometry).
// ---------------------------------------------------------------------------
__global__ __launch_bounds__(512, 2) void gemm_val_merged(
    const unsigned short* __restrict__ FEAT, const unsigned short* __restrict__ WW,
    const float* __restrict__ b1, unsigned short* __restrict__ VAL,
    unsigned short* __restrict__ PART2, unsigned short* __restrict__ PART3)
{
    __shared__ unsigned short As[2 * 256 * 64];   // 64KB
    __shared__ unsigned short Bs[2 * 256 * 64];   // 64KB

    int bid = blockIdx.x;
    if (bid < 256) {
        int s = ((bid & 7) << 5) | (bid >> 3);
        int z = s >> 6, r = s & 63;
        gemm_body<3, true, 27>(As, Bs, FEAT, WW, nullptr,
                               PART3 + (size_t)z * 4194304, r >> 2, r & 3, z * 27);
    } else if (bid < 688) {
        int j = bid - 256;
        int s = (j & 7) * 54 + (j >> 3);
        int z = s / 144, r = s - z * 144;
        gemm_body<2, true, 16>(As, Bs, FEAT, WW, nullptr,
                               PART2 + (size_t)z * 9437184, r >> 2, r & 3, z * 16);
    } else {
        int j = bid - 688;
        int s = (j & 7) * 72 + (j >> 3);
        gemm_body<1, false, 12>(As, Bs, FEAT, WW, b1, VAL, s >> 2, s & 3, 0);
    }
}

// ---------------------------------------------------------------------------
// Fused gather + split-K reduce + bias (round-18 proven)
// ---------------------------------------------------------------------------
__global__ void gather_fused_kernel(const unsigned short* __restrict__ VAL,
                                    const unsigned short* __restrict__ P2,
                                    const unsigned short* __restrict__ P3,
                                    const float* __restrict__ b2, const float* __restrict__ b3,
                                    const float* __restrict__ awf, const int* __restrict__ idxv,
                                    unsigned short* __restrict__ out0)
{
    int idx = blockIdx.x * 256 + threadIdx.x;     // 524288 threads
    int d8 = idx & 7;
    int h  = (idx >> 3) & 15;
    int bq = idx >> 7;                            // b*64+q
    int b  = bq >> 6, q = bq & 63;
    int n0 = h * 64 + d8 * 8;
    float s[8] = {0.f};

#pragma unroll
    for (int p = 0; p < 4; ++p) {
        int row = idxv[((0 * 64 + q) * 16 + h) * 4 + p];
        float wgt = awf[(q * 16 + h) * 4 + p];
        ushort8 v = *(const ushort8*)(VAL + ((size_t)(b * 576 + row)) * 1024 + n0);
#pragma unroll
        for (int i = 0; i < 8; ++i) s[i] += wgt * b2f(v[i]);
    }

    float bias2[8];
#pragma unroll
    for (int i = 0; i < 8; ++i) bias2[i] = b2[n0 + i];
#pragma unroll
    for (int p = 0; p < 4; ++p) {
        int rl = idxv[((1 * 64 + q) * 16 + h) * 4 + p] - 576;
        float wgt = awf[(q * 16 + h) * 4 + p];
        size_t mo = ((size_t)(b * 144 + rl)) * 1024 + n0;
        ushort8 va = *(const ushort8*)(P2 + mo);
        ushort8 vb = *(const ushort8*)(P2 + 9437184 + mo);
        ushort8 vc = *(const ushort8*)(P2 + 2 * 9437184 + mo);
#pragma unroll
        for (int i = 0; i < 8; ++i)
            s[i] += wgt * (b2f(va[i]) + b2f(vb[i]) + b2f(vc[i]) + bias2[i]);
    }

    float bias3[8];
#pragma unroll
    for (int i = 0; i < 8; ++i) bias3[i] = b3[n0 + i];
#pragma unroll
    for (int p = 0; p < 4; ++p) {
        int rl = idxv[((2 * 64 + q) * 16 + h) * 4 + p] - 720;
        float wgt = awf[(q * 16 + h) * 4 + p];
        size_t mo = ((size_t)(b * 64 + rl)) * 1024 + n0;
        float a8[8] = {0.f};
#pragma unroll
        for (int k = 0; k < 4; ++k) {
            ushort8 v = *(const ushort8*)(P3 + (size_t)k * 4194304 + mo);
#pragma unroll
            for (int i = 0; i < 8; ++i) a8[i] += b2f(v[i]);
        }
#pragma unroll
        for (int i = 0; i < 8; ++i) s[i] += wgt * (a8[i] + bias3[i]);
    }

    ushort8 o;
#pragma unroll
    for (int i = 0; i < 8; ++i) o[i] = f2b(s[i]);
    *(ushort8*)(out0 + (size_t)bq * 1024 + n0) = o;
}

// ---------------------------------------------------------------------------
// 128x128 GEMM body, BK=64, 4 waves (2x2) — mid-phase barrier removed (same
// proof as gemm_body). OB: bf16 out; else fp32.
// ---------------------------------------------------------------------------
template<bool OB>
__device__ __forceinline__ void gemm2w_body(
    unsigned short* __restrict__ AsB, unsigned short* __restrict__ BsB,
    const unsigned short* __restrict__ A, const unsigned short* __restrict__ Bw,
    const float* __restrict__ bias, void* __restrict__ Cv,
    int M, int N, int K, int by, int bx, int kBase, int nt)
{
    const int t = threadIdx.x;
    const int lane = t & 63;
    const int w = t >> 6;                // 0..3
    const int wm = w >> 1, wn = w & 1;
    const int m0 = by * 128, n0 = bx * 128;

    f32x4 acc[4][4] = {};

    const int srow = lane >> 3;                  // 0..7
    const int sseg = lane & 7;
    const int sgx  = sseg ^ srow;
    const unsigned short* gA = A + (size_t)(m0 + w * 32 + srow) * K + kBase + sgx * 8;
    const unsigned short* gB = Bw + (size_t)(n0 + w * 32 + srow) * K + kBase + sgx * 8;

    const int fr = lane & 15;
    const int kg = lane >> 4;
    const int kgx0 = kg ^ (fr & 7);
    const int kgx1 = kgx0 ^ 4;
    const int aOff0 = (wm * 64 + fr) * 64 + kgx0 * 8;
    const int aOff1 = (wm * 64 + fr) * 64 + kgx1 * 8;
    const int bOff0 = (wn * 64 + fr) * 64 + kgx0 * 8;
    const int bOff1 = (wn * 64 + fr) * 64 + kgx1 * 8;

    auto STAGE = [&](int buf, int kt) {
        size_t k0 = (size_t)kt * 64;
        unsigned short* Asb = AsB + buf * 8192;
        unsigned short* Bsb = BsB + buf * 8192;
#pragma unroll
        for (int g = 0; g < 4; ++g)
            GLOAD16(gA + (size_t)(g * 8) * K + k0, Asb + (w * 32 + g * 8) * 64);
#pragma unroll
        for (int g = 0; g < 4; ++g)
            GLOAD16(gB + (size_t)(g * 8) * K + k0, Bsb + (w * 32 + g * 8) * 64);
    };

    int cur = 0;
    STAGE(0, 0);

    for (int tt = 0; tt < nt; ++tt) {
        asm volatile("s_waitcnt vmcnt(0)" ::: "memory");
        __builtin_amdgcn_s_barrier();
        __builtin_amdgcn_sched_barrier(0);

        if (tt + 1 < nt) STAGE(cur ^ 1, tt + 1);
        __builtin_amdgcn_sched_barrier(0);

        const unsigned short* Asc = AsB + cur * 8192;
        const unsigned short* Bsc = BsB + cur * 8192;

        {
            bf16x8 bf[4], af[4];
#pragma unroll
            for (int j = 0; j < 4; ++j) bf[j] = *(const bf16x8*)(Bsc + bOff0 + j * 1024);
#pragma unroll
            for (int i = 0; i < 4; ++i) af[i] = *(const bf16x8*)(Asc + aOff0 + i * 1024);
            __builtin_amdgcn_s_setprio(1);
#pragma unroll
            for (int i = 0; i < 4; ++i)
#pragma unroll
                for (int j = 0; j < 4; ++j)
                    acc[i][j] = __builtin_amdgcn_mfma_f32_16x16x32_bf16(af[i], bf[j], acc[i][j], 0, 0, 0);
            __builtin_amdgcn_s_setprio(0);
        }
        // (mid-phase barrier removed)
        {
            bf16x8 bf[4], af[4];
#pragma unroll
            for (int j = 0; j < 4; ++j) bf[j] = *(const bf16x8*)(Bsc + bOff1 + j * 1024);
#pragma unroll
            for (int i = 0; i < 4; ++i) af[i] = *(const bf16x8*)(Asc + aOff1 + i * 1024);
            __builtin_amdgcn_s_setprio(1);
#pragma unroll
            for (int i = 0; i < 4; ++i)
#pragma unroll
                for (int j = 0; j < 4; ++j)
                    acc[i][j] = __builtin_amdgcn_mfma_f32_16x16x32_bf16(af[i], bf[j], acc[i][j], 0, 0, 0);
            __builtin_amdgcn_s_setprio(0);
        }
        cur ^= 1;
    }

#pragma unroll
    for (int i = 0; i < 4; ++i) {
#pragma unroll
        for (int r = 0; r < 4; ++r) {
            int m = m0 + wm * 64 + i * 16 + kg * 4 + r;
#pragma unroll
            for (int j = 0; j < 4; ++j) {
                int n = n0 + wn * 64 + j * 16 + fr;
                float v = acc[i][j][r];
                if (bias) v += bias[n];
                if (OB) ((unsigned short*)Cv)[(size_t)m * N + n] = f2b(v);
                else    ((float*)Cv)[(size_t)m * N + n] = v;
            }
        }
    }
}

// ---------------------------------------------------------------------------
// qfin body (round-19 proven)
// ---------------------------------------------------------------------------
__device__ __forceinline__ void qfin_body(
    int q, double* red, double* stats, double* hsh, double* rps,
    const double* __restrict__ h0, const float* __restrict__ g,
    const float* __restrict__ bb, const float* __restrict__ w2,
    const float* __restrict__ b2,
    const double* __restrict__ offv_g, const double* __restrict__ logit_g,
    float* __restrict__ awf, int* __restrict__ idxv)
{
    int t = threadIdx.x;
    double x[4];
#pragma unroll
    for (int i = 0; i < 4; ++i) x[i] = h0[q * 1024 + t + i * 256];
    double s = x[0] + x[1] + x[2] + x[3];
    red[t] = s; __syncthreads();
    for (int o = 128; o; o >>= 1) { if (t < o) red[t] += red[t + o]; __syncthreads(); }
    if (t == 0) stats[0] = red[0] / 1024.0;
    __syncthreads();
    double mean = stats[0];
    double d = 0.0;
#pragma unroll
    for (int i = 0; i < 4; ++i) { double dd = x[i] - mean; d += dd * dd; }
    red[t] = d; __syncthreads();
    for (int o = 128; o; o >>= 1) { if (t < o) red[t] += red[t + o]; __syncthreads(); }
    if (t == 0) stats[1] = red[0] / 1024.0;
    __syncthreads();
    double inv = 1.0 / sqrt(stats[1] + 1e-5);
#pragma unroll
    for (int i = 0; i < 4; ++i) {
        int c = t + i * 256;
        double y = (x[i] - mean) * inv * (double)g[c] + (double)bb[c];
        hsh[c] = y * 0.5 * (1.0 + erf(y * 0.70710678118654752440));
    }
    __syncthreads();
    if (t < 128) {
        int r = t >> 6;
        int lane = t & 63;
        double sv = 0.0;
        for (int k = lane; k < EE; k += 64)
            sv += hsh[k] * (double)w2[r * 1024 + k];
#pragma unroll
        for (int off = 32; off > 0; off >>= 1) sv += __shfl_down(sv, off, 64);
        if (lane == 0) rps[r] = 1.0 / (1.0 + exp(-(sv + (double)b2[r])));
    }
    __syncthreads();
    if (t < 64) {
        int hh = t >> 2, p = t & 3;
        const double* logit = logit_g + q * 64;
        const double* offv  = offv_g + q * 128;
        double l0 = logit[hh * 4 + 0], l1 = logit[hh * 4 + 1];
        double l2 = logit[hh * 4 + 2], l3 = logit[hh * 4 + 3];
        double m = fmax(fmax(l0, l1), fmax(l2, l3));
        double den = exp(l0 - m) + exp(l1 - m) + exp(l2 - m) + exp(l3 - m);
        awf[(q * 16 + hh) * 4 + p] = (float)(exp(logit[hh * 4 + p] - m) / den);
        const int Wss[3] = {24, 12, 8};
        const int starts[3] = {0, 576, 720};
        double ox = offv[(hh * 4 + p) * 2 + 0], oy = offv[(hh * 4 + p) * 2 + 1];
        double rx = rps[0], ry = rps[1];
#pragma unroll
        for (int l = 0; l < 3; ++l) {
            int Ws = Wss[l];
            double sx = rx + ox; sx = sx < 0.0 ? 0.0 : (sx > 1.0 ? 1.0 : sx);
            double sy = ry + oy; sy = sy < 0.0 ? 0.0 : (sy > 1.0 ? 1.0 : sy);
            int x0 = (int)floor(sx * (double)(Ws - 1));
            int y0 = (int)floor(sy * (double)(Ws - 1));
            idxv[((l * 64 + q) * 16 + hh) * 4 + p] = starts[l] + y0 * Ws + x0;
        }
    }
}

// ---------------------------------------------------------------------------
// WW GEMM + qfin merged dispatch (round-20 proven)
// ---------------------------------------------------------------------------
__global__ __launch_bounds__(256, 2) void ww_qfin_kernel(
    const unsigned short* __restrict__ VPW, const unsigned short* __restrict__ PT,
    unsigned short* __restrict__ WW,
    const double* __restrict__ h0, const float* __restrict__ rg_g,
    const float* __restrict__ rg_b, const float* __restrict__ rg_w2,
    const float* __restrict__ rg_b2,
    const double* __restrict__ offv_g, const double* __restrict__ logit_g,
    float* __restrict__ awf, int* __restrict__ idxv)
{
    __shared__ unsigned short As[2 * 128 * 64];   // 32KB
    __shared__ unsigned short Bs[2 * 128 * 64];   // 32KB
    __shared__ double qsh[256 + 2 + 1024 + 2];    // ~10KB

    int bid = blockIdx.x;
    if (bid < 672) {
        int swz = (bid & 7) * 84 + (bid >> 3);    // bijective over 672
        int by = swz / 84, bx = swz % 84;
        gemm2w_body<true>(As, Bs, VPW, PT, nullptr, WW, 1024, WWN, 1024, by, bx, 0, 16);
    } else {
        qfin_body(bid - 672, qsh, qsh + 256, qsh + 258, qsh + 1282,
                  h0, rg_g, rg_b, rg_w2, rg_b2, offv_g, logit_g, awf, idxv);
    }
}

// ---------------------------------------------------------------------------
// split-K (z in {0,1}) partial 4096x1024x1024 GEMM, fp32 partials.
// ---------------------------------------------------------------------------
__global__ __launch_bounds__(256, 2) void gemm_pk_kernel(
    const unsigned short* __restrict__ A, const unsigned short* __restrict__ Bw,
    float* __restrict__ P)
{
    __shared__ unsigned short As[2 * 128 * 64];
    __shared__ unsigned short Bs[2 * 128 * 64];
    int nwg = gridDim.x * gridDim.y;              // 256
    int bid = blockIdx.y * gridDim.x + blockIdx.x;
    int chunk = nwg >> 3;
    int swz = (bid & 7) * chunk + (bid >> 3);
    int by = swz / gridDim.x, bx = swz % gridDim.x;
    gemm2w_body<false>(As, Bs, A, Bw, nullptr,
                       P + (size_t)blockIdx.z * 4194304,
                       4096, 1024, 1024, by, bx, blockIdx.z * 512, 8);
}

// ---------------------------------------------------------------------------
// LN over (p0 + p1 + op_b), bf16 out (round-20 proven)
// ---------------------------------------------------------------------------
__global__ void lnsum_b2b_kernel(const float* __restrict__ p0, const float* __restrict__ p1,
                                 const float* __restrict__ opb, const float* __restrict__ g,
                                 const float* __restrict__ bb, unsigned short* __restrict__ y)
{
    __shared__ float red[256];
    __shared__ float stats[2];
    int r = blockIdx.x, t = threadIdx.x;
    f4 a = *(const f4*)(p0 + (size_t)r * 1024 + t * 4);
    f4 bvec = *(const f4*)(p1 + (size_t)r * 1024 + t * 4);
    float v[4];
#pragma unroll
    for (int i = 0; i < 4; ++i) v[i] = a[i] + bvec[i] + opb[t * 4 + i];
    float s = v[0] + v[1] + v[2] + v[3];
    red[t] = s; __syncthreads();
    for (int o = 128; o; o >>= 1) { if (t < o) red[t] += red[t + o]; __syncthreads(); }
    if (t == 0) stats[0] = red[0] / 1024.f;
    __syncthreads();
    float mean = stats[0];
    float d = 0.f;
#pragma unroll
    for (int i = 0; i < 4; ++i) { float dd = v[i] - mean; d += dd * dd; }
    red[t] = d; __syncthreads();
    for (int o = 128; o; o >>= 1) { if (t < o) red[t] += red[t + o]; __syncthreads(); }
    if (t == 0) stats[1] = red[0] / 1024.f;
    __syncthreads();
    float inv = 1.f / sqrtf(stats[1] + 1e-5f);
    us4 o4;
#pragma unroll
    for (int i = 0; i < 4; ++i) {
        int c = t * 4 + i;
        o4[i] = f2b((v[i] - mean) * inv * g[c] + bb[c]);
    }
    *(us4*)(y + (size_t)r * 1024 + t * 4) = o4;
}

// out = p0 + p1 + fin_b (fp32) — round-4 proven
__global__ void finred_kernel(const float* __restrict__ p0, const float* __restrict__ p1,
                              const float* __restrict__ fb, float* __restrict__ out)
{
    int idx = blockIdx.x * 256 + threadIdx.x;
    size_t e0 = (size_t)idx * 8;
    int n = (int)(e0 & 1023);
    f4 a0 = *(const f4*)(p0 + e0);
    f4 a1 = *(const f4*)(p0 + e0 + 4);
    f4 b0 = *(const f4*)(p1 + e0);
    f4 b1 = *(const f4*)(p1 + e0 + 4);
    f4 o0, o1;
#pragma unroll
    for (int i = 0; i < 4; ++i) { o0[i] = a0[i] + b0[i] + fb[n + i]; o1[i] = a1[i] + b1[i] + fb[n + 4 + i]; }
    *(f4*)(out + e0) = o0;
    *(f4*)(out + e0 + 4) = o1;
}

// ---------------------------------------------------------------------------
// MEGA-HEAD dispatch (round-19 proven): rg1 + offlog + prep.
// ---------------------------------------------------------------------------
__global__ void mega_head_kernel(
    const float* __restrict__ qe, const float* __restrict__ rg_w1, const float* __restrict__ rg_b1,
    double* __restrict__ h0,
    const float* __restrict__ so_w, const float* __restrict__ so_b,
    const float* __restrict__ aw_w, const float* __restrict__ aw_b,
    double* __restrict__ offv_g, double* __restrict__ logit_g,
    const float* __restrict__ feat, unsigned short* __restrict__ FEAT,
    const float* __restrict__ vpw, unsigned short* __restrict__ VPW,
    const float* __restrict__ opw, unsigned short* __restrict__ OPW,
    const float* __restrict__ finw, unsigned short* __restrict__ FINW,
    const float* __restrict__ p1, const float* __restrict__ p2,
    const float* __restrict__ p3, unsigned short* __restrict__ PT,
    const float* __restrict__ vp_b,
    const float* __restrict__ pb1, const float* __restrict__ pb2, const float* __restrict__ pb3,
    float* __restrict__ o1, float* __restrict__ o2, float* __restrict__ o3)
{
    __shared__ float tile[32][33];
    int B = blockIdx.x;
    if (B < 16384) {
        int o = B * 4 + (threadIdx.x >> 6);
        int lane = threadIdx.x & 63;
        int q = o >> 10, n = o & 1023;
        double s = 0.0;
        for (int k = lane; k < EE; k += 64)
            s += (double)qe[q * EE + k] * (double)rg_w1[(size_t)n * EE + k];
#pragma unroll
        for (int off = 32; off > 0; off >>= 1) s += __shfl_down(s, off, 64);
        if (lane == 0) h0[o] = s + (double)rg_b1[n];
    } else if (B < 19456) {
        int o = (B - 16384) * 4 + (threadIdx.x >> 6);
        int lane = threadIdx.x & 63;
        const float* wrow;
        double bias;
        int q;
        if (o < 8192) { q = o >> 7; int j = o & 127; wrow = so_w + (size_t)j * EE; bias = (double)so_b[j]; }
        else          { int r = o - 8192; q = r >> 6; int n = r & 63; wrow = aw_w + (size_t)n * EE; bias = (double)aw_b[n]; }
        double s = 0.0;
        for (int k = lane; k < EE; k += 64)
            s += (double)qe[q * EE + k] * (double)wrow[k];
#pragma unroll
        for (int off = 32; off > 0; off >>= 1) s += __shfl_down(s, off, 64);
        if (lane == 0) {
            if (o < 8192) offv_g[o] = s + bias;
            else          logit_g[o - 8192] = s + bias;
        }
    } else {
        int blk = B - 19456;
        if (blk < 15360) {
            const float* in; unsigned short* out;
            if (blk < 13824)       { in = feat; out = FEAT; }
            else if (blk < 14336)  { in = vpw;  out = VPW;  blk -= 13824; }
            else if (blk < 14848)  { in = opw;  out = OPW;  blk -= 14336; }
            else                   { in = finw; out = FINW; blk -= 14848; }
            size_t i = ((size_t)blk * 256 + threadIdx.x) * 8;
            f4 x = *(const f4*)(in + i);
            f4 y = *(const f4*)(in + i + 4);
            ushort8 o;
            o[0] = f2b(x[0]); o[1] = f2b(x[1]); o[2] = f2b(x[2]); o[3] = f2b(x[3]);
            o[4] = f2b(y[0]); o[5] = f2b(y[1]); o[6] = f2b(y[2]); o[7] = f2b(y[3]);
            *(ushort8*)(out + i) = o;
        } else if (blk < 26112) {
            int fl = blk - 15360;
            int bx = fl % 336, byy = fl / 336;
            const float* in; unsigned short* out; int C;
            if (bx < 24)       { in = p1; out = PT;                C = 768; }
            else if (bx < 120) { in = p2; out = PT + 768  * 1024;  C = 3072; bx -= 24; }
            else               { in = p3; out = PT + 3840 * 1024;  C = 6912; bx -= 120; }
            const int R = 1024;
            int c0 = bx * 32, r0 = byy * 32;
            int tx = threadIdx.x & 31, ty = threadIdx.x >> 5;
#pragma unroll
            for (int i = 0; i < 32; i += 8)
                tile[ty + i][tx] = in[(size_t)(r0 + ty + i) * C + c0 + tx];
            __syncthreads();
#pragma unroll
            for (int i = 0; i < 32; i += 8)
                out[(size_t)(c0 + ty + i) * R + r0 + tx] = f2b(tile[tx][ty + i]);
        } else {
            int b = blk - 26112;
            const float* pb; float* bout;
            if (b < 256)      { pb = pb1; bout = o1; }
            else if (b < 512) { pb = pb2; bout = o2; b -= 256; }
            else              { pb = pb3; bout = o3; b -= 512; }
            int e = b * 4 + (threadIdx.x >> 6);
            int lane = threadIdx.x & 63;
            float s = 0.f;
            for (int k = lane; k < EE; k += 64) s += vpw[(size_t)e * EE + k] * pb[k];
#pragma unroll
            for (int o = 32; o > 0; o >>= 1) s += __shfl_down(s, o, 64);
            if (lane == 0) bout[e] = s + vp_b[e];
        }
    }
}

extern "C" void kernel_launch(void* const* d_in, const int* in_sizes, int n_in,
                              void* d_out, int out_size, void* d_ws, size_t ws_size,
                              hipStream_t stream)
{
    const float* features  = (const float*)d_in[0];
    const float* p1_w      = (const float*)d_in[1];
    const float* p1_b      = (const float*)d_in[2];
    const float* p2_w      = (const float*)d_in[3];
    const float* p2_b      = (const float*)d_in[4];
    const float* p3_w      = (const float*)d_in[5];
    const float* p3_b      = (const float*)d_in[6];
    const float* query_emb = (const float*)d_in[7];
    const float* rg_w1     = (const float*)d_in[8];
    const float* rg_b1     = (const float*)d_in[9];
    const float* rg_g      = (const float*)d_in[10];
    const float* rg_b      = (const float*)d_in[11];
    const float* rg_w2     = (const float*)d_in[12];
    const float* rg_b2     = (const float*)d_in[13];
    const float* so_w      = (const float*)d_in[14];
    const float* so_b      = (const float*)d_in[15];
    const float* aw_w      = (const float*)d_in[16];
    const float* aw_b      = (const float*)d_in[17];
    const float* vp_w      = (const float*)d_in[18];
    const float* vp_b      = (const float*)d_in[19];
    const float* op_w      = (const float*)d_in[20];
    const float* op_b      = (const float*)d_in[21];
    const float* fln_g     = (const float*)d_in[22];
    const float* fln_b     = (const float*)d_in[23];
    const float* fin_w     = (const float*)d_in[24];
    const float* fin_b     = (const float*)d_in[25];
    float* out = (float*)d_out;

    // ---- workspace layout (bytes) ----
    char* p = (char*)d_ws;
    unsigned short* FEAT = (unsigned short*)p; p += 56623104;   // bf16 [B*576,768]
    unsigned short* PT   = (unsigned short*)p; p += 22020096;   // [10752,1024] stacked p_w^T
    unsigned short* WW   = (unsigned short*)p; p += 22020096;   // [1024,10752] fused weights
    unsigned short* VPW  = (unsigned short*)p; p += 2097152;
    unsigned short* VAL  = (unsigned short*)p; p += 75497472;   // bf16 [64*576,1024] (L1 only)
    unsigned short* PART = (unsigned short*)p; p += 90177536;   // bf16 partials; reused as fp32 POUT/PFIN
    unsigned short* OUT0 = (unsigned short*)p; p += 8388608;
    unsigned short* LNO  = (unsigned short*)p; p += 8388608;
    unsigned short* OPW  = (unsigned short*)p; p += 2097152;
    unsigned short* FINW = (unsigned short*)p; p += 2097152;
    float* b1p  = (float*)p; p += 4096;
    float* b2p  = (float*)p; p += 4096;
    float* b3p  = (float*)p; p += 4096;
    float* awf  = (float*)p; p += 16384;
    int*   idxv = (int*)p;   p += 49152;
    double* h0  = (double*)p; p += 524288;
    double* offv_g  = (double*)p; p += 65536;   // [64,128]
    double* logit_g = (double*)p; p += 32768;   // [64,64]

    unsigned short* PART2 = PART;                       // 3 x 9437184 elems
    unsigned short* PART3 = PART + 3 * 9437184;         // 4 x 4194304 elems
    float* PPK = (float*)PART;                          // 2 x 4194304 f32 (epilogue partials)

    dim3 blk(256);

    // ---- mega head: rg1 + offlog + prep (independent producers) ----
    mega_head_kernel<<<46336, blk, 0, stream>>>(
        query_emb, rg_w1, rg_b1, h0,
        so_w, so_b, aw_w, aw_b, offv_g, logit_g,
        features, FEAT, vp_w, VPW, op_w, OPW, fin_w, FINW,
        p1_w, p2_w, p3_w, PT,
        vp_b, p1_b, p2_b, p3_b, b1p, b2p, b3p);

    // ---- WW GEMM + qfin merged ----
    ww_qfin_kernel<<<736, blk, 0, stream>>>(VPW, PT, WW,
                                            h0, rg_g, rg_b, rg_w2, rg_b2,
                                            offv_g, logit_g, awf, idxv);

    // ---- value GEMMs: merged LPT dispatch (L3 z=4, L2 z=3, L1) ----
    gemm_val_merged<<<1264, 512, 0, stream>>>(FEAT, WW, b1p, VAL, PART2, PART3);

    // ---- fused gather + split-K reduce + bias ----
    gather_fused_kernel<<<2048, blk, 0, stream>>>(VAL, PART2, PART3, b2p, b3p, awf, idxv, OUT0);

    // ---- output projection (split-K x2, fp32 partials) + LN(sum) ----
    gemm_pk_kernel<<<dim3(8, 32, 2), blk, 0, stream>>>(OUT0, OPW, PPK);
    lnsum_b2b_kernel<<<4096, blk, 0, stream>>>(PPK, PPK + 4194304, op_b, fln_g, fln_b, LNO);

    // ---- final projection (split-K x2) + reduce ----
    gemm_pk_kernel<<<dim3(8, 32, 2), blk, 0, stream>>>(LNO, FINW, PPK);
    finred_kernel<<<2048, blk, 0, stream>>>(PPK, PPK + 4194304, fin_b, out);
}